// Round 4
// baseline (866.996 us; speedup 1.0000x reference)
//
#include <hip/hip_runtime.h>
#include <cmath>

typedef unsigned long long u64;

#define PRE_TOPN 12000
#define POST_TOPN 2000
#define SORTN 32768
#define TILE 8192
#define NTILE (SORTN / TILE)   // 4 tiles per batch
#define NBLK 188               // 64-bit column blocks covering 12032
#define PADN (NBLK * 64)       // 12032
// ROW-MAJOR triangular bitmap: row r stores words for col-blocks
// cb in [r/64, NBLK) contiguously at rowoff(r). Total words per batch:
#define TRI_WORDS (32 * (NBLK - 1) * NBLK + NBLK * 64)  // 1,137,024
#define MASK_WORDS 192         // 188 used, padded

__device__ __forceinline__ int rowoff(int r) {
    int rb = r >> 6;
    int q = r & 63;
    return r * NBLK - (32 * rb * (rb - 1) + q * rb);
}

// ---------------------------------------------------------------------------
// Kernel 1: decode boxes (exact fp32 op order, no FMA contraction, exp via
// double) and pack sort keys. key = (~score_bits)<<32 | idx.
// Also resets the per-batch NMS progress state (kcnt/done) for this launch.
// ---------------------------------------------------------------------------
__global__ void decode_pack(const float* __restrict__ anchors,
                            const float* __restrict__ deltas,
                            const float* __restrict__ scores,
                            float* __restrict__ boxes,
                            u64* __restrict__ keys,
                            int* __restrict__ kcnt,
                            int* __restrict__ done,
                            int N) {
#pragma clang fp contract(off)
    int n = blockIdx.x * blockDim.x + threadIdx.x;
    int b = blockIdx.y;
    if (kcnt != nullptr && blockIdx.x == 0 && threadIdx.x == 0) {
        kcnt[b] = 0;
        done[b] = 0;
    }
    if (n >= SORTN) return;
    u64* kb = keys + (size_t)b * SORTN;
    if (n < N) {
        float a0 = anchors[n * 4 + 0];
        float a1 = anchors[n * 4 + 1];
        float a2 = anchors[n * 4 + 2];
        float a3 = anchors[n * 4 + 3];
        float w = (a2 - a0) + 1.0f;
        float h = (a3 - a1) + 1.0f;
        float cx = a0 + 0.5f * w;
        float cy = a1 + 0.5f * h;
        const float* d = deltas + ((size_t)b * N + n) * 4;
        float dx = d[0], dy = d[1], dw = d[2], dh = d[3];
        float px = cx + w * dx;
        float py = cy + h * dy;
        float pw = (float)::exp((double)dw) * w;
        float ph = (float)::exp((double)dh) * h;
        float* bb = boxes + ((size_t)b * N + n) * 4;
        bb[0] = px - 0.5f * pw;
        bb[1] = py - 0.5f * ph;
        bb[2] = px + 0.5f * (pw - 2.0f);
        bb[3] = py + 0.5f * (ph - 2.0f);
        unsigned int sb = __float_as_uint(scores[(size_t)b * N + n]);
        kb[n] = ((u64)(~sb) << 32) | (u64)(unsigned int)n;
    } else {
        kb[n] = ~0ULL;
    }
}

// ---------------------------------------------------------------------------
// Hybrid bitonic sort (unchanged).
// ---------------------------------------------------------------------------
__global__ __launch_bounds__(1024) void bitonic_local_sort(u64* __restrict__ keys) {
    __shared__ u64 sk[TILE];
    int tile = blockIdx.x;
    u64* kb = keys + (size_t)tile * TILE;
    int base = (tile % NTILE) * TILE;
    for (int i = threadIdx.x; i < TILE; i += 1024) sk[i] = kb[i];
    __syncthreads();
    for (int k = 2; k <= TILE; k <<= 1) {
        for (int j = k >> 1; j > 0; j >>= 1) {
            for (int t = threadIdx.x; t < TILE / 2; t += 1024) {
                int i = ((t & ~(j - 1)) << 1) | (t & (j - 1));
                int ixj = i | j;
                u64 a = sk[i];
                u64 c = sk[ixj];
                bool up = (((base + i) & k) == 0);
                if ((a > c) == up) { sk[i] = c; sk[ixj] = a; }
            }
            __syncthreads();
        }
    }
    for (int i = threadIdx.x; i < TILE; i += 1024) kb[i] = sk[i];
}

__global__ void bitonic_global_step(u64* __restrict__ keys, int k, int j) {
    int t = blockIdx.x * blockDim.x + threadIdx.x;
    int b = t / (SORTN / 2);
    int s = t % (SORTN / 2);
    int i = ((s & ~(j - 1)) << 1) | (s & (j - 1));
    int ixj = i | j;
    u64* kb = keys + (size_t)b * SORTN;
    u64 a = kb[i];
    u64 c = kb[ixj];
    bool up = ((i & k) == 0);
    if ((a > c) == up) { kb[i] = c; kb[ixj] = a; }
}

__global__ __launch_bounds__(1024) void bitonic_local_merge(u64* __restrict__ keys, int k) {
    __shared__ u64 sk[TILE];
    int tile = blockIdx.x;
    u64* kb = keys + (size_t)tile * TILE;
    int base = (tile % NTILE) * TILE;
    bool up = ((base & k) == 0);
    for (int i = threadIdx.x; i < TILE; i += 1024) sk[i] = kb[i];
    __syncthreads();
    for (int j = TILE / 2; j > 0; j >>= 1) {
        for (int t = threadIdx.x; t < TILE / 2; t += 1024) {
            int i = ((t & ~(j - 1)) << 1) | (t & (j - 1));
            int ixj = i | j;
            u64 a = sk[i];
            u64 c = sk[ixj];
            if ((a > c) == up) { sk[i] = c; sk[ixj] = a; }
        }
        __syncthreads();
    }
    for (int i = threadIdx.x; i < TILE; i += 1024) kb[i] = sk[i];
}

// ---------------------------------------------------------------------------
// Gather sorted top-PADN boxes. Pad rows get far-away degenerate boxes.
// ---------------------------------------------------------------------------
__global__ void gather_sorted(const float* __restrict__ boxes,
                              const u64* __restrict__ keys,
                              float4* __restrict__ sbox, int N) {
    int r = blockIdx.x * 256 + threadIdx.x;
    int b = blockIdx.y;
    if (r >= PADN) return;
    float4 v;
    if (r < PRE_TOPN) {
        u64 key = keys[(size_t)b * SORTN + r];
        int n = (int)(unsigned)(key & 0xffffffffULL);
        v = ((const float4*)boxes)[(size_t)b * N + n];
    } else {
        v = make_float4(-4e8f, -4e8f, -4e8f, -4e8f);
    }
    sbox[(size_t)b * PADN + r] = v;
}

// ---------------------------------------------------------------------------
// Exact-f32 suppression predicate (bit-identical to the f64 reference test).
// ---------------------------------------------------------------------------
__device__ __forceinline__ void iou_bit(float4 me, float ar, float4 cj, float aj,
                                        int j, unsigned& lo, unsigned& hi, int& tie) {
#pragma clang fp contract(off)
    float xx1 = fmaxf(me.x, cj.x);
    float yy1 = fmaxf(me.y, cj.y);
    float xx2 = fminf(me.z, cj.z);
    float yy2 = fminf(me.w, cj.w);
    float w = fmaxf((xx2 - xx1) + 1.0f, 0.0f);
    float h = fmaxf((yy2 - yy1) + 1.0f, 0.0f);
    float inter = w * h;
    float un = (ar + aj) - inter;
    float t = __builtin_fmaf(-0.7f, un, inter);
    float u25 = un * 0x1p-25f;
    unsigned sup = (t > u25) ? 1u : 0u;
    tie |= (t == u25) ? 1 : 0;
    if (j < 32) lo |= sup << j;
    else        hi |= sup << (j - 32);
}

__device__ __attribute__((noinline)) u64 slow_word(float4 me, float ar,
                                                   const float4* cbox,
                                                   const float* carea) {
#pragma clang fp contract(off)
    const double MD = (double)0.7f + 0x1p-25;   // exact midpoint multiplier
    u64 word = 0;
    for (int j = 0; j < 64; ++j) {
        float4 cj = cbox[j];
        float aj = carea[j];
        float xx1 = fmaxf(me.x, cj.x);
        float yy1 = fmaxf(me.y, cj.y);
        float xx2 = fminf(me.z, cj.z);
        float yy2 = fminf(me.w, cj.w);
        float w = fmaxf((xx2 - xx1) + 1.0f, 0.0f);
        float h = fmaxf((yy2 - yy1) + 1.0f, 0.0f);
        float inter = w * h;
        float un = (ar + aj) - inter;
        bool sup = ((double)inter >= MD * (double)un);
        word |= ((u64)sup) << j;
    }
    return word;
}

// ---------------------------------------------------------------------------
// Build ROW-MAJOR suppression bitmap for col-block pairs [pair0, ...).
// Block = 256 rows x 2 col-blocks; thread t: cb = 2*pair + (t&1),
// rows chunk*256 + (t>>1) and +128. Word (r,cb) written at
// bitmap[rowoff(r) + cb - r/64]; lane pairs write adjacent words (16B).
// ---------------------------------------------------------------------------
__global__ __launch_bounds__(256) void build_bitmap(const float4* __restrict__ sbox,
                                                    u64* __restrict__ bitmap,
                                                    const int* __restrict__ done,
                                                    int pair0) {
    int pair = pair0 + blockIdx.x;   // covers cbs 2*pair, 2*pair+1
    int chunk = blockIdx.y;          // 256-row chunk
    int b = blockIdx.z;
    if (done[b]) return;
    if (2 * chunk > pair) return;    // chunk's first row >= (2p+2)*64 -> empty
    int tid = threadIdx.x;
    int w = tid & 1;
    int cb = pair * 2 + w;
    int lim = (cb + 1) * 64;         // rows with words in column-block cb

    __shared__ float4 cbox[2][64];
    __shared__ float carea[2][64];
    const float4* sb = sbox + (size_t)b * PADN;
    if (tid < 128) {
        int which = tid >> 6, j = tid & 63;
        float4 c4 = sb[(pair * 2 + which) * 64 + j];
        cbox[which][j] = c4;
        carea[which][j] = ((c4.z - c4.x) + 1.0f) * ((c4.w - c4.y) + 1.0f);
    }
    int rl = tid >> 1;               // 0..127
    int r1 = chunk * 256 + rl;       // <= 46*256+127 = 11903 < PADN
    int r2 = r1 + 128;               // <= 12031 < PADN
    bool a1 = (r1 < lim);
    bool a2 = (r2 < lim);
    float4 me1 = sb[r1];
    float4 me2 = sb[r2];
    float ar1 = ((me1.z - me1.x) + 1.0f) * ((me1.w - me1.y) + 1.0f);
    float ar2 = ((me2.z - me2.x) + 1.0f) * ((me2.w - me2.y) + 1.0f);
    __syncthreads();

    if (a1) {
        unsigned lo1 = 0, hi1 = 0;
        int tie1 = 0;
#pragma unroll
        for (int j = 0; j < 64; ++j) {
            iou_bit(me1, ar1, cbox[w][j], carea[w][j], j, lo1, hi1, tie1);
        }
        u64 w1 = ((u64)hi1 << 32) | lo1;
        if (__builtin_expect(tie1, 0)) w1 = slow_word(me1, ar1, cbox[w], carea[w]);
        int d1 = r1 - cb * 64;
        if (d1 >= 0) w1 &= ~((2ULL << d1) - 1ULL);   // upper triangle only
        bitmap[(size_t)b * TRI_WORDS + rowoff(r1) + (cb - (r1 >> 6))] = w1;
    }
    if (a2) {
        unsigned lo2 = 0, hi2 = 0;
        int tie2 = 0;
#pragma unroll
        for (int j = 0; j < 64; ++j) {
            iou_bit(me2, ar2, cbox[w][j], carea[w][j], j, lo2, hi2, tie2);
        }
        u64 w2 = ((u64)hi2 << 32) | lo2;
        if (__builtin_expect(tie2, 0)) w2 = slow_word(me2, ar2, cbox[w], carea[w]);
        int d2 = r2 - cb * 64;
        if (d2 >= 0) w2 &= ~((2ULL << d2) - 1ULL);
        bitmap[(size_t)b * TRI_WORDS + rowoff(r2) + (cb - (r2 >> 6))] = w2;
    }
}

// ---------------------------------------------------------------------------
// DPP all-reduce OR within a 16-lane row; wave total via readlanes.
// ---------------------------------------------------------------------------
__device__ __forceinline__ unsigned dpp_or16(unsigned v) {
    v |= (unsigned)__builtin_amdgcn_update_dpp(0, (int)v, 0xB1, 0xF, 0xF, true);   // quad_perm {1,0,3,2}
    v |= (unsigned)__builtin_amdgcn_update_dpp(0, (int)v, 0x4E, 0xF, 0xF, true);   // quad_perm {2,3,0,1}
    v |= (unsigned)__builtin_amdgcn_update_dpp(0, (int)v, 0x141, 0xF, 0xF, true);  // row_half_mirror
    v |= (unsigned)__builtin_amdgcn_update_dpp(0, (int)v, 0x140, 0xF, 0xF, true);  // row_mirror
    return v;
}

__device__ __forceinline__ unsigned wave_or_from_rows(unsigned rowred) {
    unsigned a = (unsigned)__builtin_amdgcn_readlane((int)rowred, 0) |
                 (unsigned)__builtin_amdgcn_readlane((int)rowred, 16);
    unsigned c = (unsigned)__builtin_amdgcn_readlane((int)rowred, 32) |
                 (unsigned)__builtin_amdgcn_readlane((int)rowred, 48);
    return a | c;
}

// ---------------------------------------------------------------------------
// Resumable scan, round-9: INCREMENTAL suppression mask.
// s_S[cb] = OR over all committed picks p of word(p,cb). Per iteration rb:
//   - sup for block rb = s_S[rb] | dpp_or(delta)    (delta: picks of rb-1,
//     word cb=rb, self-loaded by the picking lanes last iteration)
//   - wave0 resolves the greedy (scalar, readlane row fetch) and appends
//     picks; picking lanes load their word cb=rb+1 as next delta.
//   - waves 1-3 concurrently OR the tails (cb >= rb+1) of the PREVIOUS
//     block's picks into s_S: contiguous coalesced loads (row-major rows),
//     LDS atomicOr. One barrier per iteration. Parity-double-buffered pick
//     lists avoid write/read races. Stage-end cleanup ORs the last block's
//     picks (cb >= rb1) before persisting s_S to S_g for the next stage.
// Semantics identical to round-7/8 scans.
// ---------------------------------------------------------------------------
__global__ __launch_bounds__(256) void scan_nms(const float4* __restrict__ sbox,
                                                const u64* __restrict__ bitmap,
                                                float* __restrict__ out,
                                                u64* __restrict__ S_g,
                                                int* __restrict__ kcnt,
                                                int* __restrict__ done,
                                                int rb0, int rb1) {
    int b = blockIdx.x;
    if (done[b]) return;
    int tid = threadIdx.x;
    int lane = tid & 63;
    int wv = tid >> 6;
    __shared__ u64 s_S[MASK_WORDS];        // 1.5 KB running suppression mask
    __shared__ int s_prevpicks[2][64];
    __shared__ int s_np[2];
    __shared__ int s_K;

    u64* Sg = S_g + (size_t)b * MASK_WORDS;
    int K0 = kcnt[b];
    if (tid == 0) s_K = K0;
    if (tid < 2) s_np[tid] = 0;
    if (tid < MASK_WORDS) s_S[tid] = (tid < NBLK && rb0 > 0) ? Sg[tid] : 0ULL;

    const u64* bm = bitmap + (size_t)b * TRI_WORDS;
    const float4* sbb = sbox + (size_t)b * PADN;

    // prologue: diag row + box for rb0 (wave0)
    u64 myrow = 0, delta = 0;
    float4 mybox = make_float4(0.f, 0.f, 0.f, 0.f);
    if (wv == 0) {
        int r = rb0 * 64 + lane;
        myrow = bm[rowoff(r)];             // word (r, rb0): diagonal
        mybox = sbb[r];
    }
    __syncthreads();

    int rb = rb0;
    for (; rb < rb1; ++rb) {
        int K = s_K;                       // uniform (post-barrier)
        if (K >= POST_TOPN) break;
        int base = rb * 64;
        bool havenext = (rb + 1 < rb1);
        int pq = (rb + 1) & 1;             // parity of block rb-1

        if (wv == 0) {
            // early prefetch of next diagonal row+box (independent of picks)
            u64 nrow = 0;
            float4 nbox = make_float4(0.f, 0.f, 0.f, 0.f);
            if (havenext) {
                int rn = (rb + 1) * 64 + lane;
                nrow = bm[rowoff(rn)];
                nbox = sbb[rn];
            }
            // delta reduce: picks of rb-1 suppression into cb=rb
            unsigned rlo = dpp_or16((unsigned)(delta & 0xffffffffULL));
            unsigned rhi = dpp_or16((unsigned)(delta >> 32));
            u64 dtot = ((u64)wave_or_from_rows(rhi) << 32) | wave_or_from_rows(rlo);
            u64 t4 = s_S[rb] | dtot;
            if (rb == NBLK - 1) t4 |= 0xFFFFFFFF00000000ULL;   // pad rows >= 12000
            unsigned tlo = (unsigned)__builtin_amdgcn_readfirstlane((int)(t4 & 0xffffffffULL));
            unsigned thi = (unsigned)__builtin_amdgcn_readfirstlane((int)(t4 >> 32));
            u64 alive = ~(((u64)thi << 32) | tlo);
            int mrl = (int)(myrow & 0xffffffffULL);
            int mrh = (int)(myrow >> 32);
            u64 picks = 0;
            u64 cur = alive;
            while (cur) {
                int i = (int)__builtin_ctzll(cur);
                picks |= 1ULL << i;
                unsigned rl = (unsigned)__builtin_amdgcn_readlane(mrl, i);
                unsigned rh = (unsigned)__builtin_amdgcn_readlane(mrh, i);
                u64 row = ((u64)rh << 32) | rl;
                alive &= ~row;
                cur = alive & ~((2ULL << i) - 1ULL);
            }
            int avail = POST_TOPN - K;
            int np = __popcll(picks);
            while (np > avail) {                       // truncate latest picks
                picks &= ~(1ULL << (63 - __clzll(picks)));
                --np;
            }
            int c = lane;
            bool ipick = ((picks >> c) & 1ULL) != 0;
            delta = 0;
            if (ipick) {
                int rank = __popcll(picks & ((1ULL << c) - 1ULL));
                int p = base + c;
                s_prevpicks[rb & 1][rank] = p;
                float* o = out + ((size_t)b * POST_TOPN + K + rank) * 5;
                o[0] = (float)b; o[1] = mybox.x; o[2] = mybox.y; o[3] = mybox.z; o[4] = mybox.w;
                if (havenext) delta = bm[rowoff(p) + 1];   // word (p, rb+1)
            }
            if (c == 0) {
                s_K = K + np;
                s_np[rb & 1] = np;
            }
            myrow = nrow; mybox = nbox;
        } else {
            // OR-step: tails of block rb-1's picks, cb in [rb+1, NBLK)
            int npp = s_np[pq];
            int st = tid - 64;             // 0..191, len <= 187 -> one round
            int len = NBLK - (rb + 1);
            for (int q = 0; q < npp; ++q) {
                int p = s_prevpicks[pq][q];
                if (st < len) {
                    u64 wq = bm[rowoff(p) + 2 + st];   // word (p, rb+1+st)
                    if (wq) atomicOr(&s_S[rb + 1 + st], wq);
                }
            }
        }
        __syncthreads();
    }

    int K = s_K;
    bool finished = (K >= POST_TOPN) || (rb1 >= NBLK);
    if (!finished) {
        // cleanup: OR tails (cb >= rb1) of block rb1-1's picks, persist S
        int pq = (rb1 - 1) & 1;
        int npp = s_np[pq];
        int len = NBLK - rb1;
        for (int q = 0; q < npp; ++q) {
            int p = s_prevpicks[pq][q];
            if (tid < len) {
                u64 wq = bm[rowoff(p) + 1 + tid];      // word (p, rb1+tid)
                if (wq) atomicOr(&s_S[rb1 + tid], wq);
            }
        }
        __syncthreads();
        if (tid < NBLK) Sg[tid] = s_S[tid];
    } else {
        for (int r = K + tid; r < POST_TOPN; r += 256) {
            float* o = out + ((size_t)b * POST_TOPN + r) * 5;
            o[0] = 0.0f; o[1] = 0.0f; o[2] = 0.0f; o[3] = 0.0f; o[4] = 0.0f;
        }
        if (tid == 0) done[b] = 1;
    }
    if (tid == 0) kcnt[b] = K;
}

// ---------------------------------------------------------------------------
// Fallback (round-2) NMS kernel — used only if ws_size can't hold the bitmap.
// ---------------------------------------------------------------------------
__global__ __launch_bounds__(1024) void nms_kernel(const float* __restrict__ boxes,
                                                   const u64* __restrict__ keys,
                                                   float* __restrict__ out,
                                                   int N) {
#pragma clang fp contract(off)
    __shared__ float4 kbox[POST_TOPN];
    __shared__ float kar[POST_TOPN];
    __shared__ float4 cbox[64];
    __shared__ float car_s[64];
    __shared__ int supp[64];
    __shared__ int s_cnt;

    int b = blockIdx.x;
    int tid = threadIdx.x;
    const u64* kb = keys + (size_t)b * SORTN;
    const float* bb = boxes + (size_t)b * N * 4;

    if (tid == 0) s_cnt = 0;
    __syncthreads();

    for (int start = 0; start < PRE_TOPN; start += 64) {
        int K = s_cnt;
        if (K >= POST_TOPN) break;
        int csize = min(64, PRE_TOPN - start);

        if (tid < 64) {
            int c = tid;
            if (c < csize) {
                u64 key = kb[start + c];
                int n = (int)(unsigned int)(key & 0xFFFFFFFFULL);
                const float* p = bb + (size_t)n * 4;
                float x1 = p[0], y1 = p[1], x2 = p[2], y2 = p[3];
                cbox[c] = make_float4(x1, y1, x2, y2);
                car_s[c] = ((x2 - x1) + 1.0f) * ((y2 - y1) + 1.0f);
            }
            supp[c] = 0;
        }
        __syncthreads();

        {
            int c = tid & 63;
            int sl = tid >> 6;
            if (c < csize) {
                float4 me = cbox[c];
                float ar = car_s[c];
                int flag = 0;
                for (int kk = sl; kk < K; kk += 16) {
                    float4 k0 = kbox[kk];
                    float a0 = kar[kk];
                    float xx1 = fmaxf(k0.x, me.x);
                    float yy1 = fmaxf(k0.y, me.y);
                    float xx2 = fminf(k0.z, me.z);
                    float yy2 = fminf(k0.w, me.w);
                    float w0 = fmaxf((xx2 - xx1) + 1.0f, 0.0f);
                    float h0 = fmaxf((yy2 - yy1) + 1.0f, 0.0f);
                    float inter0 = w0 * h0;
                    float iou0 = inter0 / ((a0 + ar) - inter0);
                    if (iou0 > 0.7f) { flag = 1; break; }
                }
                if (flag) supp[c] = 1;
            }
        }
        __syncthreads();

        if (tid < 64) {
            int c = tid;
            bool alive = (c < csize) && (supp[c] == 0);
            float4 me = cbox[c];
            float ar = car_s[c];
            int cnt = K;
            u64 m = __ballot(alive);
            while (m != 0 && cnt < POST_TOPN) {
                int i = __ffsll((unsigned long long)m) - 1;
                float ix1 = __shfl(me.x, i);
                float iy1 = __shfl(me.y, i);
                float ix2 = __shfl(me.z, i);
                float iy2 = __shfl(me.w, i);
                float iar = __shfl(ar, i);
                if (c == i) {
                    kbox[cnt] = me;
                    kar[cnt] = ar;
                    float* o = out + ((size_t)b * POST_TOPN + cnt) * 5;
                    o[0] = (float)b; o[1] = me.x; o[2] = me.y; o[3] = me.z; o[4] = me.w;
                }
                if (alive && c > i) {
                    float xx1 = fmaxf(ix1, me.x);
                    float yy1 = fmaxf(iy1, me.y);
                    float xx2 = fminf(ix2, me.z);
                    float yy2 = fminf(iy2, me.w);
                    float w = fmaxf((xx2 - xx1) + 1.0f, 0.0f);
                    float h = fmaxf((yy2 - yy1) + 1.0f, 0.0f);
                    float inter = w * h;
                    float iou = inter / ((iar + ar) - inter);
                    if (iou > 0.7f) alive = false;
                }
                cnt++;
                m = __ballot(alive);
                u64 clearmask = (2ULL << i) - 1ULL;
                m &= ~clearmask;
            }
            if (c == 0) s_cnt = cnt;
        }
        __syncthreads();
    }

    __syncthreads();
    int K = s_cnt;
    for (int r = K + tid; r < POST_TOPN; r += (int)blockDim.x) {
        float* o = out + ((size_t)b * POST_TOPN + r) * 5;
        o[0] = 0.0f; o[1] = 0.0f; o[2] = 0.0f; o[3] = 0.0f; o[4] = 0.0f;
    }
}

// ---------------------------------------------------------------------------
extern "C" void kernel_launch(void* const* d_in, const int* in_sizes, int n_in,
                              void* d_out, int out_size, void* d_ws, size_t ws_size,
                              hipStream_t stream) {
    const float* anchors = (const float*)d_in[0];
    const float* deltas  = (const float*)d_in[1];
    const float* scores  = (const float*)d_in[2];
    float* out = (float*)d_out;

    int N = in_sizes[0] / 4;           // 27380
    int B = in_sizes[2] / N;           // 8

    size_t off = 0;
    auto take = [&](size_t bytes) { size_t o = off; off = (off + bytes + 255) & ~(size_t)255; return o; };
    size_t boxesOff  = take((size_t)B * N * 4 * sizeof(float));
    size_t keysOff   = take((size_t)B * SORTN * sizeof(u64));
    size_t sboxOff   = take((size_t)B * PADN * sizeof(float4));
    size_t bitmapOff = take((size_t)B * TRI_WORDS * sizeof(u64));
    size_t SgOff     = take((size_t)B * MASK_WORDS * sizeof(u64));
    size_t kcntOff   = take((size_t)B * sizeof(int));
    size_t doneOff   = take((size_t)B * sizeof(int));
    bool bitmap_path = (off <= ws_size);

    float* boxes = (float*)((char*)d_ws + boxesOff);
    u64*   keys  = (u64*)((char*)d_ws + keysOff);
    u64* S_g     = bitmap_path ? (u64*)((char*)d_ws + SgOff)   : nullptr;
    int* kcnt    = bitmap_path ? (int*)((char*)d_ws + kcntOff) : nullptr;
    int* done    = bitmap_path ? (int*)((char*)d_ws + doneOff) : nullptr;

    dim3 g1((unsigned)((SORTN + 255) / 256), (unsigned)B);
    decode_pack<<<g1, 256, 0, stream>>>(anchors, deltas, scores, boxes, keys, kcnt, done, N);

    int ntiles = B * NTILE;
    bitonic_local_sort<<<ntiles, 1024, 0, stream>>>(keys);
    int gsteps = B * (SORTN / 2) / 256;
    bitonic_global_step<<<gsteps, 256, 0, stream>>>(keys, 2 * TILE, TILE);
    bitonic_local_merge<<<ntiles, 1024, 0, stream>>>(keys, 2 * TILE);
    bitonic_global_step<<<gsteps, 256, 0, stream>>>(keys, 4 * TILE, 2 * TILE);
    bitonic_global_step<<<gsteps, 256, 0, stream>>>(keys, 4 * TILE, TILE);
    bitonic_local_merge<<<ntiles, 1024, 0, stream>>>(keys, 4 * TILE);

    if (bitmap_path) {
        float4* sbox = (float4*)((char*)d_ws + sboxOff);
        u64* bitmap  = (u64*)((char*)d_ws + bitmapOff);
        dim3 gg((unsigned)((PADN + 255) / 256), (unsigned)B);
        gather_sorted<<<gg, 256, 0, stream>>>(boxes, keys, sbox, N);

        // Progressive build/scan with per-batch done[] cutoff. Segments in
        // col-block units (all even, so they split into whole cb-pairs).
        const int seg[6] = {0, 48, 64, 88, 120, NBLK};
        for (int s = 0; s < 5; ++s) {
            int c0 = seg[s], c1 = seg[s + 1];
            int p0 = c0 / 2;
            int npair = (c1 - c0) / 2;
            unsigned gy = (unsigned)(((c1 / 2 - 1) >> 1) + 1);   // 256-row chunks
            dim3 gb((unsigned)npair, gy, (unsigned)B);
            build_bitmap<<<gb, 256, 0, stream>>>(sbox, bitmap, done, p0);
            scan_nms<<<B, 256, 0, stream>>>(sbox, bitmap, out, S_g, kcnt, done, c0, c1);
        }
    } else {
        nms_kernel<<<B, 1024, 0, stream>>>(boxes, keys, out, N);
    }
}

// Round 5
// 425.140 us; speedup vs baseline: 2.0393x; 2.0393x over previous
//
#include <hip/hip_runtime.h>
#include <cmath>

typedef unsigned long long u64;

#define PRE_TOPN 12000
#define POST_TOPN 2000
#define SORTN 32768
#define TILE 8192
#define NTILE (SORTN / TILE)   // 4 tiles per batch
#define NBLK 188               // 64-bit column blocks covering 12032
#define PADN (NBLK * 64)       // 12032
// ROW-MAJOR triangular bitmap: row r stores words for col-blocks
// cb in [r/64, NBLK) contiguously at rowoff(r). Total words per batch:
#define TRI_WORDS (32 * (NBLK - 1) * NBLK + NBLK * 64)  // 1,137,024
#define MASK_WORDS 192         // 188 used, padded

__device__ __forceinline__ int rowoff(int r) {
    int rb = r >> 6;
    int q = r & 63;
    return r * NBLK - (32 * rb * (rb - 1) + q * rb);
}

// ---------------------------------------------------------------------------
// Kernel 1: decode boxes (exact fp32 op order, no FMA contraction, exp via
// double) and pack sort keys. key = (~score_bits)<<32 | idx.
// Also resets the per-batch NMS progress state (kcnt/done) for this launch.
// ---------------------------------------------------------------------------
__global__ void decode_pack(const float* __restrict__ anchors,
                            const float* __restrict__ deltas,
                            const float* __restrict__ scores,
                            float* __restrict__ boxes,
                            u64* __restrict__ keys,
                            int* __restrict__ kcnt,
                            int* __restrict__ done,
                            int N) {
#pragma clang fp contract(off)
    int n = blockIdx.x * blockDim.x + threadIdx.x;
    int b = blockIdx.y;
    if (kcnt != nullptr && blockIdx.x == 0 && threadIdx.x == 0) {
        kcnt[b] = 0;
        done[b] = 0;
    }
    if (n >= SORTN) return;
    u64* kb = keys + (size_t)b * SORTN;
    if (n < N) {
        float a0 = anchors[n * 4 + 0];
        float a1 = anchors[n * 4 + 1];
        float a2 = anchors[n * 4 + 2];
        float a3 = anchors[n * 4 + 3];
        float w = (a2 - a0) + 1.0f;
        float h = (a3 - a1) + 1.0f;
        float cx = a0 + 0.5f * w;
        float cy = a1 + 0.5f * h;
        const float* d = deltas + ((size_t)b * N + n) * 4;
        float dx = d[0], dy = d[1], dw = d[2], dh = d[3];
        float px = cx + w * dx;
        float py = cy + h * dy;
        float pw = (float)::exp((double)dw) * w;
        float ph = (float)::exp((double)dh) * h;
        float* bb = boxes + ((size_t)b * N + n) * 4;
        bb[0] = px - 0.5f * pw;
        bb[1] = py - 0.5f * ph;
        bb[2] = px + 0.5f * (pw - 2.0f);
        bb[3] = py + 0.5f * (ph - 2.0f);
        unsigned int sb = __float_as_uint(scores[(size_t)b * N + n]);
        kb[n] = ((u64)(~sb) << 32) | (u64)(unsigned int)n;
    } else {
        kb[n] = ~0ULL;
    }
}

// ---------------------------------------------------------------------------
// Hybrid bitonic sort (unchanged).
// ---------------------------------------------------------------------------
__global__ __launch_bounds__(1024) void bitonic_local_sort(u64* __restrict__ keys) {
    __shared__ u64 sk[TILE];
    int tile = blockIdx.x;
    u64* kb = keys + (size_t)tile * TILE;
    int base = (tile % NTILE) * TILE;
    for (int i = threadIdx.x; i < TILE; i += 1024) sk[i] = kb[i];
    __syncthreads();
    for (int k = 2; k <= TILE; k <<= 1) {
        for (int j = k >> 1; j > 0; j >>= 1) {
            for (int t = threadIdx.x; t < TILE / 2; t += 1024) {
                int i = ((t & ~(j - 1)) << 1) | (t & (j - 1));
                int ixj = i | j;
                u64 a = sk[i];
                u64 c = sk[ixj];
                bool up = (((base + i) & k) == 0);
                if ((a > c) == up) { sk[i] = c; sk[ixj] = a; }
            }
            __syncthreads();
        }
    }
    for (int i = threadIdx.x; i < TILE; i += 1024) kb[i] = sk[i];
}

__global__ void bitonic_global_step(u64* __restrict__ keys, int k, int j) {
    int t = blockIdx.x * blockDim.x + threadIdx.x;
    int b = t / (SORTN / 2);
    int s = t % (SORTN / 2);
    int i = ((s & ~(j - 1)) << 1) | (s & (j - 1));
    int ixj = i | j;
    u64* kb = keys + (size_t)b * SORTN;
    u64 a = kb[i];
    u64 c = kb[ixj];
    bool up = ((i & k) == 0);
    if ((a > c) == up) { kb[i] = c; kb[ixj] = a; }
}

__global__ __launch_bounds__(1024) void bitonic_local_merge(u64* __restrict__ keys, int k) {
    __shared__ u64 sk[TILE];
    int tile = blockIdx.x;
    u64* kb = keys + (size_t)tile * TILE;
    int base = (tile % NTILE) * TILE;
    bool up = ((base & k) == 0);
    for (int i = threadIdx.x; i < TILE; i += 1024) sk[i] = kb[i];
    __syncthreads();
    for (int j = TILE / 2; j > 0; j >>= 1) {
        for (int t = threadIdx.x; t < TILE / 2; t += 1024) {
            int i = ((t & ~(j - 1)) << 1) | (t & (j - 1));
            int ixj = i | j;
            u64 a = sk[i];
            u64 c = sk[ixj];
            if ((a > c) == up) { sk[i] = c; sk[ixj] = a; }
        }
        __syncthreads();
    }
    for (int i = threadIdx.x; i < TILE; i += 1024) kb[i] = sk[i];
}

// ---------------------------------------------------------------------------
// Gather sorted top-PADN boxes. Pad rows get far-away degenerate boxes.
// ---------------------------------------------------------------------------
__global__ void gather_sorted(const float* __restrict__ boxes,
                              const u64* __restrict__ keys,
                              float4* __restrict__ sbox, int N) {
    int r = blockIdx.x * 256 + threadIdx.x;
    int b = blockIdx.y;
    if (r >= PADN) return;
    float4 v;
    if (r < PRE_TOPN) {
        u64 key = keys[(size_t)b * SORTN + r];
        int n = (int)(unsigned)(key & 0xffffffffULL);
        v = ((const float4*)boxes)[(size_t)b * N + n];
    } else {
        v = make_float4(-4e8f, -4e8f, -4e8f, -4e8f);
    }
    sbox[(size_t)b * PADN + r] = v;
}

// ---------------------------------------------------------------------------
// Exact-f32 suppression predicate (bit-identical to the f64 reference test).
// ---------------------------------------------------------------------------
__device__ __forceinline__ void iou_bit(float4 me, float ar, float4 cj, float aj,
                                        int j, unsigned& lo, unsigned& hi, int& tie) {
#pragma clang fp contract(off)
    float xx1 = fmaxf(me.x, cj.x);
    float yy1 = fmaxf(me.y, cj.y);
    float xx2 = fminf(me.z, cj.z);
    float yy2 = fminf(me.w, cj.w);
    float w = fmaxf((xx2 - xx1) + 1.0f, 0.0f);
    float h = fmaxf((yy2 - yy1) + 1.0f, 0.0f);
    float inter = w * h;
    float un = (ar + aj) - inter;
    float t = __builtin_fmaf(-0.7f, un, inter);
    float u25 = un * 0x1p-25f;
    unsigned sup = (t > u25) ? 1u : 0u;
    tie |= (t == u25) ? 1 : 0;
    if (j < 32) lo |= sup << j;
    else        hi |= sup << (j - 32);
}

__device__ __attribute__((noinline)) u64 slow_word(float4 me, float ar,
                                                   const float4* cbox,
                                                   const float* carea) {
#pragma clang fp contract(off)
    const double MD = (double)0.7f + 0x1p-25;   // exact midpoint multiplier
    u64 word = 0;
    for (int j = 0; j < 64; ++j) {
        float4 cj = cbox[j];
        float aj = carea[j];
        float xx1 = fmaxf(me.x, cj.x);
        float yy1 = fmaxf(me.y, cj.y);
        float xx2 = fminf(me.z, cj.z);
        float yy2 = fminf(me.w, cj.w);
        float w = fmaxf((xx2 - xx1) + 1.0f, 0.0f);
        float h = fmaxf((yy2 - yy1) + 1.0f, 0.0f);
        float inter = w * h;
        float un = (ar + aj) - inter;
        bool sup = ((double)inter >= MD * (double)un);
        word |= ((u64)sup) << j;
    }
    return word;
}

// ---------------------------------------------------------------------------
// Build ROW-MAJOR suppression bitmap for col-block pairs [pair0, ...).
// Block = 256 rows x 2 col-blocks; thread t: cb = 2*pair + (t&1),
// rows chunk*256 + (t>>1) and +128. Word (r,cb) written at
// bitmap[rowoff(r) + cb - r/64]; lane pairs write adjacent words (16B).
// ---------------------------------------------------------------------------
__global__ __launch_bounds__(256) void build_bitmap(const float4* __restrict__ sbox,
                                                    u64* __restrict__ bitmap,
                                                    const int* __restrict__ done,
                                                    int pair0) {
    int pair = pair0 + blockIdx.x;   // covers cbs 2*pair, 2*pair+1
    int chunk = blockIdx.y;          // 256-row chunk
    int b = blockIdx.z;
    if (done[b]) return;
    if (2 * chunk > pair) return;    // chunk's first row >= (2p+2)*64 -> empty
    int tid = threadIdx.x;
    int w = tid & 1;
    int cb = pair * 2 + w;
    int lim = (cb + 1) * 64;         // rows with words in column-block cb

    __shared__ float4 cbox[2][64];
    __shared__ float carea[2][64];
    const float4* sb = sbox + (size_t)b * PADN;
    if (tid < 128) {
        int which = tid >> 6, j = tid & 63;
        float4 c4 = sb[(pair * 2 + which) * 64 + j];
        cbox[which][j] = c4;
        carea[which][j] = ((c4.z - c4.x) + 1.0f) * ((c4.w - c4.y) + 1.0f);
    }
    int rl = tid >> 1;               // 0..127
    int r1 = chunk * 256 + rl;       // <= 46*256+127 = 11903 < PADN
    int r2 = r1 + 128;               // <= 12031 < PADN
    bool a1 = (r1 < lim);
    bool a2 = (r2 < lim);
    float4 me1 = sb[r1];
    float4 me2 = sb[r2];
    float ar1 = ((me1.z - me1.x) + 1.0f) * ((me1.w - me1.y) + 1.0f);
    float ar2 = ((me2.z - me2.x) + 1.0f) * ((me2.w - me2.y) + 1.0f);
    __syncthreads();

    if (a1) {
        unsigned lo1 = 0, hi1 = 0;
        int tie1 = 0;
#pragma unroll
        for (int j = 0; j < 64; ++j) {
            iou_bit(me1, ar1, cbox[w][j], carea[w][j], j, lo1, hi1, tie1);
        }
        u64 w1 = ((u64)hi1 << 32) | lo1;
        if (__builtin_expect(tie1, 0)) w1 = slow_word(me1, ar1, cbox[w], carea[w]);
        int d1 = r1 - cb * 64;
        if (d1 >= 0) w1 &= ~((2ULL << d1) - 1ULL);   // upper triangle only
        bitmap[(size_t)b * TRI_WORDS + rowoff(r1) + (cb - (r1 >> 6))] = w1;
    }
    if (a2) {
        unsigned lo2 = 0, hi2 = 0;
        int tie2 = 0;
#pragma unroll
        for (int j = 0; j < 64; ++j) {
            iou_bit(me2, ar2, cbox[w][j], carea[w][j], j, lo2, hi2, tie2);
        }
        u64 w2 = ((u64)hi2 << 32) | lo2;
        if (__builtin_expect(tie2, 0)) w2 = slow_word(me2, ar2, cbox[w], carea[w]);
        int d2 = r2 - cb * 64;
        if (d2 >= 0) w2 &= ~((2ULL << d2) - 1ULL);
        bitmap[(size_t)b * TRI_WORDS + rowoff(r2) + (cb - (r2 >> 6))] = w2;
    }
}

// ---------------------------------------------------------------------------
// DPP all-reduce OR within a 16-lane row; wave total via readlanes.
// ---------------------------------------------------------------------------
__device__ __forceinline__ unsigned dpp_or16(unsigned v) {
    v |= (unsigned)__builtin_amdgcn_update_dpp(0, (int)v, 0xB1, 0xF, 0xF, true);   // quad_perm {1,0,3,2}
    v |= (unsigned)__builtin_amdgcn_update_dpp(0, (int)v, 0x4E, 0xF, 0xF, true);   // quad_perm {2,3,0,1}
    v |= (unsigned)__builtin_amdgcn_update_dpp(0, (int)v, 0x141, 0xF, 0xF, true);  // row_half_mirror
    v |= (unsigned)__builtin_amdgcn_update_dpp(0, (int)v, 0x140, 0xF, 0xF, true);  // row_mirror
    return v;
}

__device__ __forceinline__ unsigned wave_or_from_rows(unsigned rowred) {
    unsigned a = (unsigned)__builtin_amdgcn_readlane((int)rowred, 0) |
                 (unsigned)__builtin_amdgcn_readlane((int)rowred, 16);
    unsigned c = (unsigned)__builtin_amdgcn_readlane((int)rowred, 32) |
                 (unsigned)__builtin_amdgcn_readlane((int)rowred, 48);
    return a | c;
}

// ---------------------------------------------------------------------------
// Resumable scan, round-10: incremental suppression mask with a PIPELINED
// OR-step. s_S[cb] = OR over committed picks p (up to block cadence) of
// word(p,cb). Per iteration rb:
//   - wave0: sup = s_S[rb] | dpp_or(delta); scalar greedy; picking lanes
//     self-load word (p, rb+1) as next delta; prefetch next diag row/box.
//   - waves 1-3 (concurrently): OR the tails of block rb-1's picks into
//     s_S. Lane->column mapping (wave wv owns columns rb+1+(wv-1)*64+lane)
//     makes each pick's read a COALESCED 512B row segment; the pick loop
//     is 16/4-deep batched (independent loads in flight, one OR after) and
//     accumulates in a register, with a single exclusive-owner LDS OR at
//     the end. This replaces round-9's serial load->atomicOr per pick
//     (~900 cy HBM round-trip each) that caused the 800 us regression.
// Parity-double-buffered pick lists; one barrier per iteration. Stage-end
// cleanup (same batched structure) ORs the last block's picks before
// persisting s_S. Semantics identical to rounds 7-9.
// ---------------------------------------------------------------------------
__global__ __launch_bounds__(256) void scan_nms(const float4* __restrict__ sbox,
                                                const u64* __restrict__ bitmap,
                                                float* __restrict__ out,
                                                u64* __restrict__ S_g,
                                                int* __restrict__ kcnt,
                                                int* __restrict__ done,
                                                int rb0, int rb1) {
    int b = blockIdx.x;
    if (done[b]) return;
    int tid = threadIdx.x;
    int lane = tid & 63;
    int wv = tid >> 6;
    __shared__ u64 s_S[MASK_WORDS];        // 1.5 KB running suppression mask
    __shared__ int s_prevpicks[2][64];
    __shared__ int s_np[2];
    __shared__ int s_K;

    u64* Sg = S_g + (size_t)b * MASK_WORDS;
    int K0 = kcnt[b];
    if (tid == 0) s_K = K0;
    if (tid < 2) s_np[tid] = 0;
    if (tid < MASK_WORDS) s_S[tid] = (tid < NBLK && rb0 > 0) ? Sg[tid] : 0ULL;

    const u64* bm = bitmap + (size_t)b * TRI_WORDS;
    const float4* sbb = sbox + (size_t)b * PADN;

    // prologue: diag row + box for rb0 (wave0)
    u64 myrow = 0, delta = 0;
    float4 mybox = make_float4(0.f, 0.f, 0.f, 0.f);
    if (wv == 0) {
        int r = rb0 * 64 + lane;
        myrow = bm[rowoff(r)];             // word (r, rb0): diagonal
        mybox = sbb[r];
    }
    __syncthreads();

    int rb = rb0;
    for (; rb < rb1; ++rb) {
        int K = s_K;                       // uniform (post-barrier)
        if (K >= POST_TOPN) break;
        int base = rb * 64;
        bool havenext = (rb + 1 < rb1);
        int pq = (rb + 1) & 1;             // parity of block rb-1

        if (wv == 0) {
            // early prefetch of next diagonal row+box (independent of picks)
            u64 nrow = 0;
            float4 nbox = make_float4(0.f, 0.f, 0.f, 0.f);
            if (havenext) {
                int rn = (rb + 1) * 64 + lane;
                nrow = bm[rowoff(rn)];
                nbox = sbb[rn];
            }
            // delta reduce: picks of rb-1 suppression into cb=rb
            unsigned rlo = dpp_or16((unsigned)(delta & 0xffffffffULL));
            unsigned rhi = dpp_or16((unsigned)(delta >> 32));
            u64 dtot = ((u64)wave_or_from_rows(rhi) << 32) | wave_or_from_rows(rlo);
            u64 t4 = s_S[rb] | dtot;
            if (rb == NBLK - 1) t4 |= 0xFFFFFFFF00000000ULL;   // pad rows >= 12000
            unsigned tlo = (unsigned)__builtin_amdgcn_readfirstlane((int)(t4 & 0xffffffffULL));
            unsigned thi = (unsigned)__builtin_amdgcn_readfirstlane((int)(t4 >> 32));
            u64 alive = ~(((u64)thi << 32) | tlo);
            int mrl = (int)(myrow & 0xffffffffULL);
            int mrh = (int)(myrow >> 32);
            u64 picks = 0;
            u64 cur = alive;
            while (cur) {
                int i = (int)__builtin_ctzll(cur);
                picks |= 1ULL << i;
                unsigned rl = (unsigned)__builtin_amdgcn_readlane(mrl, i);
                unsigned rh = (unsigned)__builtin_amdgcn_readlane(mrh, i);
                u64 row = ((u64)rh << 32) | rl;
                alive &= ~row;
                cur = alive & ~((2ULL << i) - 1ULL);
            }
            int avail = POST_TOPN - K;
            int np = __popcll(picks);
            while (np > avail) {                       // truncate latest picks
                picks &= ~(1ULL << (63 - __clzll(picks)));
                --np;
            }
            int c = lane;
            bool ipick = ((picks >> c) & 1ULL) != 0;
            delta = 0;
            if (ipick) {
                int rank = __popcll(picks & ((1ULL << c) - 1ULL));
                int p = base + c;
                s_prevpicks[rb & 1][rank] = p;
                float* o = out + ((size_t)b * POST_TOPN + K + rank) * 5;
                o[0] = (float)b; o[1] = mybox.x; o[2] = mybox.y; o[3] = mybox.z; o[4] = mybox.w;
                if (havenext) delta = bm[rowoff(p) + 1];   // word (p, rb+1)
            }
            if (c == 0) {
                s_K = K + np;
                s_np[rb & 1] = np;
            }
            myrow = nrow; mybox = nbox;
        } else {
            // Pipelined OR-step: tails of block rb-1's picks.
            int npp = s_np[pq];
            if (npp > 0) {
                const int* pp = s_prevpicks[pq];
                int st = (wv - 1) * 64 + lane;     // 0..191 tail col offset
                int col = rb + 1 + st;
                bool act = (col < NBLK);
                int off = 2 + st;                  // word offset from rowoff(p)
                u64 acc = 0;
                int q = 0;
                for (; q + 15 < npp; q += 16) {
                    u64 t0  = act ? bm[rowoff(pp[q + 0])  + off] : 0;
                    u64 t1  = act ? bm[rowoff(pp[q + 1])  + off] : 0;
                    u64 t2  = act ? bm[rowoff(pp[q + 2])  + off] : 0;
                    u64 t3  = act ? bm[rowoff(pp[q + 3])  + off] : 0;
                    u64 t4_ = act ? bm[rowoff(pp[q + 4])  + off] : 0;
                    u64 t5  = act ? bm[rowoff(pp[q + 5])  + off] : 0;
                    u64 t6  = act ? bm[rowoff(pp[q + 6])  + off] : 0;
                    u64 t7  = act ? bm[rowoff(pp[q + 7])  + off] : 0;
                    u64 t8  = act ? bm[rowoff(pp[q + 8])  + off] : 0;
                    u64 t9  = act ? bm[rowoff(pp[q + 9])  + off] : 0;
                    u64 t10 = act ? bm[rowoff(pp[q + 10]) + off] : 0;
                    u64 t11 = act ? bm[rowoff(pp[q + 11]) + off] : 0;
                    u64 t12 = act ? bm[rowoff(pp[q + 12]) + off] : 0;
                    u64 t13 = act ? bm[rowoff(pp[q + 13]) + off] : 0;
                    u64 t14 = act ? bm[rowoff(pp[q + 14]) + off] : 0;
                    u64 t15 = act ? bm[rowoff(pp[q + 15]) + off] : 0;
                    acc |= (((t0 | t1) | (t2 | t3)) | ((t4_ | t5) | (t6 | t7))) |
                           (((t8 | t9) | (t10 | t11)) | ((t12 | t13) | (t14 | t15)));
                }
                for (; q + 3 < npp; q += 4) {
                    u64 t0 = act ? bm[rowoff(pp[q + 0]) + off] : 0;
                    u64 t1 = act ? bm[rowoff(pp[q + 1]) + off] : 0;
                    u64 t2 = act ? bm[rowoff(pp[q + 2]) + off] : 0;
                    u64 t3 = act ? bm[rowoff(pp[q + 3]) + off] : 0;
                    acc |= (t0 | t1) | (t2 | t3);
                }
                for (; q < npp; ++q) {
                    acc |= act ? bm[rowoff(pp[q]) + off] : 0;
                }
                if (act && acc) s_S[col] |= acc;   // exclusive column owner
            }
        }
        __syncthreads();
    }

    int K = s_K;
    bool finished = (K >= POST_TOPN) || (rb1 >= NBLK);
    if (!finished) {
        // cleanup: OR tails (cb >= rb1) of block rb1-1's picks, persist S.
        // Waves stride picks, lanes stride columns; atomicOr merges waves.
        int pq = (rb1 - 1) & 1;
        int npp = s_np[pq];
        int len = NBLK - rb1;
        for (int q = wv; q < npp; q += 4) {
            int p = s_prevpicks[pq][q];
            int ro = rowoff(p) + 1;
            for (int seg = lane; seg < len; seg += 64) {
                u64 wq = bm[ro + seg];
                if (wq) atomicOr(&s_S[rb1 + seg], wq);
            }
        }
        __syncthreads();
        if (tid < NBLK) Sg[tid] = s_S[tid];
    } else {
        for (int r = K + tid; r < POST_TOPN; r += 256) {
            float* o = out + ((size_t)b * POST_TOPN + r) * 5;
            o[0] = 0.0f; o[1] = 0.0f; o[2] = 0.0f; o[3] = 0.0f; o[4] = 0.0f;
        }
        if (tid == 0) done[b] = 1;
    }
    if (tid == 0) kcnt[b] = K;
}

// ---------------------------------------------------------------------------
// Fallback (round-2) NMS kernel — used only if ws_size can't hold the bitmap.
// ---------------------------------------------------------------------------
__global__ __launch_bounds__(1024) void nms_kernel(const float* __restrict__ boxes,
                                                   const u64* __restrict__ keys,
                                                   float* __restrict__ out,
                                                   int N) {
#pragma clang fp contract(off)
    __shared__ float4 kbox[POST_TOPN];
    __shared__ float kar[POST_TOPN];
    __shared__ float4 cbox[64];
    __shared__ float car_s[64];
    __shared__ int supp[64];
    __shared__ int s_cnt;

    int b = blockIdx.x;
    int tid = threadIdx.x;
    const u64* kb = keys + (size_t)b * SORTN;
    const float* bb = boxes + (size_t)b * N * 4;

    if (tid == 0) s_cnt = 0;
    __syncthreads();

    for (int start = 0; start < PRE_TOPN; start += 64) {
        int K = s_cnt;
        if (K >= POST_TOPN) break;
        int csize = min(64, PRE_TOPN - start);

        if (tid < 64) {
            int c = tid;
            if (c < csize) {
                u64 key = kb[start + c];
                int n = (int)(unsigned int)(key & 0xFFFFFFFFULL);
                const float* p = bb + (size_t)n * 4;
                float x1 = p[0], y1 = p[1], x2 = p[2], y2 = p[3];
                cbox[c] = make_float4(x1, y1, x2, y2);
                car_s[c] = ((x2 - x1) + 1.0f) * ((y2 - y1) + 1.0f);
            }
            supp[c] = 0;
        }
        __syncthreads();

        {
            int c = tid & 63;
            int sl = tid >> 6;
            if (c < csize) {
                float4 me = cbox[c];
                float ar = car_s[c];
                int flag = 0;
                for (int kk = sl; kk < K; kk += 16) {
                    float4 k0 = kbox[kk];
                    float a0 = kar[kk];
                    float xx1 = fmaxf(k0.x, me.x);
                    float yy1 = fmaxf(k0.y, me.y);
                    float xx2 = fminf(k0.z, me.z);
                    float yy2 = fminf(k0.w, me.w);
                    float w0 = fmaxf((xx2 - xx1) + 1.0f, 0.0f);
                    float h0 = fmaxf((yy2 - yy1) + 1.0f, 0.0f);
                    float inter0 = w0 * h0;
                    float iou0 = inter0 / ((a0 + ar) - inter0);
                    if (iou0 > 0.7f) { flag = 1; break; }
                }
                if (flag) supp[c] = 1;
            }
        }
        __syncthreads();

        if (tid < 64) {
            int c = tid;
            bool alive = (c < csize) && (supp[c] == 0);
            float4 me = cbox[c];
            float ar = car_s[c];
            int cnt = K;
            u64 m = __ballot(alive);
            while (m != 0 && cnt < POST_TOPN) {
                int i = __ffsll((unsigned long long)m) - 1;
                float ix1 = __shfl(me.x, i);
                float iy1 = __shfl(me.y, i);
                float ix2 = __shfl(me.z, i);
                float iy2 = __shfl(me.w, i);
                float iar = __shfl(ar, i);
                if (c == i) {
                    kbox[cnt] = me;
                    kar[cnt] = ar;
                    float* o = out + ((size_t)b * POST_TOPN + cnt) * 5;
                    o[0] = (float)b; o[1] = me.x; o[2] = me.y; o[3] = me.z; o[4] = me.w;
                }
                if (alive && c > i) {
                    float xx1 = fmaxf(ix1, me.x);
                    float yy1 = fmaxf(iy1, me.y);
                    float xx2 = fminf(ix2, me.z);
                    float yy2 = fminf(iy2, me.w);
                    float w = fmaxf((xx2 - xx1) + 1.0f, 0.0f);
                    float h = fmaxf((yy2 - yy1) + 1.0f, 0.0f);
                    float inter = w * h;
                    float iou = inter / ((iar + ar) - inter);
                    if (iou > 0.7f) alive = false;
                }
                cnt++;
                m = __ballot(alive);
                u64 clearmask = (2ULL << i) - 1ULL;
                m &= ~clearmask;
            }
            if (c == 0) s_cnt = cnt;
        }
        __syncthreads();
    }

    __syncthreads();
    int K = s_cnt;
    for (int r = K + tid; r < POST_TOPN; r += (int)blockDim.x) {
        float* o = out + ((size_t)b * POST_TOPN + r) * 5;
        o[0] = 0.0f; o[1] = 0.0f; o[2] = 0.0f; o[3] = 0.0f; o[4] = 0.0f;
    }
}

// ---------------------------------------------------------------------------
extern "C" void kernel_launch(void* const* d_in, const int* in_sizes, int n_in,
                              void* d_out, int out_size, void* d_ws, size_t ws_size,
                              hipStream_t stream) {
    const float* anchors = (const float*)d_in[0];
    const float* deltas  = (const float*)d_in[1];
    const float* scores  = (const float*)d_in[2];
    float* out = (float*)d_out;

    int N = in_sizes[0] / 4;           // 27380
    int B = in_sizes[2] / N;           // 8

    size_t off = 0;
    auto take = [&](size_t bytes) { size_t o = off; off = (off + bytes + 255) & ~(size_t)255; return o; };
    size_t boxesOff  = take((size_t)B * N * 4 * sizeof(float));
    size_t keysOff   = take((size_t)B * SORTN * sizeof(u64));
    size_t sboxOff   = take((size_t)B * PADN * sizeof(float4));
    size_t bitmapOff = take((size_t)B * TRI_WORDS * sizeof(u64));
    size_t SgOff     = take((size_t)B * MASK_WORDS * sizeof(u64));
    size_t kcntOff   = take((size_t)B * sizeof(int));
    size_t doneOff   = take((size_t)B * sizeof(int));
    bool bitmap_path = (off <= ws_size);

    float* boxes = (float*)((char*)d_ws + boxesOff);
    u64*   keys  = (u64*)((char*)d_ws + keysOff);
    u64* S_g     = bitmap_path ? (u64*)((char*)d_ws + SgOff)   : nullptr;
    int* kcnt    = bitmap_path ? (int*)((char*)d_ws + kcntOff) : nullptr;
    int* done    = bitmap_path ? (int*)((char*)d_ws + doneOff) : nullptr;

    dim3 g1((unsigned)((SORTN + 255) / 256), (unsigned)B);
    decode_pack<<<g1, 256, 0, stream>>>(anchors, deltas, scores, boxes, keys, kcnt, done, N);

    int ntiles = B * NTILE;
    bitonic_local_sort<<<ntiles, 1024, 0, stream>>>(keys);
    int gsteps = B * (SORTN / 2) / 256;
    bitonic_global_step<<<gsteps, 256, 0, stream>>>(keys, 2 * TILE, TILE);
    bitonic_local_merge<<<ntiles, 1024, 0, stream>>>(keys, 2 * TILE);
    bitonic_global_step<<<gsteps, 256, 0, stream>>>(keys, 4 * TILE, 2 * TILE);
    bitonic_global_step<<<gsteps, 256, 0, stream>>>(keys, 4 * TILE, TILE);
    bitonic_local_merge<<<ntiles, 1024, 0, stream>>>(keys, 4 * TILE);

    if (bitmap_path) {
        float4* sbox = (float4*)((char*)d_ws + sboxOff);
        u64* bitmap  = (u64*)((char*)d_ws + bitmapOff);
        dim3 gg((unsigned)((PADN + 255) / 256), (unsigned)B);
        gather_sorted<<<gg, 256, 0, stream>>>(boxes, keys, sbox, N);

        // Progressive build/scan with per-batch done[] cutoff. Segments in
        // col-block units (all even, so they split into whole cb-pairs).
        const int seg[6] = {0, 48, 64, 88, 120, NBLK};
        for (int s = 0; s < 5; ++s) {
            int c0 = seg[s], c1 = seg[s + 1];
            int p0 = c0 / 2;
            int npair = (c1 - c0) / 2;
            unsigned gy = (unsigned)(((c1 / 2 - 1) >> 1) + 1);   // 256-row chunks
            dim3 gb((unsigned)npair, gy, (unsigned)B);
            build_bitmap<<<gb, 256, 0, stream>>>(sbox, bitmap, done, p0);
            scan_nms<<<B, 256, 0, stream>>>(sbox, bitmap, out, S_g, kcnt, done, c0, c1);
        }
    } else {
        nms_kernel<<<B, 1024, 0, stream>>>(boxes, keys, out, N);
    }
}

// Round 6
// 336.025 us; speedup vs baseline: 2.5802x; 1.2652x over previous
//
#include <hip/hip_runtime.h>
#include <cmath>

typedef unsigned long long u64;

#define PRE_TOPN 12000
#define POST_TOPN 2000
#define SORTN 32768
#define TILE 8192
#define NTILE (SORTN / TILE)   // 4 tiles per batch
#define NBLK 188               // 64-bit column blocks covering 12032
#define PADN (NBLK * 64)       // 12032
// ROW-MAJOR triangular bitmap: row r stores words for col-blocks
// cb in [r/64, NBLK) contiguously at rowoff(r). Total words per batch:
#define TRI_WORDS (32 * (NBLK - 1) * NBLK + NBLK * 64)  // 1,137,024
#define MASK_WORDS 192         // 188 used, padded

__device__ __forceinline__ int rowoff(int r) {
    int rb = r >> 6;
    int q = r & 63;
    return r * NBLK - (32 * rb * (rb - 1) + q * rb);
}

// ---------------------------------------------------------------------------
// Kernel 1: decode boxes (exact fp32 op order, no FMA contraction, exp via
// double) and pack sort keys. key = (~score_bits)<<32 | idx.
// Also resets the per-batch NMS progress state (kcnt/done) for this launch.
// ---------------------------------------------------------------------------
__global__ void decode_pack(const float* __restrict__ anchors,
                            const float* __restrict__ deltas,
                            const float* __restrict__ scores,
                            float* __restrict__ boxes,
                            u64* __restrict__ keys,
                            int* __restrict__ kcnt,
                            int* __restrict__ done,
                            int N) {
#pragma clang fp contract(off)
    int n = blockIdx.x * blockDim.x + threadIdx.x;
    int b = blockIdx.y;
    if (kcnt != nullptr && blockIdx.x == 0 && threadIdx.x == 0) {
        kcnt[b] = 0;
        done[b] = 0;
    }
    if (n >= SORTN) return;
    u64* kb = keys + (size_t)b * SORTN;
    if (n < N) {
        float a0 = anchors[n * 4 + 0];
        float a1 = anchors[n * 4 + 1];
        float a2 = anchors[n * 4 + 2];
        float a3 = anchors[n * 4 + 3];
        float w = (a2 - a0) + 1.0f;
        float h = (a3 - a1) + 1.0f;
        float cx = a0 + 0.5f * w;
        float cy = a1 + 0.5f * h;
        const float* d = deltas + ((size_t)b * N + n) * 4;
        float dx = d[0], dy = d[1], dw = d[2], dh = d[3];
        float px = cx + w * dx;
        float py = cy + h * dy;
        float pw = (float)::exp((double)dw) * w;
        float ph = (float)::exp((double)dh) * h;
        float* bb = boxes + ((size_t)b * N + n) * 4;
        bb[0] = px - 0.5f * pw;
        bb[1] = py - 0.5f * ph;
        bb[2] = px + 0.5f * (pw - 2.0f);
        bb[3] = py + 0.5f * (ph - 2.0f);
        unsigned int sb = __float_as_uint(scores[(size_t)b * N + n]);
        kb[n] = ((u64)(~sb) << 32) | (u64)(unsigned int)n;
    } else {
        kb[n] = ~0ULL;
    }
}

// ---------------------------------------------------------------------------
// Hybrid bitonic sort (unchanged).
// ---------------------------------------------------------------------------
__global__ __launch_bounds__(1024) void bitonic_local_sort(u64* __restrict__ keys) {
    __shared__ u64 sk[TILE];
    int tile = blockIdx.x;
    u64* kb = keys + (size_t)tile * TILE;
    int base = (tile % NTILE) * TILE;
    for (int i = threadIdx.x; i < TILE; i += 1024) sk[i] = kb[i];
    __syncthreads();
    for (int k = 2; k <= TILE; k <<= 1) {
        for (int j = k >> 1; j > 0; j >>= 1) {
            for (int t = threadIdx.x; t < TILE / 2; t += 1024) {
                int i = ((t & ~(j - 1)) << 1) | (t & (j - 1));
                int ixj = i | j;
                u64 a = sk[i];
                u64 c = sk[ixj];
                bool up = (((base + i) & k) == 0);
                if ((a > c) == up) { sk[i] = c; sk[ixj] = a; }
            }
            __syncthreads();
        }
    }
    for (int i = threadIdx.x; i < TILE; i += 1024) kb[i] = sk[i];
}

__global__ void bitonic_global_step(u64* __restrict__ keys, int k, int j) {
    int t = blockIdx.x * blockDim.x + threadIdx.x;
    int b = t / (SORTN / 2);
    int s = t % (SORTN / 2);
    int i = ((s & ~(j - 1)) << 1) | (s & (j - 1));
    int ixj = i | j;
    u64* kb = keys + (size_t)b * SORTN;
    u64 a = kb[i];
    u64 c = kb[ixj];
    bool up = ((i & k) == 0);
    if ((a > c) == up) { kb[i] = c; kb[ixj] = a; }
}

__global__ __launch_bounds__(1024) void bitonic_local_merge(u64* __restrict__ keys, int k) {
    __shared__ u64 sk[TILE];
    int tile = blockIdx.x;
    u64* kb = keys + (size_t)tile * TILE;
    int base = (tile % NTILE) * TILE;
    bool up = ((base & k) == 0);
    for (int i = threadIdx.x; i < TILE; i += 1024) sk[i] = kb[i];
    __syncthreads();
    for (int j = TILE / 2; j > 0; j >>= 1) {
        for (int t = threadIdx.x; t < TILE / 2; t += 1024) {
            int i = ((t & ~(j - 1)) << 1) | (t & (j - 1));
            int ixj = i | j;
            u64 a = sk[i];
            u64 c = sk[ixj];
            if ((a > c) == up) { sk[i] = c; sk[ixj] = a; }
        }
        __syncthreads();
    }
    for (int i = threadIdx.x; i < TILE; i += 1024) kb[i] = sk[i];
}

// ---------------------------------------------------------------------------
// Gather sorted top-PADN boxes. Pad rows get far-away degenerate boxes.
// ---------------------------------------------------------------------------
__global__ void gather_sorted(const float* __restrict__ boxes,
                              const u64* __restrict__ keys,
                              float4* __restrict__ sbox, int N) {
    int r = blockIdx.x * 256 + threadIdx.x;
    int b = blockIdx.y;
    if (r >= PADN) return;
    float4 v;
    if (r < PRE_TOPN) {
        u64 key = keys[(size_t)b * SORTN + r];
        int n = (int)(unsigned)(key & 0xffffffffULL);
        v = ((const float4*)boxes)[(size_t)b * N + n];
    } else {
        v = make_float4(-4e8f, -4e8f, -4e8f, -4e8f);
    }
    sbox[(size_t)b * PADN + r] = v;
}

// ---------------------------------------------------------------------------
// Exact-f32 suppression predicate (bit-identical to the f64 reference test).
// ---------------------------------------------------------------------------
__device__ __forceinline__ void iou_bit(float4 me, float ar, float4 cj, float aj,
                                        int j, unsigned& lo, unsigned& hi, int& tie) {
#pragma clang fp contract(off)
    float xx1 = fmaxf(me.x, cj.x);
    float yy1 = fmaxf(me.y, cj.y);
    float xx2 = fminf(me.z, cj.z);
    float yy2 = fminf(me.w, cj.w);
    float w = fmaxf((xx2 - xx1) + 1.0f, 0.0f);
    float h = fmaxf((yy2 - yy1) + 1.0f, 0.0f);
    float inter = w * h;
    float un = (ar + aj) - inter;
    float t = __builtin_fmaf(-0.7f, un, inter);
    float u25 = un * 0x1p-25f;
    unsigned sup = (t > u25) ? 1u : 0u;
    tie |= (t == u25) ? 1 : 0;
    if (j < 32) lo |= sup << j;
    else        hi |= sup << (j - 32);
}

__device__ __attribute__((noinline)) u64 slow_word(float4 me, float ar,
                                                   const float4* cbox,
                                                   const float* carea) {
#pragma clang fp contract(off)
    const double MD = (double)0.7f + 0x1p-25;   // exact midpoint multiplier
    u64 word = 0;
    for (int j = 0; j < 64; ++j) {
        float4 cj = cbox[j];
        float aj = carea[j];
        float xx1 = fmaxf(me.x, cj.x);
        float yy1 = fmaxf(me.y, cj.y);
        float xx2 = fminf(me.z, cj.z);
        float yy2 = fminf(me.w, cj.w);
        float w = fmaxf((xx2 - xx1) + 1.0f, 0.0f);
        float h = fmaxf((yy2 - yy1) + 1.0f, 0.0f);
        float inter = w * h;
        float un = (ar + aj) - inter;
        bool sup = ((double)inter >= MD * (double)un);
        word |= ((u64)sup) << j;
    }
    return word;
}

// ---------------------------------------------------------------------------
// Build ROW-MAJOR suppression bitmap for col-block pairs [pair0, ...).
// (unchanged from round 5)
// ---------------------------------------------------------------------------
__global__ __launch_bounds__(256) void build_bitmap(const float4* __restrict__ sbox,
                                                    u64* __restrict__ bitmap,
                                                    const int* __restrict__ done,
                                                    int pair0) {
    int pair = pair0 + blockIdx.x;   // covers cbs 2*pair, 2*pair+1
    int chunk = blockIdx.y;          // 256-row chunk
    int b = blockIdx.z;
    if (done[b]) return;
    if (2 * chunk > pair) return;    // chunk's first row >= (2p+2)*64 -> empty
    int tid = threadIdx.x;
    int w = tid & 1;
    int cb = pair * 2 + w;
    int lim = (cb + 1) * 64;         // rows with words in column-block cb

    __shared__ float4 cbox[2][64];
    __shared__ float carea[2][64];
    const float4* sb = sbox + (size_t)b * PADN;
    if (tid < 128) {
        int which = tid >> 6, j = tid & 63;
        float4 c4 = sb[(pair * 2 + which) * 64 + j];
        cbox[which][j] = c4;
        carea[which][j] = ((c4.z - c4.x) + 1.0f) * ((c4.w - c4.y) + 1.0f);
    }
    int rl = tid >> 1;               // 0..127
    int r1 = chunk * 256 + rl;       // <= 46*256+127 = 11903 < PADN
    int r2 = r1 + 128;               // <= 12031 < PADN
    bool a1 = (r1 < lim);
    bool a2 = (r2 < lim);
    float4 me1 = sb[r1];
    float4 me2 = sb[r2];
    float ar1 = ((me1.z - me1.x) + 1.0f) * ((me1.w - me1.y) + 1.0f);
    float ar2 = ((me2.z - me2.x) + 1.0f) * ((me2.w - me2.y) + 1.0f);
    __syncthreads();

    if (a1) {
        unsigned lo1 = 0, hi1 = 0;
        int tie1 = 0;
#pragma unroll
        for (int j = 0; j < 64; ++j) {
            iou_bit(me1, ar1, cbox[w][j], carea[w][j], j, lo1, hi1, tie1);
        }
        u64 w1 = ((u64)hi1 << 32) | lo1;
        if (__builtin_expect(tie1, 0)) w1 = slow_word(me1, ar1, cbox[w], carea[w]);
        int d1 = r1 - cb * 64;
        if (d1 >= 0) w1 &= ~((2ULL << d1) - 1ULL);   // upper triangle only
        bitmap[(size_t)b * TRI_WORDS + rowoff(r1) + (cb - (r1 >> 6))] = w1;
    }
    if (a2) {
        unsigned lo2 = 0, hi2 = 0;
        int tie2 = 0;
#pragma unroll
        for (int j = 0; j < 64; ++j) {
            iou_bit(me2, ar2, cbox[w][j], carea[w][j], j, lo2, hi2, tie2);
        }
        u64 w2 = ((u64)hi2 << 32) | lo2;
        if (__builtin_expect(tie2, 0)) w2 = slow_word(me2, ar2, cbox[w], carea[w]);
        int d2 = r2 - cb * 64;
        if (d2 >= 0) w2 &= ~((2ULL << d2) - 1ULL);
        bitmap[(size_t)b * TRI_WORDS + rowoff(r2) + (cb - (r2 >> 6))] = w2;
    }
}

// ---------------------------------------------------------------------------
// DPP all-reduce OR within a 16-lane row; wave total via readlanes.
// ---------------------------------------------------------------------------
__device__ __forceinline__ unsigned dpp_or16(unsigned v) {
    v |= (unsigned)__builtin_amdgcn_update_dpp(0, (int)v, 0xB1, 0xF, 0xF, true);   // quad_perm {1,0,3,2}
    v |= (unsigned)__builtin_amdgcn_update_dpp(0, (int)v, 0x4E, 0xF, 0xF, true);   // quad_perm {2,3,0,1}
    v |= (unsigned)__builtin_amdgcn_update_dpp(0, (int)v, 0x141, 0xF, 0xF, true);  // row_half_mirror
    v |= (unsigned)__builtin_amdgcn_update_dpp(0, (int)v, 0x140, 0xF, 0xF, true);  // row_mirror
    return v;
}

__device__ __forceinline__ unsigned wave_or_from_rows(unsigned rowred) {
    unsigned a = (unsigned)__builtin_amdgcn_readlane((int)rowred, 0) |
                 (unsigned)__builtin_amdgcn_readlane((int)rowred, 16);
    unsigned c = (unsigned)__builtin_amdgcn_readlane((int)rowred, 32) |
                 (unsigned)__builtin_amdgcn_readlane((int)rowred, 48);
    return a | c;
}

// ---------------------------------------------------------------------------
// Resumable scan, round-11. 1024 threads (16 waves). Invariant: after stage
// [rb0,rb1), s_S[cb] is complete for cb < rb1 (no reads of unbuilt columns —
// fixes the round-9/10 stale-workspace dependence).
//  - stage prologue CATCH-UP: OR word(p,cb) over all K0 prior picks (from
//    picks_g) for the newly built cols [rb0,rb1). 2D (pick x segment) over
//    15 waves, 8-deep idempotent-clamped batches.
//  - per iter rb: wave0 = reduce(s_S[rb] | delta) + scalar greedy + delta
//    self-load (col rb+1); waves 1-15 = OR-step over picks of rb-1 into
//    cols [rb+1, rb1): wave w owns col-segment (w-1)%3 and pick-stripe
//    (w-1)/3 (stride 5) -> ~npp/5 loads per wave, ONE 8-deep batch (clamped
//    duplicate loads are safe: OR is idempotent) -> one latency exposure.
//  - one barrier per iteration; parity-double-buffered pick lists.
// Semantics identical to rounds 7-10.
// ---------------------------------------------------------------------------
__global__ __launch_bounds__(1024) void scan_nms(const float4* __restrict__ sbox,
                                                 const u64* __restrict__ bitmap,
                                                 float* __restrict__ out,
                                                 u64* __restrict__ S_g,
                                                 int* __restrict__ picks_g,
                                                 int* __restrict__ kcnt,
                                                 int* __restrict__ done,
                                                 int rb0, int rb1) {
    int b = blockIdx.x;
    if (done[b]) return;
    int tid = threadIdx.x;
    int lane = tid & 63;
    int wv = tid >> 6;                     // 0..15
    __shared__ u64 s_S[MASK_WORDS];        // 1.5 KB running suppression mask
    __shared__ int s_pp[POST_TOPN];        // 8 KB committed pick rows
    __shared__ int s_prevpicks[2][64];
    __shared__ int s_np[2];
    __shared__ int s_K;

    u64* Sg = S_g + (size_t)b * MASK_WORDS;
    int* pg = picks_g + (size_t)b * POST_TOPN;
    int K0 = kcnt[b];
    if (tid == 0) s_K = K0;
    if (tid < 2) s_np[tid] = 0;
    if (tid < MASK_WORDS) s_S[tid] = (tid < NBLK && rb0 > 0) ? Sg[tid] : 0ULL;
    for (int t = tid; t < K0; t += 1024) s_pp[t] = pg[t];
    __syncthreads();

    const u64* bm = bitmap + (size_t)b * TRI_WORDS;
    const float4* sbb = sbox + (size_t)b * PADN;

    u64 myrow = 0, delta = 0;
    float4 mybox = make_float4(0.f, 0.f, 0.f, 0.f);
    if (wv == 0) {
        // prologue diag row + box for rb0 (loads overlap others' catch-up)
        int r = rb0 * 64 + lane;
        myrow = bm[rowoff(r)];
        mybox = sbb[r];
    } else if (rb0 > 0 && K0 > 0) {
        // ---- CATCH-UP: cols [rb0, rb1) x all K0 prior picks ----
        int width = rb1 - rb0;             // <= 128 by stage construction
        int nseg2 = (width + 63) >> 6;     // 1 or 2
        int w = wv - 1;                    // 0..14
        int s2, str, nstr;
        if (nseg2 == 2) { s2 = w & 1; str = w >> 1; nstr = (s2 == 0) ? 8 : 7; }
        else            { s2 = 0;     str = w;      nstr = 15; }
        int ce = s2 * 64 + lane;
        bool act = (ce < width);
        u64 amask = act ? ~0ULL : 0ULL;
        int cb = rb0 + ce;
        int cbc = act ? cb : rb0;
        u64 acc = 0;
        int last = K0 - 1;
        for (int q = str; q < K0; q += 8 * nstr) {
            int q0 = q;
            int q1 = q + nstr;     if (q1 > last) q1 = q0;
            int q2 = q + 2 * nstr; if (q2 > last) q2 = q0;
            int q3 = q + 3 * nstr; if (q3 > last) q3 = q0;
            int q4 = q + 4 * nstr; if (q4 > last) q4 = q0;
            int q5 = q + 5 * nstr; if (q5 > last) q5 = q0;
            int q6 = q + 6 * nstr; if (q6 > last) q6 = q0;
            int q7 = q + 7 * nstr; if (q7 > last) q7 = q0;
            int p0 = s_pp[q0], p1 = s_pp[q1], p2 = s_pp[q2], p3 = s_pp[q3];
            int p4 = s_pp[q4], p5 = s_pp[q5], p6 = s_pp[q6], p7 = s_pp[q7];
            u64 v0 = bm[rowoff(p0) + (cbc - (p0 >> 6))];
            u64 v1 = bm[rowoff(p1) + (cbc - (p1 >> 6))];
            u64 v2 = bm[rowoff(p2) + (cbc - (p2 >> 6))];
            u64 v3 = bm[rowoff(p3) + (cbc - (p3 >> 6))];
            u64 v4 = bm[rowoff(p4) + (cbc - (p4 >> 6))];
            u64 v5 = bm[rowoff(p5) + (cbc - (p5 >> 6))];
            u64 v6 = bm[rowoff(p6) + (cbc - (p6 >> 6))];
            u64 v7 = bm[rowoff(p7) + (cbc - (p7 >> 6))];
            acc |= ((v0 | v1) | (v2 | v3)) | ((v4 | v5) | (v6 | v7));
        }
        acc &= amask;
        if (act && acc) atomicOr(&s_S[cb], acc);
    }
    __syncthreads();

    int rb = rb0;
    for (; rb < rb1; ++rb) {
        int K = s_K;                       // uniform (post-barrier)
        if (K >= POST_TOPN) break;
        int base = rb * 64;
        bool havenext = (rb + 1 < rb1);
        int pq = (rb + 1) & 1;             // parity of block rb-1

        if (wv == 0) {
            // early prefetch of next diagonal row+box (independent of picks)
            u64 nrow = 0;
            float4 nbox = make_float4(0.f, 0.f, 0.f, 0.f);
            if (havenext) {
                int rn = (rb + 1) * 64 + lane;
                nrow = bm[rowoff(rn)];
                nbox = sbb[rn];
            }
            // delta reduce: picks of rb-1 suppression into cb=rb
            unsigned rlo = dpp_or16((unsigned)(delta & 0xffffffffULL));
            unsigned rhi = dpp_or16((unsigned)(delta >> 32));
            u64 dtot = ((u64)wave_or_from_rows(rhi) << 32) | wave_or_from_rows(rlo);
            u64 t4 = s_S[rb] | dtot;
            if (rb == NBLK - 1) t4 |= 0xFFFFFFFF00000000ULL;   // pad rows >= 12000
            unsigned tlo = (unsigned)__builtin_amdgcn_readfirstlane((int)(t4 & 0xffffffffULL));
            unsigned thi = (unsigned)__builtin_amdgcn_readfirstlane((int)(t4 >> 32));
            u64 alive = ~(((u64)thi << 32) | tlo);
            int mrl = (int)(myrow & 0xffffffffULL);
            int mrh = (int)(myrow >> 32);
            u64 picks = 0;
            u64 cur = alive;
            while (cur) {
                int i = (int)__builtin_ctzll(cur);
                picks |= 1ULL << i;
                unsigned rl = (unsigned)__builtin_amdgcn_readlane(mrl, i);
                unsigned rh = (unsigned)__builtin_amdgcn_readlane(mrh, i);
                u64 row = ((u64)rh << 32) | rl;
                alive &= ~row;
                cur = alive & ~((2ULL << i) - 1ULL);
            }
            int avail = POST_TOPN - K;
            int np = __popcll(picks);
            while (np > avail) {                       // truncate latest picks
                picks &= ~(1ULL << (63 - __clzll(picks)));
                --np;
            }
            int c = lane;
            bool ipick = ((picks >> c) & 1ULL) != 0;
            delta = 0;
            if (ipick) {
                int rank = __popcll(picks & ((1ULL << c) - 1ULL));
                int p = base + c;
                s_prevpicks[rb & 1][rank] = p;
                pg[K + rank] = p;                      // persist pick row
                float* o = out + ((size_t)b * POST_TOPN + K + rank) * 5;
                o[0] = (float)b; o[1] = mybox.x; o[2] = mybox.y; o[3] = mybox.z; o[4] = mybox.w;
                if (havenext) delta = bm[rowoff(p) + 1];   // word (p, rb+1)
            }
            if (c == 0) {
                s_K = K + np;
                s_np[rb & 1] = np;
            }
            myrow = nrow; mybox = nbox;
        } else {
            // OR-step: tails of block rb-1's picks into cols [rb+1, rb1).
            // wave w: col-segment r=(w-1)%3, pick-stripe a=(w-1)/3 (of 5).
            int npp = s_np[pq];
            int len = rb1 - (rb + 1);
            int w = wv - 1;                   // 0..14
            int a3 = (w * 11) >> 5;           // w / 3
            int r3 = w - a3 * 3;              // w % 3
            if (npp > 0 && r3 * 64 < len) {
                const int* pp = s_prevpicks[pq];
                int ce = r3 * 64 + lane;
                bool act = (ce < len);
                u64 amask = act ? ~0ULL : 0ULL;
                int off = act ? (2 + ce) : 0;
                int last = npp - 1;
                u64 acc = 0;
                for (int q = a3; q < npp; q += 40) {
                    int q0 = q;
                    int q1 = q + 5;  if (q1 > last) q1 = q0;
                    int q2 = q + 10; if (q2 > last) q2 = q0;
                    int q3 = q + 15; if (q3 > last) q3 = q0;
                    int q4 = q + 20; if (q4 > last) q4 = q0;
                    int q5 = q + 25; if (q5 > last) q5 = q0;
                    int q6 = q + 30; if (q6 > last) q6 = q0;
                    int q7 = q + 35; if (q7 > last) q7 = q0;
                    u64 v0 = bm[rowoff(pp[q0]) + off];
                    u64 v1 = bm[rowoff(pp[q1]) + off];
                    u64 v2 = bm[rowoff(pp[q2]) + off];
                    u64 v3 = bm[rowoff(pp[q3]) + off];
                    u64 v4 = bm[rowoff(pp[q4]) + off];
                    u64 v5 = bm[rowoff(pp[q5]) + off];
                    u64 v6 = bm[rowoff(pp[q6]) + off];
                    u64 v7 = bm[rowoff(pp[q7]) + off];
                    acc |= ((v0 | v1) | (v2 | v3)) | ((v4 | v5) | (v6 | v7));
                }
                acc &= amask;
                if (act && acc) atomicOr(&s_S[rb + 1 + ce], acc);
            }
        }
        __syncthreads();
    }

    int K = s_K;
    bool finished = (K >= POST_TOPN) || (rb1 >= NBLK);
    if (finished) {
        for (int r = K + tid; r < POST_TOPN; r += 1024) {
            float* o = out + ((size_t)b * POST_TOPN + r) * 5;
            o[0] = 0.0f; o[1] = 0.0f; o[2] = 0.0f; o[3] = 0.0f; o[4] = 0.0f;
        }
        if (tid == 0) done[b] = 1;
    } else {
        // persist running mask; picks of the last block get their tail
        // (cols >= rb1) OR'd by the NEXT stage's catch-up via picks_g.
        if (tid < NBLK) Sg[tid] = s_S[tid];
    }
    if (tid == 0) kcnt[b] = K;
}

// ---------------------------------------------------------------------------
// Fallback (round-2) NMS kernel — used only if ws_size can't hold the bitmap.
// ---------------------------------------------------------------------------
__global__ __launch_bounds__(1024) void nms_kernel(const float* __restrict__ boxes,
                                                   const u64* __restrict__ keys,
                                                   float* __restrict__ out,
                                                   int N) {
#pragma clang fp contract(off)
    __shared__ float4 kbox[POST_TOPN];
    __shared__ float kar[POST_TOPN];
    __shared__ float4 cbox[64];
    __shared__ float car_s[64];
    __shared__ int supp[64];
    __shared__ int s_cnt;

    int b = blockIdx.x;
    int tid = threadIdx.x;
    const u64* kb = keys + (size_t)b * SORTN;
    const float* bb = boxes + (size_t)b * N * 4;

    if (tid == 0) s_cnt = 0;
    __syncthreads();

    for (int start = 0; start < PRE_TOPN; start += 64) {
        int K = s_cnt;
        if (K >= POST_TOPN) break;
        int csize = min(64, PRE_TOPN - start);

        if (tid < 64) {
            int c = tid;
            if (c < csize) {
                u64 key = kb[start + c];
                int n = (int)(unsigned int)(key & 0xFFFFFFFFULL);
                const float* p = bb + (size_t)n * 4;
                float x1 = p[0], y1 = p[1], x2 = p[2], y2 = p[3];
                cbox[c] = make_float4(x1, y1, x2, y2);
                car_s[c] = ((x2 - x1) + 1.0f) * ((y2 - y1) + 1.0f);
            }
            supp[c] = 0;
        }
        __syncthreads();

        {
            int c = tid & 63;
            int sl = tid >> 6;
            if (c < csize) {
                float4 me = cbox[c];
                float ar = car_s[c];
                int flag = 0;
                for (int kk = sl; kk < K; kk += 16) {
                    float4 k0 = kbox[kk];
                    float a0 = kar[kk];
                    float xx1 = fmaxf(k0.x, me.x);
                    float yy1 = fmaxf(k0.y, me.y);
                    float xx2 = fminf(k0.z, me.z);
                    float yy2 = fminf(k0.w, me.w);
                    float w0 = fmaxf((xx2 - xx1) + 1.0f, 0.0f);
                    float h0 = fmaxf((yy2 - yy1) + 1.0f, 0.0f);
                    float inter0 = w0 * h0;
                    float iou0 = inter0 / ((a0 + ar) - inter0);
                    if (iou0 > 0.7f) { flag = 1; break; }
                }
                if (flag) supp[c] = 1;
            }
        }
        __syncthreads();

        if (tid < 64) {
            int c = tid;
            bool alive = (c < csize) && (supp[c] == 0);
            float4 me = cbox[c];
            float ar = car_s[c];
            int cnt = K;
            u64 m = __ballot(alive);
            while (m != 0 && cnt < POST_TOPN) {
                int i = __ffsll((unsigned long long)m) - 1;
                float ix1 = __shfl(me.x, i);
                float iy1 = __shfl(me.y, i);
                float ix2 = __shfl(me.z, i);
                float iy2 = __shfl(me.w, i);
                float iar = __shfl(ar, i);
                if (c == i) {
                    kbox[cnt] = me;
                    kar[cnt] = ar;
                    float* o = out + ((size_t)b * POST_TOPN + cnt) * 5;
                    o[0] = (float)b; o[1] = me.x; o[2] = me.y; o[3] = me.z; o[4] = me.w;
                }
                if (alive && c > i) {
                    float xx1 = fmaxf(ix1, me.x);
                    float yy1 = fmaxf(iy1, me.y);
                    float xx2 = fminf(ix2, me.z);
                    float yy2 = fminf(iy2, me.w);
                    float w = fmaxf((xx2 - xx1) + 1.0f, 0.0f);
                    float h = fmaxf((yy2 - yy1) + 1.0f, 0.0f);
                    float inter = w * h;
                    float iou = inter / ((iar + ar) - inter);
                    if (iou > 0.7f) alive = false;
                }
                cnt++;
                m = __ballot(alive);
                u64 clearmask = (2ULL << i) - 1ULL;
                m &= ~clearmask;
            }
            if (c == 0) s_cnt = cnt;
        }
        __syncthreads();
    }

    __syncthreads();
    int K = s_cnt;
    for (int r = K + tid; r < POST_TOPN; r += (int)blockDim.x) {
        float* o = out + ((size_t)b * POST_TOPN + r) * 5;
        o[0] = 0.0f; o[1] = 0.0f; o[2] = 0.0f; o[3] = 0.0f; o[4] = 0.0f;
    }
}

// ---------------------------------------------------------------------------
extern "C" void kernel_launch(void* const* d_in, const int* in_sizes, int n_in,
                              void* d_out, int out_size, void* d_ws, size_t ws_size,
                              hipStream_t stream) {
    const float* anchors = (const float*)d_in[0];
    const float* deltas  = (const float*)d_in[1];
    const float* scores  = (const float*)d_in[2];
    float* out = (float*)d_out;

    int N = in_sizes[0] / 4;           // 27380
    int B = in_sizes[2] / N;           // 8

    size_t off = 0;
    auto take = [&](size_t bytes) { size_t o = off; off = (off + bytes + 255) & ~(size_t)255; return o; };
    size_t boxesOff  = take((size_t)B * N * 4 * sizeof(float));
    size_t keysOff   = take((size_t)B * SORTN * sizeof(u64));
    size_t sboxOff   = take((size_t)B * PADN * sizeof(float4));
    size_t bitmapOff = take((size_t)B * TRI_WORDS * sizeof(u64));
    size_t SgOff     = take((size_t)B * MASK_WORDS * sizeof(u64));
    size_t pgOff     = take((size_t)B * POST_TOPN * sizeof(int));
    size_t kcntOff   = take((size_t)B * sizeof(int));
    size_t doneOff   = take((size_t)B * sizeof(int));
    bool bitmap_path = (off <= ws_size);

    float* boxes = (float*)((char*)d_ws + boxesOff);
    u64*   keys  = (u64*)((char*)d_ws + keysOff);
    u64* S_g     = bitmap_path ? (u64*)((char*)d_ws + SgOff)   : nullptr;
    int* pg      = bitmap_path ? (int*)((char*)d_ws + pgOff)   : nullptr;
    int* kcnt    = bitmap_path ? (int*)((char*)d_ws + kcntOff) : nullptr;
    int* done    = bitmap_path ? (int*)((char*)d_ws + doneOff) : nullptr;

    dim3 g1((unsigned)((SORTN + 255) / 256), (unsigned)B);
    decode_pack<<<g1, 256, 0, stream>>>(anchors, deltas, scores, boxes, keys, kcnt, done, N);

    int ntiles = B * NTILE;
    bitonic_local_sort<<<ntiles, 1024, 0, stream>>>(keys);
    int gsteps = B * (SORTN / 2) / 256;
    bitonic_global_step<<<gsteps, 256, 0, stream>>>(keys, 2 * TILE, TILE);
    bitonic_local_merge<<<ntiles, 1024, 0, stream>>>(keys, 2 * TILE);
    bitonic_global_step<<<gsteps, 256, 0, stream>>>(keys, 4 * TILE, 2 * TILE);
    bitonic_global_step<<<gsteps, 256, 0, stream>>>(keys, 4 * TILE, TILE);
    bitonic_local_merge<<<ntiles, 1024, 0, stream>>>(keys, 4 * TILE);

    if (bitmap_path) {
        float4* sbox = (float4*)((char*)d_ws + sboxOff);
        u64* bitmap  = (u64*)((char*)d_ws + bitmapOff);
        dim3 gg((unsigned)((PADN + 255) / 256), (unsigned)B);
        gather_sorted<<<gg, 256, 0, stream>>>(boxes, keys, sbox, N);

        // Progressive build/scan with per-batch done[] cutoff. Segments in
        // col-block units (even; widths <= 128 per the catch-up's 2-segment
        // mapping).
        const int seg[6] = {0, 48, 64, 88, 120, NBLK};
        for (int s = 0; s < 5; ++s) {
            int c0 = seg[s], c1 = seg[s + 1];
            int p0 = c0 / 2;
            int npair = (c1 - c0) / 2;
            unsigned gy = (unsigned)(((c1 / 2 - 1) >> 1) + 1);   // 256-row chunks
            dim3 gb((unsigned)npair, gy, (unsigned)B);
            build_bitmap<<<gb, 256, 0, stream>>>(sbox, bitmap, done, p0);
            scan_nms<<<B, 1024, 0, stream>>>(sbox, bitmap, out, S_g, pg, kcnt, done, c0, c1);
        }
    } else {
        nms_kernel<<<B, 1024, 0, stream>>>(boxes, keys, out, N);
    }
}

// Round 7
// 335.215 us; speedup vs baseline: 2.5864x; 1.0024x over previous
//
#include <hip/hip_runtime.h>
#include <cmath>

typedef unsigned long long u64;

#define PRE_TOPN 12000
#define POST_TOPN 2000
#define SORTN 32768
#define TILE 8192
#define NTILE (SORTN / TILE)   // 4 tiles per batch
#define NBLK 188               // 64-bit column blocks covering 12032
#define PADN (NBLK * 64)       // 12032
// ROW-MAJOR triangular bitmap: row r stores words for col-blocks
// cb in [r/64, NBLK) contiguously at rowoff(r). Total words per batch:
#define TRI_WORDS (32 * (NBLK - 1) * NBLK + NBLK * 64)  // 1,137,024
#define MASK_WORDS 192         // 188 used, padded

// Light workgroup barrier: orders LDS (lgkmcnt) but lets global loads stay
// in flight across the barrier (their results are private VGPRs; the
// compiler inserts vmcnt waits at first use). HIP __syncthreads would drain
// vmcnt(0) and serially expose every end-of-iteration prefetch latency.
#define WG_SYNC() asm volatile("s_waitcnt lgkmcnt(0)\n\ts_barrier" ::: "memory")

__device__ __forceinline__ int rowoff(int r) {
    int rb = r >> 6;
    int q = r & 63;
    return r * NBLK - (32 * rb * (rb - 1) + q * rb);
}

// ---------------------------------------------------------------------------
// Kernel 1: decode boxes (exact fp32 op order, no FMA contraction, exp via
// double) and pack sort keys. key = (~score_bits)<<32 | idx.
// Also resets the per-batch NMS progress state (kcnt/done) for this launch.
// ---------------------------------------------------------------------------
__global__ void decode_pack(const float* __restrict__ anchors,
                            const float* __restrict__ deltas,
                            const float* __restrict__ scores,
                            float* __restrict__ boxes,
                            u64* __restrict__ keys,
                            int* __restrict__ kcnt,
                            int* __restrict__ done,
                            int N) {
#pragma clang fp contract(off)
    int n = blockIdx.x * blockDim.x + threadIdx.x;
    int b = blockIdx.y;
    if (kcnt != nullptr && blockIdx.x == 0 && threadIdx.x == 0) {
        kcnt[b] = 0;
        done[b] = 0;
    }
    if (n >= SORTN) return;
    u64* kb = keys + (size_t)b * SORTN;
    if (n < N) {
        float a0 = anchors[n * 4 + 0];
        float a1 = anchors[n * 4 + 1];
        float a2 = anchors[n * 4 + 2];
        float a3 = anchors[n * 4 + 3];
        float w = (a2 - a0) + 1.0f;
        float h = (a3 - a1) + 1.0f;
        float cx = a0 + 0.5f * w;
        float cy = a1 + 0.5f * h;
        const float* d = deltas + ((size_t)b * N + n) * 4;
        float dx = d[0], dy = d[1], dw = d[2], dh = d[3];
        float px = cx + w * dx;
        float py = cy + h * dy;
        float pw = (float)::exp((double)dw) * w;
        float ph = (float)::exp((double)dh) * h;
        float* bb = boxes + ((size_t)b * N + n) * 4;
        bb[0] = px - 0.5f * pw;
        bb[1] = py - 0.5f * ph;
        bb[2] = px + 0.5f * (pw - 2.0f);
        bb[3] = py + 0.5f * (ph - 2.0f);
        unsigned int sb = __float_as_uint(scores[(size_t)b * N + n]);
        kb[n] = ((u64)(~sb) << 32) | (u64)(unsigned int)n;
    } else {
        kb[n] = ~0ULL;
    }
}

// ---------------------------------------------------------------------------
// Hybrid bitonic sort (unchanged).
// ---------------------------------------------------------------------------
__global__ __launch_bounds__(1024) void bitonic_local_sort(u64* __restrict__ keys) {
    __shared__ u64 sk[TILE];
    int tile = blockIdx.x;
    u64* kb = keys + (size_t)tile * TILE;
    int base = (tile % NTILE) * TILE;
    for (int i = threadIdx.x; i < TILE; i += 1024) sk[i] = kb[i];
    __syncthreads();
    for (int k = 2; k <= TILE; k <<= 1) {
        for (int j = k >> 1; j > 0; j >>= 1) {
            for (int t = threadIdx.x; t < TILE / 2; t += 1024) {
                int i = ((t & ~(j - 1)) << 1) | (t & (j - 1));
                int ixj = i | j;
                u64 a = sk[i];
                u64 c = sk[ixj];
                bool up = (((base + i) & k) == 0);
                if ((a > c) == up) { sk[i] = c; sk[ixj] = a; }
            }
            __syncthreads();
        }
    }
    for (int i = threadIdx.x; i < TILE; i += 1024) kb[i] = sk[i];
}

__global__ void bitonic_global_step(u64* __restrict__ keys, int k, int j) {
    int t = blockIdx.x * blockDim.x + threadIdx.x;
    int b = t / (SORTN / 2);
    int s = t % (SORTN / 2);
    int i = ((s & ~(j - 1)) << 1) | (s & (j - 1));
    int ixj = i | j;
    u64* kb = keys + (size_t)b * SORTN;
    u64 a = kb[i];
    u64 c = kb[ixj];
    bool up = ((i & k) == 0);
    if ((a > c) == up) { kb[i] = c; kb[ixj] = a; }
}

__global__ __launch_bounds__(1024) void bitonic_local_merge(u64* __restrict__ keys, int k) {
    __shared__ u64 sk[TILE];
    int tile = blockIdx.x;
    u64* kb = keys + (size_t)tile * TILE;
    int base = (tile % NTILE) * TILE;
    bool up = ((base & k) == 0);
    for (int i = threadIdx.x; i < TILE; i += 1024) sk[i] = kb[i];
    __syncthreads();
    for (int j = TILE / 2; j > 0; j >>= 1) {
        for (int t = threadIdx.x; t < TILE / 2; t += 1024) {
            int i = ((t & ~(j - 1)) << 1) | (t & (j - 1));
            int ixj = i | j;
            u64 a = sk[i];
            u64 c = sk[ixj];
            if ((a > c) == up) { sk[i] = c; sk[ixj] = a; }
        }
        __syncthreads();
    }
    for (int i = threadIdx.x; i < TILE; i += 1024) kb[i] = sk[i];
}

// ---------------------------------------------------------------------------
// Gather sorted top-PADN boxes. Pad rows get far-away degenerate boxes.
// ---------------------------------------------------------------------------
__global__ void gather_sorted(const float* __restrict__ boxes,
                              const u64* __restrict__ keys,
                              float4* __restrict__ sbox, int N) {
    int r = blockIdx.x * 256 + threadIdx.x;
    int b = blockIdx.y;
    if (r >= PADN) return;
    float4 v;
    if (r < PRE_TOPN) {
        u64 key = keys[(size_t)b * SORTN + r];
        int n = (int)(unsigned)(key & 0xffffffffULL);
        v = ((const float4*)boxes)[(size_t)b * N + n];
    } else {
        v = make_float4(-4e8f, -4e8f, -4e8f, -4e8f);
    }
    sbox[(size_t)b * PADN + r] = v;
}

// ---------------------------------------------------------------------------
// Exact-f32 suppression predicate (bit-identical to the f64 reference test).
// ---------------------------------------------------------------------------
__device__ __forceinline__ void iou_bit(float4 me, float ar, float4 cj, float aj,
                                        int j, unsigned& lo, unsigned& hi, int& tie) {
#pragma clang fp contract(off)
    float xx1 = fmaxf(me.x, cj.x);
    float yy1 = fmaxf(me.y, cj.y);
    float xx2 = fminf(me.z, cj.z);
    float yy2 = fminf(me.w, cj.w);
    float w = fmaxf((xx2 - xx1) + 1.0f, 0.0f);
    float h = fmaxf((yy2 - yy1) + 1.0f, 0.0f);
    float inter = w * h;
    float un = (ar + aj) - inter;
    float t = __builtin_fmaf(-0.7f, un, inter);
    float u25 = un * 0x1p-25f;
    unsigned sup = (t > u25) ? 1u : 0u;
    tie |= (t == u25) ? 1 : 0;
    if (j < 32) lo |= sup << j;
    else        hi |= sup << (j - 32);
}

__device__ __attribute__((noinline)) u64 slow_word(float4 me, float ar,
                                                   const float4* cbox,
                                                   const float* carea) {
#pragma clang fp contract(off)
    const double MD = (double)0.7f + 0x1p-25;   // exact midpoint multiplier
    u64 word = 0;
    for (int j = 0; j < 64; ++j) {
        float4 cj = cbox[j];
        float aj = carea[j];
        float xx1 = fmaxf(me.x, cj.x);
        float yy1 = fmaxf(me.y, cj.y);
        float xx2 = fminf(me.z, cj.z);
        float yy2 = fminf(me.w, cj.w);
        float w = fmaxf((xx2 - xx1) + 1.0f, 0.0f);
        float h = fmaxf((yy2 - yy1) + 1.0f, 0.0f);
        float inter = w * h;
        float un = (ar + aj) - inter;
        bool sup = ((double)inter >= MD * (double)un);
        word |= ((u64)sup) << j;
    }
    return word;
}

// ---------------------------------------------------------------------------
// Build ROW-MAJOR suppression bitmap for col-block pairs [pair0, ...).
// Diagonal words (r in block cb) are ALSO written to the contiguous diag[]
// array so the scan's next-block row fetch is coalesced (8 lines instead of
// a 64-line divergent gather).
// ---------------------------------------------------------------------------
__global__ __launch_bounds__(256) void build_bitmap(const float4* __restrict__ sbox,
                                                    u64* __restrict__ bitmap,
                                                    u64* __restrict__ diag,
                                                    const int* __restrict__ done,
                                                    int pair0) {
    int pair = pair0 + blockIdx.x;   // covers cbs 2*pair, 2*pair+1
    int chunk = blockIdx.y;          // 256-row chunk
    int b = blockIdx.z;
    if (done[b]) return;
    if (2 * chunk > pair) return;    // chunk's first row >= (2p+2)*64 -> empty
    int tid = threadIdx.x;
    int w = tid & 1;
    int cb = pair * 2 + w;
    int lim = (cb + 1) * 64;         // rows with words in column-block cb

    __shared__ float4 cbox[2][64];
    __shared__ float carea[2][64];
    const float4* sb = sbox + (size_t)b * PADN;
    if (tid < 128) {
        int which = tid >> 6, j = tid & 63;
        float4 c4 = sb[(pair * 2 + which) * 64 + j];
        cbox[which][j] = c4;
        carea[which][j] = ((c4.z - c4.x) + 1.0f) * ((c4.w - c4.y) + 1.0f);
    }
    int rl = tid >> 1;               // 0..127
    int r1 = chunk * 256 + rl;       // <= 46*256+127 = 11903 < PADN
    int r2 = r1 + 128;               // <= 12031 < PADN
    bool a1 = (r1 < lim);
    bool a2 = (r2 < lim);
    float4 me1 = sb[r1];
    float4 me2 = sb[r2];
    float ar1 = ((me1.z - me1.x) + 1.0f) * ((me1.w - me1.y) + 1.0f);
    float ar2 = ((me2.z - me2.x) + 1.0f) * ((me2.w - me2.y) + 1.0f);
    __syncthreads();

    u64* dgb = diag + (size_t)b * PADN;
    if (a1) {
        unsigned lo1 = 0, hi1 = 0;
        int tie1 = 0;
#pragma unroll
        for (int j = 0; j < 64; ++j) {
            iou_bit(me1, ar1, cbox[w][j], carea[w][j], j, lo1, hi1, tie1);
        }
        u64 w1 = ((u64)hi1 << 32) | lo1;
        if (__builtin_expect(tie1, 0)) w1 = slow_word(me1, ar1, cbox[w], carea[w]);
        int d1 = r1 - cb * 64;
        if (d1 >= 0) {                               // diagonal block word
            w1 &= ~((2ULL << d1) - 1ULL);
            dgb[r1] = w1;
        }
        bitmap[(size_t)b * TRI_WORDS + rowoff(r1) + (cb - (r1 >> 6))] = w1;
    }
    if (a2) {
        unsigned lo2 = 0, hi2 = 0;
        int tie2 = 0;
#pragma unroll
        for (int j = 0; j < 64; ++j) {
            iou_bit(me2, ar2, cbox[w][j], carea[w][j], j, lo2, hi2, tie2);
        }
        u64 w2 = ((u64)hi2 << 32) | lo2;
        if (__builtin_expect(tie2, 0)) w2 = slow_word(me2, ar2, cbox[w], carea[w]);
        int d2 = r2 - cb * 64;
        if (d2 >= 0) {
            w2 &= ~((2ULL << d2) - 1ULL);
            dgb[r2] = w2;
        }
        bitmap[(size_t)b * TRI_WORDS + rowoff(r2) + (cb - (r2 >> 6))] = w2;
    }
}

// ---------------------------------------------------------------------------
// DPP all-reduce OR within a 16-lane row; wave total via readlanes.
// ---------------------------------------------------------------------------
__device__ __forceinline__ unsigned dpp_or16(unsigned v) {
    v |= (unsigned)__builtin_amdgcn_update_dpp(0, (int)v, 0xB1, 0xF, 0xF, true);   // quad_perm {1,0,3,2}
    v |= (unsigned)__builtin_amdgcn_update_dpp(0, (int)v, 0x4E, 0xF, 0xF, true);   // quad_perm {2,3,0,1}
    v |= (unsigned)__builtin_amdgcn_update_dpp(0, (int)v, 0x141, 0xF, 0xF, true);  // row_half_mirror
    v |= (unsigned)__builtin_amdgcn_update_dpp(0, (int)v, 0x140, 0xF, 0xF, true);  // row_mirror
    return v;
}

__device__ __forceinline__ unsigned wave_or_from_rows(unsigned rowred) {
    unsigned a = (unsigned)__builtin_amdgcn_readlane((int)rowred, 0) |
                 (unsigned)__builtin_amdgcn_readlane((int)rowred, 16);
    unsigned c = (unsigned)__builtin_amdgcn_readlane((int)rowred, 32) |
                 (unsigned)__builtin_amdgcn_readlane((int)rowred, 48);
    return a | c;
}

// ---------------------------------------------------------------------------
// Resumable scan, round-12 = round-11 structure + two latency fixes:
//  (a) light barriers (WG_SYNC: lgkmcnt-only) so the pick-dependent delta
//      load and the next-block row/box prefetches stay IN FLIGHT across the
//      barrier instead of being drained by __syncthreads' vmcnt(0);
//  (b) next-block rows come from the contiguous diag[] array (coalesced)
//      instead of a 64-line divergent rowoff gather.
// LDS ordering audit for WG_SYNC: s_prevpicks/s_np/s_K writes and s_S
// atomicOr are all LDS (lgkmcnt-covered); globals crossing barriers are
// private VGPRs only; all barriers sit in uniform control flow.
// Semantics identical to rounds 7-11.
// ---------------------------------------------------------------------------
__global__ __launch_bounds__(1024) void scan_nms(const float4* __restrict__ sbox,
                                                 const u64* __restrict__ bitmap,
                                                 const u64* __restrict__ diag,
                                                 float* __restrict__ out,
                                                 u64* __restrict__ S_g,
                                                 int* __restrict__ picks_g,
                                                 int* __restrict__ kcnt,
                                                 int* __restrict__ done,
                                                 int rb0, int rb1) {
    int b = blockIdx.x;
    if (done[b]) return;
    int tid = threadIdx.x;
    int lane = tid & 63;
    int wv = tid >> 6;                     // 0..15
    __shared__ u64 s_S[MASK_WORDS];        // 1.5 KB running suppression mask
    __shared__ int s_pp[POST_TOPN];        // 8 KB committed pick rows
    __shared__ int s_prevpicks[2][64];
    __shared__ int s_np[2];
    __shared__ int s_K;

    u64* Sg = S_g + (size_t)b * MASK_WORDS;
    int* pg = picks_g + (size_t)b * POST_TOPN;
    int K0 = kcnt[b];
    if (tid == 0) s_K = K0;
    if (tid < 2) s_np[tid] = 0;
    if (tid < MASK_WORDS) s_S[tid] = (tid < NBLK && rb0 > 0) ? Sg[tid] : 0ULL;
    for (int t = tid; t < K0; t += 1024) s_pp[t] = pg[t];
    WG_SYNC();

    const u64* bm = bitmap + (size_t)b * TRI_WORDS;
    const u64* dgb = diag + (size_t)b * PADN;
    const float4* sbb = sbox + (size_t)b * PADN;

    u64 myrow = 0, delta = 0;
    float4 mybox = make_float4(0.f, 0.f, 0.f, 0.f);
    if (wv == 0) {
        // prologue diag row + box for rb0 (coalesced; overlaps catch-up)
        int r = rb0 * 64 + lane;
        myrow = dgb[r];
        mybox = sbb[r];
    } else if (rb0 > 0 && K0 > 0) {
        // ---- CATCH-UP: cols [rb0, rb1) x all K0 prior picks ----
        int width = rb1 - rb0;             // <= 128 by stage construction
        int nseg2 = (width + 63) >> 6;     // 1 or 2
        int w = wv - 1;                    // 0..14
        int s2, str, nstr;
        if (nseg2 == 2) { s2 = w & 1; str = w >> 1; nstr = (s2 == 0) ? 8 : 7; }
        else            { s2 = 0;     str = w;      nstr = 15; }
        int ce = s2 * 64 + lane;
        bool act = (ce < width);
        u64 amask = act ? ~0ULL : 0ULL;
        int cb = rb0 + ce;
        int cbc = act ? cb : rb0;
        u64 acc = 0;
        int last = K0 - 1;
        for (int q = str; q < K0; q += 8 * nstr) {
            int q0 = q;
            int q1 = q + nstr;     if (q1 > last) q1 = q0;
            int q2 = q + 2 * nstr; if (q2 > last) q2 = q0;
            int q3 = q + 3 * nstr; if (q3 > last) q3 = q0;
            int q4 = q + 4 * nstr; if (q4 > last) q4 = q0;
            int q5 = q + 5 * nstr; if (q5 > last) q5 = q0;
            int q6 = q + 6 * nstr; if (q6 > last) q6 = q0;
            int q7 = q + 7 * nstr; if (q7 > last) q7 = q0;
            int p0 = s_pp[q0], p1 = s_pp[q1], p2 = s_pp[q2], p3 = s_pp[q3];
            int p4 = s_pp[q4], p5 = s_pp[q5], p6 = s_pp[q6], p7 = s_pp[q7];
            u64 v0 = bm[rowoff(p0) + (cbc - (p0 >> 6))];
            u64 v1 = bm[rowoff(p1) + (cbc - (p1 >> 6))];
            u64 v2 = bm[rowoff(p2) + (cbc - (p2 >> 6))];
            u64 v3 = bm[rowoff(p3) + (cbc - (p3 >> 6))];
            u64 v4 = bm[rowoff(p4) + (cbc - (p4 >> 6))];
            u64 v5 = bm[rowoff(p5) + (cbc - (p5 >> 6))];
            u64 v6 = bm[rowoff(p6) + (cbc - (p6 >> 6))];
            u64 v7 = bm[rowoff(p7) + (cbc - (p7 >> 6))];
            acc |= ((v0 | v1) | (v2 | v3)) | ((v4 | v5) | (v6 | v7));
        }
        acc &= amask;
        if (act && acc) atomicOr(&s_S[cb], acc);
    }
    WG_SYNC();

    int rb = rb0;
    for (; rb < rb1; ++rb) {
        int K = s_K;                       // uniform (post-barrier)
        if (K >= POST_TOPN) break;
        int base = rb * 64;
        bool havenext = (rb + 1 < rb1);
        int pq = (rb + 1) & 1;             // parity of block rb-1

        if (wv == 0) {
            // early prefetch of next diagonal row+box (coalesced diag[])
            u64 nrow = 0;
            float4 nbox = make_float4(0.f, 0.f, 0.f, 0.f);
            if (havenext) {
                int rn = (rb + 1) * 64 + lane;
                nrow = dgb[rn];
                nbox = sbb[rn];
            }
            // delta reduce: picks of rb-1 suppression into cb=rb
            unsigned rlo = dpp_or16((unsigned)(delta & 0xffffffffULL));
            unsigned rhi = dpp_or16((unsigned)(delta >> 32));
            u64 dtot = ((u64)wave_or_from_rows(rhi) << 32) | wave_or_from_rows(rlo);
            u64 t4 = s_S[rb] | dtot;
            if (rb == NBLK - 1) t4 |= 0xFFFFFFFF00000000ULL;   // pad rows >= 12000
            unsigned tlo = (unsigned)__builtin_amdgcn_readfirstlane((int)(t4 & 0xffffffffULL));
            unsigned thi = (unsigned)__builtin_amdgcn_readfirstlane((int)(t4 >> 32));
            u64 alive = ~(((u64)thi << 32) | tlo);
            int mrl = (int)(myrow & 0xffffffffULL);
            int mrh = (int)(myrow >> 32);
            u64 picks = 0;
            u64 cur = alive;
            while (cur) {
                int i = (int)__builtin_ctzll(cur);
                picks |= 1ULL << i;
                unsigned rl = (unsigned)__builtin_amdgcn_readlane(mrl, i);
                unsigned rh = (unsigned)__builtin_amdgcn_readlane(mrh, i);
                u64 row = ((u64)rh << 32) | rl;
                alive &= ~row;
                cur = alive & ~((2ULL << i) - 1ULL);
            }
            int avail = POST_TOPN - K;
            int np = __popcll(picks);
            while (np > avail) {                       // truncate latest picks
                picks &= ~(1ULL << (63 - __clzll(picks)));
                --np;
            }
            int c = lane;
            bool ipick = ((picks >> c) & 1ULL) != 0;
            delta = 0;
            if (ipick) {
                int rank = __popcll(picks & ((1ULL << c) - 1ULL));
                int p = base + c;
                s_prevpicks[rb & 1][rank] = p;
                pg[K + rank] = p;                      // persist pick row
                float* o = out + ((size_t)b * POST_TOPN + K + rank) * 5;
                o[0] = (float)b; o[1] = mybox.x; o[2] = mybox.y; o[3] = mybox.z; o[4] = mybox.w;
                if (havenext) delta = bm[rowoff(p) + 1];   // word (p, rb+1)
            }
            if (c == 0) {
                s_K = K + np;
                s_np[rb & 1] = np;
            }
            myrow = nrow; mybox = nbox;
        } else {
            // OR-step: tails of block rb-1's picks into cols [rb+1, rb1).
            // wave w: col-segment r=(w-1)%3, pick-stripe a=(w-1)/3 (of 5).
            int npp = s_np[pq];
            int len = rb1 - (rb + 1);
            int w = wv - 1;                   // 0..14
            int a3 = (w * 11) >> 5;           // w / 3
            int r3 = w - a3 * 3;              // w % 3
            if (npp > 0 && r3 * 64 < len) {
                const int* pp = s_prevpicks[pq];
                int ce = r3 * 64 + lane;
                bool act = (ce < len);
                u64 amask = act ? ~0ULL : 0ULL;
                int off = act ? (2 + ce) : 0;
                int last = npp - 1;
                u64 acc = 0;
                for (int q = a3; q < npp; q += 40) {
                    int q0 = q;
                    int q1 = q + 5;  if (q1 > last) q1 = q0;
                    int q2 = q + 10; if (q2 > last) q2 = q0;
                    int q3 = q + 15; if (q3 > last) q3 = q0;
                    int q4 = q + 20; if (q4 > last) q4 = q0;
                    int q5 = q + 25; if (q5 > last) q5 = q0;
                    int q6 = q + 30; if (q6 > last) q6 = q0;
                    int q7 = q + 35; if (q7 > last) q7 = q0;
                    u64 v0 = bm[rowoff(pp[q0]) + off];
                    u64 v1 = bm[rowoff(pp[q1]) + off];
                    u64 v2 = bm[rowoff(pp[q2]) + off];
                    u64 v3 = bm[rowoff(pp[q3]) + off];
                    u64 v4 = bm[rowoff(pp[q4]) + off];
                    u64 v5 = bm[rowoff(pp[q5]) + off];
                    u64 v6 = bm[rowoff(pp[q6]) + off];
                    u64 v7 = bm[rowoff(pp[q7]) + off];
                    acc |= ((v0 | v1) | (v2 | v3)) | ((v4 | v5) | (v6 | v7));
                }
                acc &= amask;
                if (act && acc) atomicOr(&s_S[rb + 1 + ce], acc);
            }
        }
        WG_SYNC();
    }

    int K = s_K;
    bool finished = (K >= POST_TOPN) || (rb1 >= NBLK);
    if (finished) {
        for (int r = K + tid; r < POST_TOPN; r += 1024) {
            float* o = out + ((size_t)b * POST_TOPN + r) * 5;
            o[0] = 0.0f; o[1] = 0.0f; o[2] = 0.0f; o[3] = 0.0f; o[4] = 0.0f;
        }
        if (tid == 0) done[b] = 1;
    } else {
        // persist running mask; picks of the last block get their tail
        // (cols >= rb1) OR'd by the NEXT stage's catch-up via picks_g.
        if (tid < NBLK) Sg[tid] = s_S[tid];
    }
    if (tid == 0) kcnt[b] = K;
}

// ---------------------------------------------------------------------------
// Fallback (round-2) NMS kernel — used only if ws_size can't hold the bitmap.
// ---------------------------------------------------------------------------
__global__ __launch_bounds__(1024) void nms_kernel(const float* __restrict__ boxes,
                                                   const u64* __restrict__ keys,
                                                   float* __restrict__ out,
                                                   int N) {
#pragma clang fp contract(off)
    __shared__ float4 kbox[POST_TOPN];
    __shared__ float kar[POST_TOPN];
    __shared__ float4 cbox[64];
    __shared__ float car_s[64];
    __shared__ int supp[64];
    __shared__ int s_cnt;

    int b = blockIdx.x;
    int tid = threadIdx.x;
    const u64* kb = keys + (size_t)b * SORTN;
    const float* bb = boxes + (size_t)b * N * 4;

    if (tid == 0) s_cnt = 0;
    __syncthreads();

    for (int start = 0; start < PRE_TOPN; start += 64) {
        int K = s_cnt;
        if (K >= POST_TOPN) break;
        int csize = min(64, PRE_TOPN - start);

        if (tid < 64) {
            int c = tid;
            if (c < csize) {
                u64 key = kb[start + c];
                int n = (int)(unsigned int)(key & 0xFFFFFFFFULL);
                const float* p = bb + (size_t)n * 4;
                float x1 = p[0], y1 = p[1], x2 = p[2], y2 = p[3];
                cbox[c] = make_float4(x1, y1, x2, y2);
                car_s[c] = ((x2 - x1) + 1.0f) * ((y2 - y1) + 1.0f);
            }
            supp[c] = 0;
        }
        __syncthreads();

        {
            int c = tid & 63;
            int sl = tid >> 6;
            if (c < csize) {
                float4 me = cbox[c];
                float ar = car_s[c];
                int flag = 0;
                for (int kk = sl; kk < K; kk += 16) {
                    float4 k0 = kbox[kk];
                    float a0 = kar[kk];
                    float xx1 = fmaxf(k0.x, me.x);
                    float yy1 = fmaxf(k0.y, me.y);
                    float xx2 = fminf(k0.z, me.z);
                    float yy2 = fminf(k0.w, me.w);
                    float w0 = fmaxf((xx2 - xx1) + 1.0f, 0.0f);
                    float h0 = fmaxf((yy2 - yy1) + 1.0f, 0.0f);
                    float inter0 = w0 * h0;
                    float iou0 = inter0 / ((a0 + ar) - inter0);
                    if (iou0 > 0.7f) { flag = 1; break; }
                }
                if (flag) supp[c] = 1;
            }
        }
        __syncthreads();

        if (tid < 64) {
            int c = tid;
            bool alive = (c < csize) && (supp[c] == 0);
            float4 me = cbox[c];
            float ar = car_s[c];
            int cnt = K;
            u64 m = __ballot(alive);
            while (m != 0 && cnt < POST_TOPN) {
                int i = __ffsll((unsigned long long)m) - 1;
                float ix1 = __shfl(me.x, i);
                float iy1 = __shfl(me.y, i);
                float ix2 = __shfl(me.z, i);
                float iy2 = __shfl(me.w, i);
                float iar = __shfl(ar, i);
                if (c == i) {
                    kbox[cnt] = me;
                    kar[cnt] = ar;
                    float* o = out + ((size_t)b * POST_TOPN + cnt) * 5;
                    o[0] = (float)b; o[1] = me.x; o[2] = me.y; o[3] = me.z; o[4] = me.w;
                }
                if (alive && c > i) {
                    float xx1 = fmaxf(ix1, me.x);
                    float yy1 = fmaxf(iy1, me.y);
                    float xx2 = fminf(ix2, me.z);
                    float yy2 = fminf(iy2, me.w);
                    float w = fmaxf((xx2 - xx1) + 1.0f, 0.0f);
                    float h = fmaxf((yy2 - yy1) + 1.0f, 0.0f);
                    float inter = w * h;
                    float iou = inter / ((iar + ar) - inter);
                    if (iou > 0.7f) alive = false;
                }
                cnt++;
                m = __ballot(alive);
                u64 clearmask = (2ULL << i) - 1ULL;
                m &= ~clearmask;
            }
            if (c == 0) s_cnt = cnt;
        }
        __syncthreads();
    }

    __syncthreads();
    int K = s_cnt;
    for (int r = K + tid; r < POST_TOPN; r += (int)blockDim.x) {
        float* o = out + ((size_t)b * POST_TOPN + r) * 5;
        o[0] = 0.0f; o[1] = 0.0f; o[2] = 0.0f; o[3] = 0.0f; o[4] = 0.0f;
    }
}

// ---------------------------------------------------------------------------
extern "C" void kernel_launch(void* const* d_in, const int* in_sizes, int n_in,
                              void* d_out, int out_size, void* d_ws, size_t ws_size,
                              hipStream_t stream) {
    const float* anchors = (const float*)d_in[0];
    const float* deltas  = (const float*)d_in[1];
    const float* scores  = (const float*)d_in[2];
    float* out = (float*)d_out;

    int N = in_sizes[0] / 4;           // 27380
    int B = in_sizes[2] / N;           // 8

    size_t off = 0;
    auto take = [&](size_t bytes) { size_t o = off; off = (off + bytes + 255) & ~(size_t)255; return o; };
    size_t boxesOff  = take((size_t)B * N * 4 * sizeof(float));
    size_t keysOff   = take((size_t)B * SORTN * sizeof(u64));
    size_t sboxOff   = take((size_t)B * PADN * sizeof(float4));
    size_t bitmapOff = take((size_t)B * TRI_WORDS * sizeof(u64));
    size_t diagOff   = take((size_t)B * PADN * sizeof(u64));
    size_t SgOff     = take((size_t)B * MASK_WORDS * sizeof(u64));
    size_t pgOff     = take((size_t)B * POST_TOPN * sizeof(int));
    size_t kcntOff   = take((size_t)B * sizeof(int));
    size_t doneOff   = take((size_t)B * sizeof(int));
    bool bitmap_path = (off <= ws_size);

    float* boxes = (float*)((char*)d_ws + boxesOff);
    u64*   keys  = (u64*)((char*)d_ws + keysOff);
    u64* diag    = bitmap_path ? (u64*)((char*)d_ws + diagOff)  : nullptr;
    u64* S_g     = bitmap_path ? (u64*)((char*)d_ws + SgOff)    : nullptr;
    int* pg      = bitmap_path ? (int*)((char*)d_ws + pgOff)    : nullptr;
    int* kcnt    = bitmap_path ? (int*)((char*)d_ws + kcntOff)  : nullptr;
    int* done    = bitmap_path ? (int*)((char*)d_ws + doneOff)  : nullptr;

    dim3 g1((unsigned)((SORTN + 255) / 256), (unsigned)B);
    decode_pack<<<g1, 256, 0, stream>>>(anchors, deltas, scores, boxes, keys, kcnt, done, N);

    int ntiles = B * NTILE;
    bitonic_local_sort<<<ntiles, 1024, 0, stream>>>(keys);
    int gsteps = B * (SORTN / 2) / 256;
    bitonic_global_step<<<gsteps, 256, 0, stream>>>(keys, 2 * TILE, TILE);
    bitonic_local_merge<<<ntiles, 1024, 0, stream>>>(keys, 2 * TILE);
    bitonic_global_step<<<gsteps, 256, 0, stream>>>(keys, 4 * TILE, 2 * TILE);
    bitonic_global_step<<<gsteps, 256, 0, stream>>>(keys, 4 * TILE, TILE);
    bitonic_local_merge<<<ntiles, 1024, 0, stream>>>(keys, 4 * TILE);

    if (bitmap_path) {
        float4* sbox = (float4*)((char*)d_ws + sboxOff);
        u64* bitmap  = (u64*)((char*)d_ws + bitmapOff);
        dim3 gg((unsigned)((PADN + 255) / 256), (unsigned)B);
        gather_sorted<<<gg, 256, 0, stream>>>(boxes, keys, sbox, N);

        // Progressive build/scan with per-batch done[] cutoff. Segments in
        // col-block units (even; widths <= 128 per the catch-up's 2-segment
        // mapping).
        const int seg[6] = {0, 48, 64, 88, 120, NBLK};
        for (int s = 0; s < 5; ++s) {
            int c0 = seg[s], c1 = seg[s + 1];
            int p0 = c0 / 2;
            int npair = (c1 - c0) / 2;
            unsigned gy = (unsigned)(((c1 / 2 - 1) >> 1) + 1);   // 256-row chunks
            dim3 gb((unsigned)npair, gy, (unsigned)B);
            build_bitmap<<<gb, 256, 0, stream>>>(sbox, bitmap, diag, done, p0);
            scan_nms<<<B, 1024, 0, stream>>>(sbox, bitmap, diag, out, S_g, pg, kcnt, done, c0, c1);
        }
    } else {
        nms_kernel<<<B, 1024, 0, stream>>>(boxes, keys, out, N);
    }
}

// Round 8
// 278.879 us; speedup vs baseline: 3.1089x; 1.2020x over previous
//
#include <hip/hip_runtime.h>
#include <cmath>

typedef unsigned long long u64;

#define PRE_TOPN 12000
#define POST_TOPN 2000
#define SORTN 32768
#define TILE 8192
#define NTILE (SORTN / TILE)   // 4 tiles per batch
#define NBLK 188               // 64-bit column blocks covering 12032
#define PADN (NBLK * 64)       // 12032
// ROW-MAJOR triangular bitmap: row r stores words for col-blocks
// cb in [r/64, NBLK) contiguously at rowoff(r). Total words per batch:
#define TRI_WORDS (32 * (NBLK - 1) * NBLK + NBLK * 64)  // 1,137,024
#define MASK_WORDS 192         // 188 used, padded

// Light workgroup barrier: orders LDS (lgkmcnt) but lets global loads stay
// in flight across the barrier.
#define WG_SYNC() asm volatile("s_waitcnt lgkmcnt(0)\n\ts_barrier" ::: "memory")

__device__ __forceinline__ int rowoff(int r) {
    int rb = r >> 6;
    int q = r & 63;
    return r * NBLK - (32 * rb * (rb - 1) + q * rb);
}

// ---------------------------------------------------------------------------
// Kernel 1: decode boxes (exact fp32 op order, no FMA contraction, exp via
// double) and pack sort keys. key = (~score_bits)<<32 | idx.
// Also resets the per-batch NMS progress state (kcnt/done) for this launch.
// ---------------------------------------------------------------------------
__global__ void decode_pack(const float* __restrict__ anchors,
                            const float* __restrict__ deltas,
                            const float* __restrict__ scores,
                            float* __restrict__ boxes,
                            u64* __restrict__ keys,
                            int* __restrict__ kcnt,
                            int* __restrict__ done,
                            int N) {
#pragma clang fp contract(off)
    int n = blockIdx.x * blockDim.x + threadIdx.x;
    int b = blockIdx.y;
    if (kcnt != nullptr && blockIdx.x == 0 && threadIdx.x == 0) {
        kcnt[b] = 0;
        done[b] = 0;
    }
    if (n >= SORTN) return;
    u64* kb = keys + (size_t)b * SORTN;
    if (n < N) {
        float a0 = anchors[n * 4 + 0];
        float a1 = anchors[n * 4 + 1];
        float a2 = anchors[n * 4 + 2];
        float a3 = anchors[n * 4 + 3];
        float w = (a2 - a0) + 1.0f;
        float h = (a3 - a1) + 1.0f;
        float cx = a0 + 0.5f * w;
        float cy = a1 + 0.5f * h;
        const float* d = deltas + ((size_t)b * N + n) * 4;
        float dx = d[0], dy = d[1], dw = d[2], dh = d[3];
        float px = cx + w * dx;
        float py = cy + h * dy;
        float pw = (float)::exp((double)dw) * w;
        float ph = (float)::exp((double)dh) * h;
        float* bb = boxes + ((size_t)b * N + n) * 4;
        bb[0] = px - 0.5f * pw;
        bb[1] = py - 0.5f * ph;
        bb[2] = px + 0.5f * (pw - 2.0f);
        bb[3] = py + 0.5f * (ph - 2.0f);
        unsigned int sb = __float_as_uint(scores[(size_t)b * N + n]);
        kb[n] = ((u64)(~sb) << 32) | (u64)(unsigned int)n;
    } else {
        kb[n] = ~0ULL;
    }
}

// ---------------------------------------------------------------------------
// Hybrid bitonic sort (unchanged).
// ---------------------------------------------------------------------------
__global__ __launch_bounds__(1024) void bitonic_local_sort(u64* __restrict__ keys) {
    __shared__ u64 sk[TILE];
    int tile = blockIdx.x;
    u64* kb = keys + (size_t)tile * TILE;
    int base = (tile % NTILE) * TILE;
    for (int i = threadIdx.x; i < TILE; i += 1024) sk[i] = kb[i];
    __syncthreads();
    for (int k = 2; k <= TILE; k <<= 1) {
        for (int j = k >> 1; j > 0; j >>= 1) {
            for (int t = threadIdx.x; t < TILE / 2; t += 1024) {
                int i = ((t & ~(j - 1)) << 1) | (t & (j - 1));
                int ixj = i | j;
                u64 a = sk[i];
                u64 c = sk[ixj];
                bool up = (((base + i) & k) == 0);
                if ((a > c) == up) { sk[i] = c; sk[ixj] = a; }
            }
            __syncthreads();
        }
    }
    for (int i = threadIdx.x; i < TILE; i += 1024) kb[i] = sk[i];
}

__global__ void bitonic_global_step(u64* __restrict__ keys, int k, int j) {
    int t = blockIdx.x * blockDim.x + threadIdx.x;
    int b = t / (SORTN / 2);
    int s = t % (SORTN / 2);
    int i = ((s & ~(j - 1)) << 1) | (s & (j - 1));
    int ixj = i | j;
    u64* kb = keys + (size_t)b * SORTN;
    u64 a = kb[i];
    u64 c = kb[ixj];
    bool up = ((i & k) == 0);
    if ((a > c) == up) { kb[i] = c; kb[ixj] = a; }
}

__global__ __launch_bounds__(1024) void bitonic_local_merge(u64* __restrict__ keys, int k) {
    __shared__ u64 sk[TILE];
    int tile = blockIdx.x;
    u64* kb = keys + (size_t)tile * TILE;
    int base = (tile % NTILE) * TILE;
    bool up = ((base & k) == 0);
    for (int i = threadIdx.x; i < TILE; i += 1024) sk[i] = kb[i];
    __syncthreads();
    for (int j = TILE / 2; j > 0; j >>= 1) {
        for (int t = threadIdx.x; t < TILE / 2; t += 1024) {
            int i = ((t & ~(j - 1)) << 1) | (t & (j - 1));
            int ixj = i | j;
            u64 a = sk[i];
            u64 c = sk[ixj];
            if ((a > c) == up) { sk[i] = c; sk[ixj] = a; }
        }
        __syncthreads();
    }
    for (int i = threadIdx.x; i < TILE; i += 1024) kb[i] = sk[i];
}

// ---------------------------------------------------------------------------
// Gather sorted top-PADN boxes. Pad rows get far-away degenerate boxes.
// ---------------------------------------------------------------------------
__global__ void gather_sorted(const float* __restrict__ boxes,
                              const u64* __restrict__ keys,
                              float4* __restrict__ sbox, int N) {
    int r = blockIdx.x * 256 + threadIdx.x;
    int b = blockIdx.y;
    if (r >= PADN) return;
    float4 v;
    if (r < PRE_TOPN) {
        u64 key = keys[(size_t)b * SORTN + r];
        int n = (int)(unsigned)(key & 0xffffffffULL);
        v = ((const float4*)boxes)[(size_t)b * N + n];
    } else {
        v = make_float4(-4e8f, -4e8f, -4e8f, -4e8f);
    }
    sbox[(size_t)b * PADN + r] = v;
}

// ---------------------------------------------------------------------------
// Exact-f32 suppression predicate (bit-identical to the f64 reference test).
// ---------------------------------------------------------------------------
__device__ __forceinline__ void iou_bit(float4 me, float ar, float4 cj, float aj,
                                        int j, unsigned& lo, unsigned& hi, int& tie) {
#pragma clang fp contract(off)
    float xx1 = fmaxf(me.x, cj.x);
    float yy1 = fmaxf(me.y, cj.y);
    float xx2 = fminf(me.z, cj.z);
    float yy2 = fminf(me.w, cj.w);
    float w = fmaxf((xx2 - xx1) + 1.0f, 0.0f);
    float h = fmaxf((yy2 - yy1) + 1.0f, 0.0f);
    float inter = w * h;
    float un = (ar + aj) - inter;
    float t = __builtin_fmaf(-0.7f, un, inter);
    float u25 = un * 0x1p-25f;
    unsigned sup = (t > u25) ? 1u : 0u;
    tie |= (t == u25) ? 1 : 0;
    if (j < 32) lo |= sup << j;
    else        hi |= sup << (j - 32);
}

__device__ __attribute__((noinline)) u64 slow_word(float4 me, float ar,
                                                   const float4* cbox,
                                                   const float* carea) {
#pragma clang fp contract(off)
    const double MD = (double)0.7f + 0x1p-25;   // exact midpoint multiplier
    u64 word = 0;
    for (int j = 0; j < 64; ++j) {
        float4 cj = cbox[j];
        float aj = carea[j];
        float xx1 = fmaxf(me.x, cj.x);
        float yy1 = fmaxf(me.y, cj.y);
        float xx2 = fminf(me.z, cj.z);
        float yy2 = fminf(me.w, cj.w);
        float w = fmaxf((xx2 - xx1) + 1.0f, 0.0f);
        float h = fmaxf((yy2 - yy1) + 1.0f, 0.0f);
        float inter = w * h;
        float un = (ar + aj) - inter;
        bool sup = ((double)inter >= MD * (double)un);
        word |= ((u64)sup) << j;
    }
    return word;
}

// ---------------------------------------------------------------------------
// Build ROW-MAJOR suppression bitmap for col-block pairs [pair0, ...).
// Diagonal words are ALSO written to the contiguous diag[] array.
// ---------------------------------------------------------------------------
__global__ __launch_bounds__(256) void build_bitmap(const float4* __restrict__ sbox,
                                                    u64* __restrict__ bitmap,
                                                    u64* __restrict__ diag,
                                                    const int* __restrict__ done,
                                                    int pair0) {
    int pair = pair0 + blockIdx.x;   // covers cbs 2*pair, 2*pair+1
    int chunk = blockIdx.y;          // 256-row chunk
    int b = blockIdx.z;
    if (done[b]) return;
    if (2 * chunk > pair) return;    // chunk's first row >= (2p+2)*64 -> empty
    int tid = threadIdx.x;
    int w = tid & 1;
    int cb = pair * 2 + w;
    int lim = (cb + 1) * 64;         // rows with words in column-block cb

    __shared__ float4 cbox[2][64];
    __shared__ float carea[2][64];
    const float4* sb = sbox + (size_t)b * PADN;
    if (tid < 128) {
        int which = tid >> 6, j = tid & 63;
        float4 c4 = sb[(pair * 2 + which) * 64 + j];
        cbox[which][j] = c4;
        carea[which][j] = ((c4.z - c4.x) + 1.0f) * ((c4.w - c4.y) + 1.0f);
    }
    int rl = tid >> 1;               // 0..127
    int r1 = chunk * 256 + rl;       // <= 46*256+127 = 11903 < PADN
    int r2 = r1 + 128;               // <= 12031 < PADN
    bool a1 = (r1 < lim);
    bool a2 = (r2 < lim);
    float4 me1 = sb[r1];
    float4 me2 = sb[r2];
    float ar1 = ((me1.z - me1.x) + 1.0f) * ((me1.w - me1.y) + 1.0f);
    float ar2 = ((me2.z - me2.x) + 1.0f) * ((me2.w - me2.y) + 1.0f);
    __syncthreads();

    u64* dgb = diag + (size_t)b * PADN;
    if (a1) {
        unsigned lo1 = 0, hi1 = 0;
        int tie1 = 0;
#pragma unroll
        for (int j = 0; j < 64; ++j) {
            iou_bit(me1, ar1, cbox[w][j], carea[w][j], j, lo1, hi1, tie1);
        }
        u64 w1 = ((u64)hi1 << 32) | lo1;
        if (__builtin_expect(tie1, 0)) w1 = slow_word(me1, ar1, cbox[w], carea[w]);
        int d1 = r1 - cb * 64;
        if (d1 >= 0) {                               // diagonal block word
            w1 &= ~((2ULL << d1) - 1ULL);
            dgb[r1] = w1;
        }
        bitmap[(size_t)b * TRI_WORDS + rowoff(r1) + (cb - (r1 >> 6))] = w1;
    }
    if (a2) {
        unsigned lo2 = 0, hi2 = 0;
        int tie2 = 0;
#pragma unroll
        for (int j = 0; j < 64; ++j) {
            iou_bit(me2, ar2, cbox[w][j], carea[w][j], j, lo2, hi2, tie2);
        }
        u64 w2 = ((u64)hi2 << 32) | lo2;
        if (__builtin_expect(tie2, 0)) w2 = slow_word(me2, ar2, cbox[w], carea[w]);
        int d2 = r2 - cb * 64;
        if (d2 >= 0) {
            w2 &= ~((2ULL << d2) - 1ULL);
            dgb[r2] = w2;
        }
        bitmap[(size_t)b * TRI_WORDS + rowoff(r2) + (cb - (r2 >> 6))] = w2;
    }
}

// ---------------------------------------------------------------------------
// DPP helpers: 16-lane OR-reduce, wave total via readlanes, and the
// canonical 64-lane inclusive prefix-OR scan (row_shr 1/2/4/8 +
// row_bcast15 into rows 1,3 + row_bcast31 into rows 2,3).
// ---------------------------------------------------------------------------
__device__ __forceinline__ unsigned dpp_or16(unsigned v) {
    v |= (unsigned)__builtin_amdgcn_update_dpp(0, (int)v, 0xB1, 0xF, 0xF, true);   // quad_perm {1,0,3,2}
    v |= (unsigned)__builtin_amdgcn_update_dpp(0, (int)v, 0x4E, 0xF, 0xF, true);   // quad_perm {2,3,0,1}
    v |= (unsigned)__builtin_amdgcn_update_dpp(0, (int)v, 0x141, 0xF, 0xF, true);  // row_half_mirror
    v |= (unsigned)__builtin_amdgcn_update_dpp(0, (int)v, 0x140, 0xF, 0xF, true);  // row_mirror
    return v;
}

__device__ __forceinline__ unsigned wave_or_from_rows(unsigned rowred) {
    unsigned a = (unsigned)__builtin_amdgcn_readlane((int)rowred, 0) |
                 (unsigned)__builtin_amdgcn_readlane((int)rowred, 16);
    unsigned c = (unsigned)__builtin_amdgcn_readlane((int)rowred, 32) |
                 (unsigned)__builtin_amdgcn_readlane((int)rowred, 48);
    return a | c;
}

__device__ __forceinline__ unsigned wave_incl_prefix_or(unsigned v) {
    v |= (unsigned)__builtin_amdgcn_update_dpp(0, (int)v, 0x111, 0xF, 0xF, true);  // row_shr:1
    v |= (unsigned)__builtin_amdgcn_update_dpp(0, (int)v, 0x112, 0xF, 0xF, true);  // row_shr:2
    v |= (unsigned)__builtin_amdgcn_update_dpp(0, (int)v, 0x114, 0xF, 0xF, true);  // row_shr:4
    v |= (unsigned)__builtin_amdgcn_update_dpp(0, (int)v, 0x118, 0xF, 0xF, true);  // row_shr:8
    v |= (unsigned)__builtin_amdgcn_update_dpp(0, (int)v, 0x142, 0xA, 0xF, true);  // row_bcast:15 -> rows 1,3
    v |= (unsigned)__builtin_amdgcn_update_dpp(0, (int)v, 0x143, 0xC, 0xF, true);  // row_bcast:31 -> rows 2,3
    return v;
}

// ---------------------------------------------------------------------------
// Resumable scan, round-13 = round-12 + FRONTIER-BATCHED GREEDY.
// The serial per-pick readlane chain (~130 cy x ~27 picks/block) is replaced
// by wave-parallel rounds. Round: front = { i in alive : no alive j<i
// suppresses i } (inclusive DPP prefix-OR of alive-masked rows; diagonal
// bits are pre-cleared by build so inclusive == exclusive), commit front,
// alive &= ~(front | sup(front)). Every front member is provably a serial-
// greedy pick and iterating reproduces the exact serial pick set; rounds =
// suppression-chain depth (typically 1-2; >=8 falls back to the serial
// loop). Semantics identical to rounds 7-12.
// ---------------------------------------------------------------------------
__global__ __launch_bounds__(1024) void scan_nms(const float4* __restrict__ sbox,
                                                 const u64* __restrict__ bitmap,
                                                 const u64* __restrict__ diag,
                                                 float* __restrict__ out,
                                                 u64* __restrict__ S_g,
                                                 int* __restrict__ picks_g,
                                                 int* __restrict__ kcnt,
                                                 int* __restrict__ done,
                                                 int rb0, int rb1) {
    int b = blockIdx.x;
    if (done[b]) return;
    int tid = threadIdx.x;
    int lane = tid & 63;
    int wv = tid >> 6;                     // 0..15
    __shared__ u64 s_S[MASK_WORDS];        // 1.5 KB running suppression mask
    __shared__ int s_pp[POST_TOPN];        // 8 KB committed pick rows
    __shared__ int s_prevpicks[2][64];
    __shared__ int s_np[2];
    __shared__ int s_K;

    u64* Sg = S_g + (size_t)b * MASK_WORDS;
    int* pg = picks_g + (size_t)b * POST_TOPN;
    int K0 = kcnt[b];
    if (tid == 0) s_K = K0;
    if (tid < 2) s_np[tid] = 0;
    if (tid < MASK_WORDS) s_S[tid] = (tid < NBLK && rb0 > 0) ? Sg[tid] : 0ULL;
    for (int t = tid; t < K0; t += 1024) s_pp[t] = pg[t];
    WG_SYNC();

    const u64* bm = bitmap + (size_t)b * TRI_WORDS;
    const u64* dgb = diag + (size_t)b * PADN;
    const float4* sbb = sbox + (size_t)b * PADN;

    u64 myrow = 0, delta = 0;
    float4 mybox = make_float4(0.f, 0.f, 0.f, 0.f);
    if (wv == 0) {
        // prologue diag row + box for rb0 (coalesced; overlaps catch-up)
        int r = rb0 * 64 + lane;
        myrow = dgb[r];
        mybox = sbb[r];
    } else if (rb0 > 0 && K0 > 0) {
        // ---- CATCH-UP: cols [rb0, rb1) x all K0 prior picks ----
        int width = rb1 - rb0;             // <= 128 by stage construction
        int nseg2 = (width + 63) >> 6;     // 1 or 2
        int w = wv - 1;                    // 0..14
        int s2, str, nstr;
        if (nseg2 == 2) { s2 = w & 1; str = w >> 1; nstr = (s2 == 0) ? 8 : 7; }
        else            { s2 = 0;     str = w;      nstr = 15; }
        int ce = s2 * 64 + lane;
        bool act = (ce < width);
        u64 amask = act ? ~0ULL : 0ULL;
        int cb = rb0 + ce;
        int cbc = act ? cb : rb0;
        u64 acc = 0;
        int last = K0 - 1;
        for (int q = str; q < K0; q += 8 * nstr) {
            int q0 = q;
            int q1 = q + nstr;     if (q1 > last) q1 = q0;
            int q2 = q + 2 * nstr; if (q2 > last) q2 = q0;
            int q3 = q + 3 * nstr; if (q3 > last) q3 = q0;
            int q4 = q + 4 * nstr; if (q4 > last) q4 = q0;
            int q5 = q + 5 * nstr; if (q5 > last) q5 = q0;
            int q6 = q + 6 * nstr; if (q6 > last) q6 = q0;
            int q7 = q + 7 * nstr; if (q7 > last) q7 = q0;
            int p0 = s_pp[q0], p1 = s_pp[q1], p2 = s_pp[q2], p3 = s_pp[q3];
            int p4 = s_pp[q4], p5 = s_pp[q5], p6 = s_pp[q6], p7 = s_pp[q7];
            u64 v0 = bm[rowoff(p0) + (cbc - (p0 >> 6))];
            u64 v1 = bm[rowoff(p1) + (cbc - (p1 >> 6))];
            u64 v2 = bm[rowoff(p2) + (cbc - (p2 >> 6))];
            u64 v3 = bm[rowoff(p3) + (cbc - (p3 >> 6))];
            u64 v4 = bm[rowoff(p4) + (cbc - (p4 >> 6))];
            u64 v5 = bm[rowoff(p5) + (cbc - (p5 >> 6))];
            u64 v6 = bm[rowoff(p6) + (cbc - (p6 >> 6))];
            u64 v7 = bm[rowoff(p7) + (cbc - (p7 >> 6))];
            acc |= ((v0 | v1) | (v2 | v3)) | ((v4 | v5) | (v6 | v7));
        }
        acc &= amask;
        if (act && acc) atomicOr(&s_S[cb], acc);
    }
    WG_SYNC();

    int rb = rb0;
    for (; rb < rb1; ++rb) {
        int K = s_K;                       // uniform (post-barrier)
        if (K >= POST_TOPN) break;
        int base = rb * 64;
        bool havenext = (rb + 1 < rb1);
        int pq = (rb + 1) & 1;             // parity of block rb-1

        if (wv == 0) {
            // early prefetch of next diagonal row+box (coalesced diag[])
            u64 nrow = 0;
            float4 nbox = make_float4(0.f, 0.f, 0.f, 0.f);
            if (havenext) {
                int rn = (rb + 1) * 64 + lane;
                nrow = dgb[rn];
                nbox = sbb[rn];
            }
            // delta reduce: picks of rb-1 suppression into cb=rb
            unsigned rlo = dpp_or16((unsigned)(delta & 0xffffffffULL));
            unsigned rhi = dpp_or16((unsigned)(delta >> 32));
            u64 dtot = ((u64)wave_or_from_rows(rhi) << 32) | wave_or_from_rows(rlo);
            u64 t4 = s_S[rb] | dtot;
            if (rb == NBLK - 1) t4 |= 0xFFFFFFFF00000000ULL;   // pad rows >= 12000
            unsigned tlo = (unsigned)__builtin_amdgcn_readfirstlane((int)(t4 & 0xffffffffULL));
            unsigned thi = (unsigned)__builtin_amdgcn_readfirstlane((int)(t4 >> 32));
            u64 alive = ~(((u64)thi << 32) | tlo);
            unsigned mlo = (unsigned)(myrow & 0xffffffffULL);
            unsigned mhi = (unsigned)(myrow >> 32);

            // ---- frontier-batched greedy (exact serial-greedy pick set) ----
            u64 picks = 0;
            int round = 0;
            while (alive) {
                if (round >= 8) {
                    // serial fallback for pathological chain depth
                    u64 cur = alive;
                    while (cur) {
                        int i = (int)__builtin_ctzll(cur);
                        picks |= 1ULL << i;
                        unsigned rl = (unsigned)__builtin_amdgcn_readlane((int)mlo, i);
                        unsigned rh = (unsigned)__builtin_amdgcn_readlane((int)mhi, i);
                        u64 row = ((u64)rh << 32) | rl;
                        alive &= ~row;
                        cur = alive & ~((2ULL << i) - 1ULL);
                    }
                    break;
                }
                bool isal = ((alive >> lane) & 1ULL) != 0ULL;
                unsigned clo = isal ? mlo : 0u;
                unsigned chi = isal ? mhi : 0u;
                unsigned plo = wave_incl_prefix_or(clo);
                unsigned phi = wave_incl_prefix_or(chi);
                u64 pre = ((u64)phi << 32) | plo;
                bool infront = isal && (((pre >> lane) & 1ULL) == 0ULL);
                u64 front = __ballot(infront);
                picks |= front;
                unsigned slo = infront ? mlo : 0u;
                unsigned shi = infront ? mhi : 0u;
                slo = dpp_or16(slo); shi = dpp_or16(shi);
                u64 sup = ((u64)wave_or_from_rows(shi) << 32) | wave_or_from_rows(slo);
                alive &= ~(front | sup);
                ++round;
            }

            int avail = POST_TOPN - K;
            int np = __popcll(picks);
            while (np > avail) {                       // truncate latest picks
                picks &= ~(1ULL << (63 - __clzll(picks)));
                --np;
            }
            int c = lane;
            bool ipick = ((picks >> c) & 1ULL) != 0;
            delta = 0;
            if (ipick) {
                int rank = __popcll(picks & ((1ULL << c) - 1ULL));
                int p = base + c;
                s_prevpicks[rb & 1][rank] = p;
                pg[K + rank] = p;                      // persist pick row
                float* o = out + ((size_t)b * POST_TOPN + K + rank) * 5;
                o[0] = (float)b; o[1] = mybox.x; o[2] = mybox.y; o[3] = mybox.z; o[4] = mybox.w;
                if (havenext) delta = bm[rowoff(p) + 1];   // word (p, rb+1)
            }
            if (c == 0) {
                s_K = K + np;
                s_np[rb & 1] = np;
            }
            myrow = nrow; mybox = nbox;
        } else {
            // OR-step: tails of block rb-1's picks into cols [rb+1, rb1).
            // wave w: col-segment r=(w-1)%3, pick-stripe a=(w-1)/3 (of 5).
            int npp = s_np[pq];
            int len = rb1 - (rb + 1);
            int w = wv - 1;                   // 0..14
            int a3 = (w * 11) >> 5;           // w / 3
            int r3 = w - a3 * 3;              // w % 3
            if (npp > 0 && r3 * 64 < len) {
                const int* pp = s_prevpicks[pq];
                int ce = r3 * 64 + lane;
                bool act = (ce < len);
                u64 amask = act ? ~0ULL : 0ULL;
                int off = act ? (2 + ce) : 0;
                int last = npp - 1;
                u64 acc = 0;
                for (int q = a3; q < npp; q += 40) {
                    int q0 = q;
                    int q1 = q + 5;  if (q1 > last) q1 = q0;
                    int q2 = q + 10; if (q2 > last) q2 = q0;
                    int q3 = q + 15; if (q3 > last) q3 = q0;
                    int q4 = q + 20; if (q4 > last) q4 = q0;
                    int q5 = q + 25; if (q5 > last) q5 = q0;
                    int q6 = q + 30; if (q6 > last) q6 = q0;
                    int q7 = q + 35; if (q7 > last) q7 = q0;
                    u64 v0 = bm[rowoff(pp[q0]) + off];
                    u64 v1 = bm[rowoff(pp[q1]) + off];
                    u64 v2 = bm[rowoff(pp[q2]) + off];
                    u64 v3 = bm[rowoff(pp[q3]) + off];
                    u64 v4 = bm[rowoff(pp[q4]) + off];
                    u64 v5 = bm[rowoff(pp[q5]) + off];
                    u64 v6 = bm[rowoff(pp[q6]) + off];
                    u64 v7 = bm[rowoff(pp[q7]) + off];
                    acc |= ((v0 | v1) | (v2 | v3)) | ((v4 | v5) | (v6 | v7));
                }
                acc &= amask;
                if (act && acc) atomicOr(&s_S[rb + 1 + ce], acc);
            }
        }
        WG_SYNC();
    }

    int K = s_K;
    bool finished = (K >= POST_TOPN) || (rb1 >= NBLK);
    if (finished) {
        for (int r = K + tid; r < POST_TOPN; r += 1024) {
            float* o = out + ((size_t)b * POST_TOPN + r) * 5;
            o[0] = 0.0f; o[1] = 0.0f; o[2] = 0.0f; o[3] = 0.0f; o[4] = 0.0f;
        }
        if (tid == 0) done[b] = 1;
    } else {
        // persist running mask; picks of the last block get their tail
        // (cols >= rb1) OR'd by the NEXT stage's catch-up via picks_g.
        if (tid < NBLK) Sg[tid] = s_S[tid];
    }
    if (tid == 0) kcnt[b] = K;
}

// ---------------------------------------------------------------------------
// Fallback (round-2) NMS kernel — used only if ws_size can't hold the bitmap.
// ---------------------------------------------------------------------------
__global__ __launch_bounds__(1024) void nms_kernel(const float* __restrict__ boxes,
                                                   const u64* __restrict__ keys,
                                                   float* __restrict__ out,
                                                   int N) {
#pragma clang fp contract(off)
    __shared__ float4 kbox[POST_TOPN];
    __shared__ float kar[POST_TOPN];
    __shared__ float4 cbox[64];
    __shared__ float car_s[64];
    __shared__ int supp[64];
    __shared__ int s_cnt;

    int b = blockIdx.x;
    int tid = threadIdx.x;
    const u64* kb = keys + (size_t)b * SORTN;
    const float* bb = boxes + (size_t)b * N * 4;

    if (tid == 0) s_cnt = 0;
    __syncthreads();

    for (int start = 0; start < PRE_TOPN; start += 64) {
        int K = s_cnt;
        if (K >= POST_TOPN) break;
        int csize = min(64, PRE_TOPN - start);

        if (tid < 64) {
            int c = tid;
            if (c < csize) {
                u64 key = kb[start + c];
                int n = (int)(unsigned int)(key & 0xFFFFFFFFULL);
                const float* p = bb + (size_t)n * 4;
                float x1 = p[0], y1 = p[1], x2 = p[2], y2 = p[3];
                cbox[c] = make_float4(x1, y1, x2, y2);
                car_s[c] = ((x2 - x1) + 1.0f) * ((y2 - y1) + 1.0f);
            }
            supp[c] = 0;
        }
        __syncthreads();

        {
            int c = tid & 63;
            int sl = tid >> 6;
            if (c < csize) {
                float4 me = cbox[c];
                float ar = car_s[c];
                int flag = 0;
                for (int kk = sl; kk < K; kk += 16) {
                    float4 k0 = kbox[kk];
                    float a0 = kar[kk];
                    float xx1 = fmaxf(k0.x, me.x);
                    float yy1 = fmaxf(k0.y, me.y);
                    float xx2 = fminf(k0.z, me.z);
                    float yy2 = fminf(k0.w, me.w);
                    float w0 = fmaxf((xx2 - xx1) + 1.0f, 0.0f);
                    float h0 = fmaxf((yy2 - yy1) + 1.0f, 0.0f);
                    float inter0 = w0 * h0;
                    float iou0 = inter0 / ((a0 + ar) - inter0);
                    if (iou0 > 0.7f) { flag = 1; break; }
                }
                if (flag) supp[c] = 1;
            }
        }
        __syncthreads();

        if (tid < 64) {
            int c = tid;
            bool alive = (c < csize) && (supp[c] == 0);
            float4 me = cbox[c];
            float ar = car_s[c];
            int cnt = K;
            u64 m = __ballot(alive);
            while (m != 0 && cnt < POST_TOPN) {
                int i = __ffsll((unsigned long long)m) - 1;
                float ix1 = __shfl(me.x, i);
                float iy1 = __shfl(me.y, i);
                float ix2 = __shfl(me.z, i);
                float iy2 = __shfl(me.w, i);
                float iar = __shfl(ar, i);
                if (c == i) {
                    kbox[cnt] = me;
                    kar[cnt] = ar;
                    float* o = out + ((size_t)b * POST_TOPN + cnt) * 5;
                    o[0] = (float)b; o[1] = me.x; o[2] = me.y; o[3] = me.z; o[4] = me.w;
                }
                if (alive && c > i) {
                    float xx1 = fmaxf(ix1, me.x);
                    float yy1 = fmaxf(iy1, me.y);
                    float xx2 = fminf(ix2, me.z);
                    float yy2 = fminf(iy2, me.w);
                    float w = fmaxf((xx2 - xx1) + 1.0f, 0.0f);
                    float h = fmaxf((yy2 - yy1) + 1.0f, 0.0f);
                    float inter = w * h;
                    float iou = inter / ((iar + ar) - inter);
                    if (iou > 0.7f) alive = false;
                }
                cnt++;
                m = __ballot(alive);
                u64 clearmask = (2ULL << i) - 1ULL;
                m &= ~clearmask;
            }
            if (c == 0) s_cnt = cnt;
        }
        __syncthreads();
    }

    __syncthreads();
    int K = s_cnt;
    for (int r = K + tid; r < POST_TOPN; r += (int)blockDim.x) {
        float* o = out + ((size_t)b * POST_TOPN + r) * 5;
        o[0] = 0.0f; o[1] = 0.0f; o[2] = 0.0f; o[3] = 0.0f; o[4] = 0.0f;
    }
}

// ---------------------------------------------------------------------------
extern "C" void kernel_launch(void* const* d_in, const int* in_sizes, int n_in,
                              void* d_out, int out_size, void* d_ws, size_t ws_size,
                              hipStream_t stream) {
    const float* anchors = (const float*)d_in[0];
    const float* deltas  = (const float*)d_in[1];
    const float* scores  = (const float*)d_in[2];
    float* out = (float*)d_out;

    int N = in_sizes[0] / 4;           // 27380
    int B = in_sizes[2] / N;           // 8

    size_t off = 0;
    auto take = [&](size_t bytes) { size_t o = off; off = (off + bytes + 255) & ~(size_t)255; return o; };
    size_t boxesOff  = take((size_t)B * N * 4 * sizeof(float));
    size_t keysOff   = take((size_t)B * SORTN * sizeof(u64));
    size_t sboxOff   = take((size_t)B * PADN * sizeof(float4));
    size_t bitmapOff = take((size_t)B * TRI_WORDS * sizeof(u64));
    size_t diagOff   = take((size_t)B * PADN * sizeof(u64));
    size_t SgOff     = take((size_t)B * MASK_WORDS * sizeof(u64));
    size_t pgOff     = take((size_t)B * POST_TOPN * sizeof(int));
    size_t kcntOff   = take((size_t)B * sizeof(int));
    size_t doneOff   = take((size_t)B * sizeof(int));
    bool bitmap_path = (off <= ws_size);

    float* boxes = (float*)((char*)d_ws + boxesOff);
    u64*   keys  = (u64*)((char*)d_ws + keysOff);
    u64* diag    = bitmap_path ? (u64*)((char*)d_ws + diagOff)  : nullptr;
    u64* S_g     = bitmap_path ? (u64*)((char*)d_ws + SgOff)    : nullptr;
    int* pg      = bitmap_path ? (int*)((char*)d_ws + pgOff)    : nullptr;
    int* kcnt    = bitmap_path ? (int*)((char*)d_ws + kcntOff)  : nullptr;
    int* done    = bitmap_path ? (int*)((char*)d_ws + doneOff)  : nullptr;

    dim3 g1((unsigned)((SORTN + 255) / 256), (unsigned)B);
    decode_pack<<<g1, 256, 0, stream>>>(anchors, deltas, scores, boxes, keys, kcnt, done, N);

    int ntiles = B * NTILE;
    bitonic_local_sort<<<ntiles, 1024, 0, stream>>>(keys);
    int gsteps = B * (SORTN / 2) / 256;
    bitonic_global_step<<<gsteps, 256, 0, stream>>>(keys, 2 * TILE, TILE);
    bitonic_local_merge<<<ntiles, 1024, 0, stream>>>(keys, 2 * TILE);
    bitonic_global_step<<<gsteps, 256, 0, stream>>>(keys, 4 * TILE, 2 * TILE);
    bitonic_global_step<<<gsteps, 256, 0, stream>>>(keys, 4 * TILE, TILE);
    bitonic_local_merge<<<ntiles, 1024, 0, stream>>>(keys, 4 * TILE);

    if (bitmap_path) {
        float4* sbox = (float4*)((char*)d_ws + sboxOff);
        u64* bitmap  = (u64*)((char*)d_ws + bitmapOff);
        dim3 gg((unsigned)((PADN + 255) / 256), (unsigned)B);
        gather_sorted<<<gg, 256, 0, stream>>>(boxes, keys, sbox, N);

        // Progressive build/scan with per-batch done[] cutoff. Segments in
        // col-block units (even; widths <= 128 per the catch-up's 2-segment
        // mapping).
        const int seg[6] = {0, 48, 64, 88, 120, NBLK};
        for (int s = 0; s < 5; ++s) {
            int c0 = seg[s], c1 = seg[s + 1];
            int p0 = c0 / 2;
            int npair = (c1 - c0) / 2;
            unsigned gy = (unsigned)(((c1 / 2 - 1) >> 1) + 1);   // 256-row chunks
            dim3 gb((unsigned)npair, gy, (unsigned)B);
            build_bitmap<<<gb, 256, 0, stream>>>(sbox, bitmap, diag, done, p0);
            scan_nms<<<B, 1024, 0, stream>>>(sbox, bitmap, diag, out, S_g, pg, kcnt, done, c0, c1);
        }
    } else {
        nms_kernel<<<B, 1024, 0, stream>>>(boxes, keys, out, N);
    }
}

// Round 9
// 256.230 us; speedup vs baseline: 3.3837x; 1.0884x over previous
//
#include <hip/hip_runtime.h>
#include <cmath>

typedef unsigned long long u64;

#define PRE_TOPN 12000
#define POST_TOPN 2000
#define SORTN 32768
#define TILE 2048              // local-sort tile (round-14: was 8192)
#define NTILE (SORTN / TILE)   // 16 tiles per batch
#define NBLK 188               // 64-bit column blocks covering 12032
#define PADN (NBLK * 64)       // 12032
// ROW-MAJOR triangular bitmap: row r stores words for col-blocks
// cb in [r/64, NBLK) contiguously at rowoff(r). Total words per batch:
#define TRI_WORDS (32 * (NBLK - 1) * NBLK + NBLK * 64)  // 1,137,024
#define MASK_WORDS 192         // 188 used, padded

// Light workgroup barrier: orders LDS (lgkmcnt) but lets global loads stay
// in flight across the barrier.
#define WG_SYNC() asm volatile("s_waitcnt lgkmcnt(0)\n\ts_barrier" ::: "memory")

__device__ __forceinline__ int rowoff(int r) {
    int rb = r >> 6;
    int q = r & 63;
    return r * NBLK - (32 * rb * (rb - 1) + q * rb);
}

// ---------------------------------------------------------------------------
// Kernel 1: decode boxes (exact fp32 op order, no FMA contraction, exp via
// double) and pack sort keys. key = (~score_bits)<<32 | idx.
// Also resets the per-batch NMS progress state (kcnt/done) for this launch.
// ---------------------------------------------------------------------------
__global__ void decode_pack(const float* __restrict__ anchors,
                            const float* __restrict__ deltas,
                            const float* __restrict__ scores,
                            float* __restrict__ boxes,
                            u64* __restrict__ keys,
                            int* __restrict__ kcnt,
                            int* __restrict__ done,
                            int N) {
#pragma clang fp contract(off)
    int n = blockIdx.x * blockDim.x + threadIdx.x;
    int b = blockIdx.y;
    if (kcnt != nullptr && blockIdx.x == 0 && threadIdx.x == 0) {
        kcnt[b] = 0;
        done[b] = 0;
    }
    if (n >= SORTN) return;
    u64* kb = keys + (size_t)b * SORTN;
    if (n < N) {
        float a0 = anchors[n * 4 + 0];
        float a1 = anchors[n * 4 + 1];
        float a2 = anchors[n * 4 + 2];
        float a3 = anchors[n * 4 + 3];
        float w = (a2 - a0) + 1.0f;
        float h = (a3 - a1) + 1.0f;
        float cx = a0 + 0.5f * w;
        float cy = a1 + 0.5f * h;
        const float* d = deltas + ((size_t)b * N + n) * 4;
        float dx = d[0], dy = d[1], dw = d[2], dh = d[3];
        float px = cx + w * dx;
        float py = cy + h * dy;
        float pw = (float)::exp((double)dw) * w;
        float ph = (float)::exp((double)dh) * h;
        float* bb = boxes + ((size_t)b * N + n) * 4;
        bb[0] = px - 0.5f * pw;
        bb[1] = py - 0.5f * ph;
        bb[2] = px + 0.5f * (pw - 2.0f);
        bb[3] = py + 0.5f * (ph - 2.0f);
        unsigned int sb = __float_as_uint(scores[(size_t)b * N + n]);
        kb[n] = ((u64)(~sb) << 32) | (u64)(unsigned int)n;
    } else {
        kb[n] = ~0ULL;
    }
}

// ---------------------------------------------------------------------------
// Hybrid bitonic sort, round-14 rebalance: 2048-element tiles (128 blocks,
// 4x CU coverage vs the old 8192/32) + register-orbit fused global steps.
// ---------------------------------------------------------------------------
__global__ __launch_bounds__(256) void bitonic_local_sort(u64* __restrict__ keys) {
    __shared__ u64 sk[TILE];
    int tile = blockIdx.x;
    u64* kb = keys + (size_t)tile * TILE;
    int base = (tile % NTILE) * TILE;
    for (int i = threadIdx.x; i < TILE; i += 256) sk[i] = kb[i];
    __syncthreads();
    for (int k = 2; k <= TILE; k <<= 1) {
        for (int j = k >> 1; j > 0; j >>= 1) {
            for (int t = threadIdx.x; t < TILE / 2; t += 256) {
                int i = ((t & ~(j - 1)) << 1) | (t & (j - 1));
                int ixj = i | j;
                u64 a = sk[i];
                u64 c = sk[ixj];
                bool up = (((base + i) & k) == 0);
                if ((a > c) == up) { sk[i] = c; sk[ixj] = a; }
            }
            __syncthreads();
        }
    }
    for (int i = threadIdx.x; i < TILE; i += 256) kb[i] = sk[i];
}

// Fused global steps for level k = TILE<<G: all strides j = k/2 .. TILE in
// ONE dispatch. Element indices varying bits 11..11+G-1 form an XOR-orbit of
// 2^G elements held in registers (compile-time G -> static indices, no
// scratch). Direction bit (index & k) is orbit-uniform (bit 11+G). Loads and
// stores are coalesced per slice (consecutive threads -> consecutive low
// bits).
template<int G>
__global__ __launch_bounds__(256) void bitonic_fused_global(u64* __restrict__ keys) {
    const int K = TILE << G;
    const int M = 1 << G;
    int nbase = SORTN >> G;                  // base indices per batch
    int t = blockIdx.x * 256 + threadIdx.x;  // over B*nbase
    int b = t / nbase;
    int r = t % nbase;
    int low = r & (TILE - 1);
    int high = (r >> 11) << (11 + G);
    int base = high | low;
    u64* kb = keys + (size_t)b * SORTN;
    bool up = ((base & K) == 0);
    u64 e[M];
#pragma unroll
    for (int m = 0; m < M; ++m) e[m] = kb[base + (m << 11)];
#pragma unroll
    for (int s = G - 1; s >= 0; --s) {
        const int bit = 1 << s;
#pragma unroll
        for (int m = 0; m < M; ++m) {
            if (!(m & bit)) {
                u64 a = e[m], c = e[m | bit];
                if ((a > c) == up) { e[m] = c; e[m | bit] = a; }
            }
        }
    }
#pragma unroll
    for (int m = 0; m < M; ++m) kb[base + (m << 11)] = e[m];
}

__global__ __launch_bounds__(256) void bitonic_local_merge(u64* __restrict__ keys, int k) {
    __shared__ u64 sk[TILE];
    int tile = blockIdx.x;
    u64* kb = keys + (size_t)tile * TILE;
    int base = (tile % NTILE) * TILE;
    bool up = ((base & k) == 0);
    for (int i = threadIdx.x; i < TILE; i += 256) sk[i] = kb[i];
    __syncthreads();
    for (int j = TILE / 2; j > 0; j >>= 1) {
        for (int t = threadIdx.x; t < TILE / 2; t += 256) {
            int i = ((t & ~(j - 1)) << 1) | (t & (j - 1));
            int ixj = i | j;
            u64 a = sk[i];
            u64 c = sk[ixj];
            if ((a > c) == up) { sk[i] = c; sk[ixj] = a; }
        }
        __syncthreads();
    }
    for (int i = threadIdx.x; i < TILE; i += 256) kb[i] = sk[i];
}

// ---------------------------------------------------------------------------
// Gather sorted top-PADN boxes. Pad rows get far-away degenerate boxes.
// ---------------------------------------------------------------------------
__global__ void gather_sorted(const float* __restrict__ boxes,
                              const u64* __restrict__ keys,
                              float4* __restrict__ sbox, int N) {
    int r = blockIdx.x * 256 + threadIdx.x;
    int b = blockIdx.y;
    if (r >= PADN) return;
    float4 v;
    if (r < PRE_TOPN) {
        u64 key = keys[(size_t)b * SORTN + r];
        int n = (int)(unsigned)(key & 0xffffffffULL);
        v = ((const float4*)boxes)[(size_t)b * N + n];
    } else {
        v = make_float4(-4e8f, -4e8f, -4e8f, -4e8f);
    }
    sbox[(size_t)b * PADN + r] = v;
}

// ---------------------------------------------------------------------------
// Exact-f32 suppression predicate (bit-identical to the f64 reference test).
// ---------------------------------------------------------------------------
__device__ __forceinline__ void iou_bit(float4 me, float ar, float4 cj, float aj,
                                        int j, unsigned& lo, unsigned& hi, int& tie) {
#pragma clang fp contract(off)
    float xx1 = fmaxf(me.x, cj.x);
    float yy1 = fmaxf(me.y, cj.y);
    float xx2 = fminf(me.z, cj.z);
    float yy2 = fminf(me.w, cj.w);
    float w = fmaxf((xx2 - xx1) + 1.0f, 0.0f);
    float h = fmaxf((yy2 - yy1) + 1.0f, 0.0f);
    float inter = w * h;
    float un = (ar + aj) - inter;
    float t = __builtin_fmaf(-0.7f, un, inter);
    float u25 = un * 0x1p-25f;
    unsigned sup = (t > u25) ? 1u : 0u;
    tie |= (t == u25) ? 1 : 0;
    if (j < 32) lo |= sup << j;
    else        hi |= sup << (j - 32);
}

__device__ __attribute__((noinline)) u64 slow_word(float4 me, float ar,
                                                   const float4* cbox,
                                                   const float* carea) {
#pragma clang fp contract(off)
    const double MD = (double)0.7f + 0x1p-25;   // exact midpoint multiplier
    u64 word = 0;
    for (int j = 0; j < 64; ++j) {
        float4 cj = cbox[j];
        float aj = carea[j];
        float xx1 = fmaxf(me.x, cj.x);
        float yy1 = fmaxf(me.y, cj.y);
        float xx2 = fminf(me.z, cj.z);
        float yy2 = fminf(me.w, cj.w);
        float w = fmaxf((xx2 - xx1) + 1.0f, 0.0f);
        float h = fmaxf((yy2 - yy1) + 1.0f, 0.0f);
        float inter = w * h;
        float un = (ar + aj) - inter;
        bool sup = ((double)inter >= MD * (double)un);
        word |= ((u64)sup) << j;
    }
    return word;
}

// ---------------------------------------------------------------------------
// Build ROW-MAJOR suppression bitmap for col-block pairs [pair0, ...).
// Diagonal words are ALSO written to the contiguous diag[] array.
// ---------------------------------------------------------------------------
__global__ __launch_bounds__(256) void build_bitmap(const float4* __restrict__ sbox,
                                                    u64* __restrict__ bitmap,
                                                    u64* __restrict__ diag,
                                                    const int* __restrict__ done,
                                                    int pair0) {
    int pair = pair0 + blockIdx.x;   // covers cbs 2*pair, 2*pair+1
    int chunk = blockIdx.y;          // 256-row chunk
    int b = blockIdx.z;
    if (done[b]) return;
    if (2 * chunk > pair) return;    // chunk's first row >= (2p+2)*64 -> empty
    int tid = threadIdx.x;
    int w = tid & 1;
    int cb = pair * 2 + w;
    int lim = (cb + 1) * 64;         // rows with words in column-block cb

    __shared__ float4 cbox[2][64];
    __shared__ float carea[2][64];
    const float4* sb = sbox + (size_t)b * PADN;
    if (tid < 128) {
        int which = tid >> 6, j = tid & 63;
        float4 c4 = sb[(pair * 2 + which) * 64 + j];
        cbox[which][j] = c4;
        carea[which][j] = ((c4.z - c4.x) + 1.0f) * ((c4.w - c4.y) + 1.0f);
    }
    int rl = tid >> 1;               // 0..127
    int r1 = chunk * 256 + rl;       // <= 46*256+127 = 11903 < PADN
    int r2 = r1 + 128;               // <= 12031 < PADN
    bool a1 = (r1 < lim);
    bool a2 = (r2 < lim);
    float4 me1 = sb[r1];
    float4 me2 = sb[r2];
    float ar1 = ((me1.z - me1.x) + 1.0f) * ((me1.w - me1.y) + 1.0f);
    float ar2 = ((me2.z - me2.x) + 1.0f) * ((me2.w - me2.y) + 1.0f);
    __syncthreads();

    u64* dgb = diag + (size_t)b * PADN;
    if (a1) {
        unsigned lo1 = 0, hi1 = 0;
        int tie1 = 0;
#pragma unroll
        for (int j = 0; j < 64; ++j) {
            iou_bit(me1, ar1, cbox[w][j], carea[w][j], j, lo1, hi1, tie1);
        }
        u64 w1 = ((u64)hi1 << 32) | lo1;
        if (__builtin_expect(tie1, 0)) w1 = slow_word(me1, ar1, cbox[w], carea[w]);
        int d1 = r1 - cb * 64;
        if (d1 >= 0) {                               // diagonal block word
            w1 &= ~((2ULL << d1) - 1ULL);
            dgb[r1] = w1;
        }
        bitmap[(size_t)b * TRI_WORDS + rowoff(r1) + (cb - (r1 >> 6))] = w1;
    }
    if (a2) {
        unsigned lo2 = 0, hi2 = 0;
        int tie2 = 0;
#pragma unroll
        for (int j = 0; j < 64; ++j) {
            iou_bit(me2, ar2, cbox[w][j], carea[w][j], j, lo2, hi2, tie2);
        }
        u64 w2 = ((u64)hi2 << 32) | lo2;
        if (__builtin_expect(tie2, 0)) w2 = slow_word(me2, ar2, cbox[w], carea[w]);
        int d2 = r2 - cb * 64;
        if (d2 >= 0) {
            w2 &= ~((2ULL << d2) - 1ULL);
            dgb[r2] = w2;
        }
        bitmap[(size_t)b * TRI_WORDS + rowoff(r2) + (cb - (r2 >> 6))] = w2;
    }
}

// ---------------------------------------------------------------------------
// DPP helpers: 16-lane OR-reduce, wave total via readlanes, and the
// canonical 64-lane inclusive prefix-OR scan.
// ---------------------------------------------------------------------------
__device__ __forceinline__ unsigned dpp_or16(unsigned v) {
    v |= (unsigned)__builtin_amdgcn_update_dpp(0, (int)v, 0xB1, 0xF, 0xF, true);   // quad_perm {1,0,3,2}
    v |= (unsigned)__builtin_amdgcn_update_dpp(0, (int)v, 0x4E, 0xF, 0xF, true);   // quad_perm {2,3,0,1}
    v |= (unsigned)__builtin_amdgcn_update_dpp(0, (int)v, 0x141, 0xF, 0xF, true);  // row_half_mirror
    v |= (unsigned)__builtin_amdgcn_update_dpp(0, (int)v, 0x140, 0xF, 0xF, true);  // row_mirror
    return v;
}

__device__ __forceinline__ unsigned wave_or_from_rows(unsigned rowred) {
    unsigned a = (unsigned)__builtin_amdgcn_readlane((int)rowred, 0) |
                 (unsigned)__builtin_amdgcn_readlane((int)rowred, 16);
    unsigned c = (unsigned)__builtin_amdgcn_readlane((int)rowred, 32) |
                 (unsigned)__builtin_amdgcn_readlane((int)rowred, 48);
    return a | c;
}

__device__ __forceinline__ unsigned wave_incl_prefix_or(unsigned v) {
    v |= (unsigned)__builtin_amdgcn_update_dpp(0, (int)v, 0x111, 0xF, 0xF, true);  // row_shr:1
    v |= (unsigned)__builtin_amdgcn_update_dpp(0, (int)v, 0x112, 0xF, 0xF, true);  // row_shr:2
    v |= (unsigned)__builtin_amdgcn_update_dpp(0, (int)v, 0x114, 0xF, 0xF, true);  // row_shr:4
    v |= (unsigned)__builtin_amdgcn_update_dpp(0, (int)v, 0x118, 0xF, 0xF, true);  // row_shr:8
    v |= (unsigned)__builtin_amdgcn_update_dpp(0, (int)v, 0x142, 0xA, 0xF, true);  // row_bcast:15 -> rows 1,3
    v |= (unsigned)__builtin_amdgcn_update_dpp(0, (int)v, 0x143, 0xC, 0xF, true);  // row_bcast:31 -> rows 2,3
    return v;
}

// ---------------------------------------------------------------------------
// Resumable scan (round-13 structure, unchanged this round): incremental
// suppression mask + frontier-batched greedy + catch-up invariant.
// ---------------------------------------------------------------------------
__global__ __launch_bounds__(1024) void scan_nms(const float4* __restrict__ sbox,
                                                 const u64* __restrict__ bitmap,
                                                 const u64* __restrict__ diag,
                                                 float* __restrict__ out,
                                                 u64* __restrict__ S_g,
                                                 int* __restrict__ picks_g,
                                                 int* __restrict__ kcnt,
                                                 int* __restrict__ done,
                                                 int rb0, int rb1) {
    int b = blockIdx.x;
    if (done[b]) return;
    int tid = threadIdx.x;
    int lane = tid & 63;
    int wv = tid >> 6;                     // 0..15
    __shared__ u64 s_S[MASK_WORDS];        // 1.5 KB running suppression mask
    __shared__ int s_pp[POST_TOPN];        // 8 KB committed pick rows
    __shared__ int s_prevpicks[2][64];
    __shared__ int s_np[2];
    __shared__ int s_K;

    u64* Sg = S_g + (size_t)b * MASK_WORDS;
    int* pg = picks_g + (size_t)b * POST_TOPN;
    int K0 = kcnt[b];
    if (tid == 0) s_K = K0;
    if (tid < 2) s_np[tid] = 0;
    if (tid < MASK_WORDS) s_S[tid] = (tid < NBLK && rb0 > 0) ? Sg[tid] : 0ULL;
    for (int t = tid; t < K0; t += 1024) s_pp[t] = pg[t];
    WG_SYNC();

    const u64* bm = bitmap + (size_t)b * TRI_WORDS;
    const u64* dgb = diag + (size_t)b * PADN;
    const float4* sbb = sbox + (size_t)b * PADN;

    u64 myrow = 0, delta = 0;
    float4 mybox = make_float4(0.f, 0.f, 0.f, 0.f);
    if (wv == 0) {
        // prologue diag row + box for rb0 (coalesced; overlaps catch-up)
        int r = rb0 * 64 + lane;
        myrow = dgb[r];
        mybox = sbb[r];
    } else if (rb0 > 0 && K0 > 0) {
        // ---- CATCH-UP: cols [rb0, rb1) x all K0 prior picks ----
        int width = rb1 - rb0;             // <= 128 by stage construction
        int nseg2 = (width + 63) >> 6;     // 1 or 2
        int w = wv - 1;                    // 0..14
        int s2, str, nstr;
        if (nseg2 == 2) { s2 = w & 1; str = w >> 1; nstr = (s2 == 0) ? 8 : 7; }
        else            { s2 = 0;     str = w;      nstr = 15; }
        int ce = s2 * 64 + lane;
        bool act = (ce < width);
        u64 amask = act ? ~0ULL : 0ULL;
        int cb = rb0 + ce;
        int cbc = act ? cb : rb0;
        u64 acc = 0;
        int last = K0 - 1;
        for (int q = str; q < K0; q += 8 * nstr) {
            int q0 = q;
            int q1 = q + nstr;     if (q1 > last) q1 = q0;
            int q2 = q + 2 * nstr; if (q2 > last) q2 = q0;
            int q3 = q + 3 * nstr; if (q3 > last) q3 = q0;
            int q4 = q + 4 * nstr; if (q4 > last) q4 = q0;
            int q5 = q + 5 * nstr; if (q5 > last) q5 = q0;
            int q6 = q + 6 * nstr; if (q6 > last) q6 = q0;
            int q7 = q + 7 * nstr; if (q7 > last) q7 = q0;
            int p0 = s_pp[q0], p1 = s_pp[q1], p2 = s_pp[q2], p3 = s_pp[q3];
            int p4 = s_pp[q4], p5 = s_pp[q5], p6 = s_pp[q6], p7 = s_pp[q7];
            u64 v0 = bm[rowoff(p0) + (cbc - (p0 >> 6))];
            u64 v1 = bm[rowoff(p1) + (cbc - (p1 >> 6))];
            u64 v2 = bm[rowoff(p2) + (cbc - (p2 >> 6))];
            u64 v3 = bm[rowoff(p3) + (cbc - (p3 >> 6))];
            u64 v4 = bm[rowoff(p4) + (cbc - (p4 >> 6))];
            u64 v5 = bm[rowoff(p5) + (cbc - (p5 >> 6))];
            u64 v6 = bm[rowoff(p6) + (cbc - (p6 >> 6))];
            u64 v7 = bm[rowoff(p7) + (cbc - (p7 >> 6))];
            acc |= ((v0 | v1) | (v2 | v3)) | ((v4 | v5) | (v6 | v7));
        }
        acc &= amask;
        if (act && acc) atomicOr(&s_S[cb], acc);
    }
    WG_SYNC();

    int rb = rb0;
    for (; rb < rb1; ++rb) {
        int K = s_K;                       // uniform (post-barrier)
        if (K >= POST_TOPN) break;
        int base = rb * 64;
        bool havenext = (rb + 1 < rb1);
        int pq = (rb + 1) & 1;             // parity of block rb-1

        if (wv == 0) {
            // early prefetch of next diagonal row+box (coalesced diag[])
            u64 nrow = 0;
            float4 nbox = make_float4(0.f, 0.f, 0.f, 0.f);
            if (havenext) {
                int rn = (rb + 1) * 64 + lane;
                nrow = dgb[rn];
                nbox = sbb[rn];
            }
            // delta reduce: picks of rb-1 suppression into cb=rb
            unsigned rlo = dpp_or16((unsigned)(delta & 0xffffffffULL));
            unsigned rhi = dpp_or16((unsigned)(delta >> 32));
            u64 dtot = ((u64)wave_or_from_rows(rhi) << 32) | wave_or_from_rows(rlo);
            u64 t4 = s_S[rb] | dtot;
            if (rb == NBLK - 1) t4 |= 0xFFFFFFFF00000000ULL;   // pad rows >= 12000
            unsigned tlo = (unsigned)__builtin_amdgcn_readfirstlane((int)(t4 & 0xffffffffULL));
            unsigned thi = (unsigned)__builtin_amdgcn_readfirstlane((int)(t4 >> 32));
            u64 alive = ~(((u64)thi << 32) | tlo);
            unsigned mlo = (unsigned)(myrow & 0xffffffffULL);
            unsigned mhi = (unsigned)(myrow >> 32);

            // ---- frontier-batched greedy (exact serial-greedy pick set) ----
            u64 picks = 0;
            int round = 0;
            while (alive) {
                if (round >= 8) {
                    // serial fallback for pathological chain depth
                    u64 cur = alive;
                    while (cur) {
                        int i = (int)__builtin_ctzll(cur);
                        picks |= 1ULL << i;
                        unsigned rl = (unsigned)__builtin_amdgcn_readlane((int)mlo, i);
                        unsigned rh = (unsigned)__builtin_amdgcn_readlane((int)mhi, i);
                        u64 row = ((u64)rh << 32) | rl;
                        alive &= ~row;
                        cur = alive & ~((2ULL << i) - 1ULL);
                    }
                    break;
                }
                bool isal = ((alive >> lane) & 1ULL) != 0ULL;
                unsigned clo = isal ? mlo : 0u;
                unsigned chi = isal ? mhi : 0u;
                unsigned plo = wave_incl_prefix_or(clo);
                unsigned phi = wave_incl_prefix_or(chi);
                u64 pre = ((u64)phi << 32) | plo;
                bool infront = isal && (((pre >> lane) & 1ULL) == 0ULL);
                u64 front = __ballot(infront);
                picks |= front;
                unsigned slo = infront ? mlo : 0u;
                unsigned shi = infront ? mhi : 0u;
                slo = dpp_or16(slo); shi = dpp_or16(shi);
                u64 sup = ((u64)wave_or_from_rows(shi) << 32) | wave_or_from_rows(slo);
                alive &= ~(front | sup);
                ++round;
            }

            int avail = POST_TOPN - K;
            int np = __popcll(picks);
            while (np > avail) {                       // truncate latest picks
                picks &= ~(1ULL << (63 - __clzll(picks)));
                --np;
            }
            int c = lane;
            bool ipick = ((picks >> c) & 1ULL) != 0;
            delta = 0;
            if (ipick) {
                int rank = __popcll(picks & ((1ULL << c) - 1ULL));
                int p = base + c;
                s_prevpicks[rb & 1][rank] = p;
                pg[K + rank] = p;                      // persist pick row
                float* o = out + ((size_t)b * POST_TOPN + K + rank) * 5;
                o[0] = (float)b; o[1] = mybox.x; o[2] = mybox.y; o[3] = mybox.z; o[4] = mybox.w;
                if (havenext) delta = bm[rowoff(p) + 1];   // word (p, rb+1)
            }
            if (c == 0) {
                s_K = K + np;
                s_np[rb & 1] = np;
            }
            myrow = nrow; mybox = nbox;
        } else {
            // OR-step: tails of block rb-1's picks into cols [rb+1, rb1).
            // wave w: col-segment r=(w-1)%3, pick-stripe a=(w-1)/3 (of 5).
            int npp = s_np[pq];
            int len = rb1 - (rb + 1);
            int w = wv - 1;                   // 0..14
            int a3 = (w * 11) >> 5;           // w / 3
            int r3 = w - a3 * 3;              // w % 3
            if (npp > 0 && r3 * 64 < len) {
                const int* pp = s_prevpicks[pq];
                int ce = r3 * 64 + lane;
                bool act = (ce < len);
                u64 amask = act ? ~0ULL : 0ULL;
                int off = act ? (2 + ce) : 0;
                int last = npp - 1;
                u64 acc = 0;
                for (int q = a3; q < npp; q += 40) {
                    int q0 = q;
                    int q1 = q + 5;  if (q1 > last) q1 = q0;
                    int q2 = q + 10; if (q2 > last) q2 = q0;
                    int q3 = q + 15; if (q3 > last) q3 = q0;
                    int q4 = q + 20; if (q4 > last) q4 = q0;
                    int q5 = q + 25; if (q5 > last) q5 = q0;
                    int q6 = q + 30; if (q6 > last) q6 = q0;
                    int q7 = q + 35; if (q7 > last) q7 = q0;
                    u64 v0 = bm[rowoff(pp[q0]) + off];
                    u64 v1 = bm[rowoff(pp[q1]) + off];
                    u64 v2 = bm[rowoff(pp[q2]) + off];
                    u64 v3 = bm[rowoff(pp[q3]) + off];
                    u64 v4 = bm[rowoff(pp[q4]) + off];
                    u64 v5 = bm[rowoff(pp[q5]) + off];
                    u64 v6 = bm[rowoff(pp[q6]) + off];
                    u64 v7 = bm[rowoff(pp[q7]) + off];
                    acc |= ((v0 | v1) | (v2 | v3)) | ((v4 | v5) | (v6 | v7));
                }
                acc &= amask;
                if (act && acc) atomicOr(&s_S[rb + 1 + ce], acc);
            }
        }
        WG_SYNC();
    }

    int K = s_K;
    bool finished = (K >= POST_TOPN) || (rb1 >= NBLK);
    if (finished) {
        for (int r = K + tid; r < POST_TOPN; r += 1024) {
            float* o = out + ((size_t)b * POST_TOPN + r) * 5;
            o[0] = 0.0f; o[1] = 0.0f; o[2] = 0.0f; o[3] = 0.0f; o[4] = 0.0f;
        }
        if (tid == 0) done[b] = 1;
    } else {
        // persist running mask; picks of the last block get their tail
        // (cols >= rb1) OR'd by the NEXT stage's catch-up via picks_g.
        if (tid < NBLK) Sg[tid] = s_S[tid];
    }
    if (tid == 0) kcnt[b] = K;
}

// ---------------------------------------------------------------------------
// Fallback (round-2) NMS kernel — used only if ws_size can't hold the bitmap.
// ---------------------------------------------------------------------------
__global__ __launch_bounds__(1024) void nms_kernel(const float* __restrict__ boxes,
                                                   const u64* __restrict__ keys,
                                                   float* __restrict__ out,
                                                   int N) {
#pragma clang fp contract(off)
    __shared__ float4 kbox[POST_TOPN];
    __shared__ float kar[POST_TOPN];
    __shared__ float4 cbox[64];
    __shared__ float car_s[64];
    __shared__ int supp[64];
    __shared__ int s_cnt;

    int b = blockIdx.x;
    int tid = threadIdx.x;
    const u64* kb = keys + (size_t)b * SORTN;
    const float* bb = boxes + (size_t)b * N * 4;

    if (tid == 0) s_cnt = 0;
    __syncthreads();

    for (int start = 0; start < PRE_TOPN; start += 64) {
        int K = s_cnt;
        if (K >= POST_TOPN) break;
        int csize = min(64, PRE_TOPN - start);

        if (tid < 64) {
            int c = tid;
            if (c < csize) {
                u64 key = kb[start + c];
                int n = (int)(unsigned int)(key & 0xFFFFFFFFULL);
                const float* p = bb + (size_t)n * 4;
                float x1 = p[0], y1 = p[1], x2 = p[2], y2 = p[3];
                cbox[c] = make_float4(x1, y1, x2, y2);
                car_s[c] = ((x2 - x1) + 1.0f) * ((y2 - y1) + 1.0f);
            }
            supp[c] = 0;
        }
        __syncthreads();

        {
            int c = tid & 63;
            int sl = tid >> 6;
            if (c < csize) {
                float4 me = cbox[c];
                float ar = car_s[c];
                int flag = 0;
                for (int kk = sl; kk < K; kk += 16) {
                    float4 k0 = kbox[kk];
                    float a0 = kar[kk];
                    float xx1 = fmaxf(k0.x, me.x);
                    float yy1 = fmaxf(k0.y, me.y);
                    float xx2 = fminf(k0.z, me.z);
                    float yy2 = fminf(k0.w, me.w);
                    float w0 = fmaxf((xx2 - xx1) + 1.0f, 0.0f);
                    float h0 = fmaxf((yy2 - yy1) + 1.0f, 0.0f);
                    float inter0 = w0 * h0;
                    float iou0 = inter0 / ((a0 + ar) - inter0);
                    if (iou0 > 0.7f) { flag = 1; break; }
                }
                if (flag) supp[c] = 1;
            }
        }
        __syncthreads();

        if (tid < 64) {
            int c = tid;
            bool alive = (c < csize) && (supp[c] == 0);
            float4 me = cbox[c];
            float ar = car_s[c];
            int cnt = K;
            u64 m = __ballot(alive);
            while (m != 0 && cnt < POST_TOPN) {
                int i = __ffsll((unsigned long long)m) - 1;
                float ix1 = __shfl(me.x, i);
                float iy1 = __shfl(me.y, i);
                float ix2 = __shfl(me.z, i);
                float iy2 = __shfl(me.w, i);
                float iar = __shfl(ar, i);
                if (c == i) {
                    kbox[cnt] = me;
                    kar[cnt] = ar;
                    float* o = out + ((size_t)b * POST_TOPN + cnt) * 5;
                    o[0] = (float)b; o[1] = me.x; o[2] = me.y; o[3] = me.z; o[4] = me.w;
                }
                if (alive && c > i) {
                    float xx1 = fmaxf(ix1, me.x);
                    float yy1 = fmaxf(iy1, me.y);
                    float xx2 = fminf(ix2, me.z);
                    float yy2 = fminf(iy2, me.w);
                    float w = fmaxf((xx2 - xx1) + 1.0f, 0.0f);
                    float h = fmaxf((yy2 - yy1) + 1.0f, 0.0f);
                    float inter = w * h;
                    float iou = inter / ((iar + ar) - inter);
                    if (iou > 0.7f) alive = false;
                }
                cnt++;
                m = __ballot(alive);
                u64 clearmask = (2ULL << i) - 1ULL;
                m &= ~clearmask;
            }
            if (c == 0) s_cnt = cnt;
        }
        __syncthreads();
    }

    __syncthreads();
    int K = s_cnt;
    for (int r = K + tid; r < POST_TOPN; r += (int)blockDim.x) {
        float* o = out + ((size_t)b * POST_TOPN + r) * 5;
        o[0] = 0.0f; o[1] = 0.0f; o[2] = 0.0f; o[3] = 0.0f; o[4] = 0.0f;
    }
}

// ---------------------------------------------------------------------------
extern "C" void kernel_launch(void* const* d_in, const int* in_sizes, int n_in,
                              void* d_out, int out_size, void* d_ws, size_t ws_size,
                              hipStream_t stream) {
    const float* anchors = (const float*)d_in[0];
    const float* deltas  = (const float*)d_in[1];
    const float* scores  = (const float*)d_in[2];
    float* out = (float*)d_out;

    int N = in_sizes[0] / 4;           // 27380
    int B = in_sizes[2] / N;           // 8

    size_t off = 0;
    auto take = [&](size_t bytes) { size_t o = off; off = (off + bytes + 255) & ~(size_t)255; return o; };
    size_t boxesOff  = take((size_t)B * N * 4 * sizeof(float));
    size_t keysOff   = take((size_t)B * SORTN * sizeof(u64));
    size_t sboxOff   = take((size_t)B * PADN * sizeof(float4));
    size_t bitmapOff = take((size_t)B * TRI_WORDS * sizeof(u64));
    size_t diagOff   = take((size_t)B * PADN * sizeof(u64));
    size_t SgOff     = take((size_t)B * MASK_WORDS * sizeof(u64));
    size_t pgOff     = take((size_t)B * POST_TOPN * sizeof(int));
    size_t kcntOff   = take((size_t)B * sizeof(int));
    size_t doneOff   = take((size_t)B * sizeof(int));
    bool bitmap_path = (off <= ws_size);

    float* boxes = (float*)((char*)d_ws + boxesOff);
    u64*   keys  = (u64*)((char*)d_ws + keysOff);
    u64* diag    = bitmap_path ? (u64*)((char*)d_ws + diagOff)  : nullptr;
    u64* S_g     = bitmap_path ? (u64*)((char*)d_ws + SgOff)    : nullptr;
    int* pg      = bitmap_path ? (int*)((char*)d_ws + pgOff)    : nullptr;
    int* kcnt    = bitmap_path ? (int*)((char*)d_ws + kcntOff)  : nullptr;
    int* done    = bitmap_path ? (int*)((char*)d_ws + doneOff)  : nullptr;

    dim3 g1((unsigned)((SORTN + 255) / 256), (unsigned)B);
    decode_pack<<<g1, 256, 0, stream>>>(anchors, deltas, scores, boxes, keys, kcnt, done, N);

    // ---- sort: 2048-tiles local sort, then per level k a fused register-
    // orbit global kernel (all j >= 2048) + one LDS local merge (j <= 1024).
    int ntiles = B * NTILE;                       // 128 blocks
    bitonic_local_sort<<<ntiles, 256, 0, stream>>>(keys);
    {
        unsigned g1b = (unsigned)(B * (SORTN >> 1) / 256);
        bitonic_fused_global<1><<<g1b, 256, 0, stream>>>(keys);
        bitonic_local_merge<<<ntiles, 256, 0, stream>>>(keys, 4096);
        unsigned g2b = (unsigned)(B * (SORTN >> 2) / 256);
        bitonic_fused_global<2><<<g2b, 256, 0, stream>>>(keys);
        bitonic_local_merge<<<ntiles, 256, 0, stream>>>(keys, 8192);
        unsigned g3b = (unsigned)(B * (SORTN >> 3) / 256);
        bitonic_fused_global<3><<<g3b, 256, 0, stream>>>(keys);
        bitonic_local_merge<<<ntiles, 256, 0, stream>>>(keys, 16384);
        unsigned g4b = (unsigned)(B * (SORTN >> 4) / 256);
        bitonic_fused_global<4><<<g4b, 256, 0, stream>>>(keys);
        bitonic_local_merge<<<ntiles, 256, 0, stream>>>(keys, 32768);
    }

    if (bitmap_path) {
        float4* sbox = (float4*)((char*)d_ws + sboxOff);
        u64* bitmap  = (u64*)((char*)d_ws + bitmapOff);
        dim3 gg((unsigned)((PADN + 255) / 256), (unsigned)B);
        gather_sorted<<<gg, 256, 0, stream>>>(boxes, keys, sbox, N);

        // Progressive build/scan with per-batch done[] cutoff. Segments in
        // col-block units (even; widths <= 128 per the catch-up's 2-segment
        // mapping).
        const int seg[6] = {0, 48, 64, 88, 120, NBLK};
        for (int s = 0; s < 5; ++s) {
            int c0 = seg[s], c1 = seg[s + 1];
            int p0 = c0 / 2;
            int npair = (c1 - c0) / 2;
            unsigned gy = (unsigned)(((c1 / 2 - 1) >> 1) + 1);   // 256-row chunks
            dim3 gb((unsigned)npair, gy, (unsigned)B);
            build_bitmap<<<gb, 256, 0, stream>>>(sbox, bitmap, diag, done, p0);
            scan_nms<<<B, 1024, 0, stream>>>(sbox, bitmap, diag, out, S_g, pg, kcnt, done, c0, c1);
        }
    } else {
        nms_kernel<<<B, 1024, 0, stream>>>(boxes, keys, out, N);
    }
}

// Round 10
// 241.909 us; speedup vs baseline: 3.5840x; 1.0592x over previous
//
#include <hip/hip_runtime.h>
#include <cmath>

typedef unsigned long long u64;

#define PRE_TOPN 12000
#define POST_TOPN 2000
#define SORTN 32768
#define TILE 2048              // local-sort tile
#define NTILE (SORTN / TILE)   // 16 tiles per batch
#define NBLK 188               // 64-bit column blocks covering 12032
#define PADN (NBLK * 64)       // 12032
// ROW-MAJOR triangular bitmap: row r stores words for col-blocks
// cb in [r/64, NBLK) contiguously at rowoff(r). Total words per batch:
#define TRI_WORDS (32 * (NBLK - 1) * NBLK + NBLK * 64)  // 1,137,024
#define MASK_WORDS 192         // 188 used, padded

// Light workgroup barrier: orders LDS (lgkmcnt) but lets global loads stay
// in flight across the barrier.
#define WG_SYNC() asm volatile("s_waitcnt lgkmcnt(0)\n\ts_barrier" ::: "memory")

__device__ __forceinline__ int rowoff(int r) {
    int rb = r >> 6;
    int q = r & 63;
    return r * NBLK - (32 * rb * (rb - 1) + q * rb);
}

// ---------------------------------------------------------------------------
// Kernel 1: decode boxes (exact fp32 op order, no FMA contraction, exp via
// double) and pack sort keys. key = (~score_bits)<<32 | idx.
// Also resets the per-batch NMS progress state (kcnt/done) for this launch.
// ---------------------------------------------------------------------------
__global__ void decode_pack(const float* __restrict__ anchors,
                            const float* __restrict__ deltas,
                            const float* __restrict__ scores,
                            float* __restrict__ boxes,
                            u64* __restrict__ keys,
                            int* __restrict__ kcnt,
                            int* __restrict__ done,
                            int N) {
#pragma clang fp contract(off)
    int n = blockIdx.x * blockDim.x + threadIdx.x;
    int b = blockIdx.y;
    if (kcnt != nullptr && blockIdx.x == 0 && threadIdx.x == 0) {
        kcnt[b] = 0;
        done[b] = 0;
    }
    if (n >= SORTN) return;
    u64* kb = keys + (size_t)b * SORTN;
    if (n < N) {
        float a0 = anchors[n * 4 + 0];
        float a1 = anchors[n * 4 + 1];
        float a2 = anchors[n * 4 + 2];
        float a3 = anchors[n * 4 + 3];
        float w = (a2 - a0) + 1.0f;
        float h = (a3 - a1) + 1.0f;
        float cx = a0 + 0.5f * w;
        float cy = a1 + 0.5f * h;
        const float* d = deltas + ((size_t)b * N + n) * 4;
        float dx = d[0], dy = d[1], dw = d[2], dh = d[3];
        float px = cx + w * dx;
        float py = cy + h * dy;
        float pw = (float)::exp((double)dw) * w;
        float ph = (float)::exp((double)dh) * h;
        float* bb = boxes + ((size_t)b * N + n) * 4;
        bb[0] = px - 0.5f * pw;
        bb[1] = py - 0.5f * ph;
        bb[2] = px + 0.5f * (pw - 2.0f);
        bb[3] = py + 0.5f * (ph - 2.0f);
        unsigned int sb = __float_as_uint(scores[(size_t)b * N + n]);
        kb[n] = ((u64)(~sb) << 32) | (u64)(unsigned int)n;
    } else {
        kb[n] = ~0ULL;
    }
}

// ---------------------------------------------------------------------------
// Hybrid bitonic sort: 2048-element tiles + register-orbit fused global steps.
// ---------------------------------------------------------------------------
__global__ __launch_bounds__(256) void bitonic_local_sort(u64* __restrict__ keys) {
    __shared__ u64 sk[TILE];
    int tile = blockIdx.x;
    u64* kb = keys + (size_t)tile * TILE;
    int base = (tile % NTILE) * TILE;
    for (int i = threadIdx.x; i < TILE; i += 256) sk[i] = kb[i];
    __syncthreads();
    for (int k = 2; k <= TILE; k <<= 1) {
        for (int j = k >> 1; j > 0; j >>= 1) {
            for (int t = threadIdx.x; t < TILE / 2; t += 256) {
                int i = ((t & ~(j - 1)) << 1) | (t & (j - 1));
                int ixj = i | j;
                u64 a = sk[i];
                u64 c = sk[ixj];
                bool up = (((base + i) & k) == 0);
                if ((a > c) == up) { sk[i] = c; sk[ixj] = a; }
            }
            __syncthreads();
        }
    }
    for (int i = threadIdx.x; i < TILE; i += 256) kb[i] = sk[i];
}

template<int G>
__global__ __launch_bounds__(256) void bitonic_fused_global(u64* __restrict__ keys) {
    const int K = TILE << G;
    const int M = 1 << G;
    int nbase = SORTN >> G;                  // base indices per batch
    int t = blockIdx.x * 256 + threadIdx.x;  // over B*nbase
    int b = t / nbase;
    int r = t % nbase;
    int low = r & (TILE - 1);
    int high = (r >> 11) << (11 + G);
    int base = high | low;
    u64* kb = keys + (size_t)b * SORTN;
    bool up = ((base & K) == 0);
    u64 e[M];
#pragma unroll
    for (int m = 0; m < M; ++m) e[m] = kb[base + (m << 11)];
#pragma unroll
    for (int s = G - 1; s >= 0; --s) {
        const int bit = 1 << s;
#pragma unroll
        for (int m = 0; m < M; ++m) {
            if (!(m & bit)) {
                u64 a = e[m], c = e[m | bit];
                if ((a > c) == up) { e[m] = c; e[m | bit] = a; }
            }
        }
    }
#pragma unroll
    for (int m = 0; m < M; ++m) kb[base + (m << 11)] = e[m];
}

__global__ __launch_bounds__(256) void bitonic_local_merge(u64* __restrict__ keys, int k) {
    __shared__ u64 sk[TILE];
    int tile = blockIdx.x;
    u64* kb = keys + (size_t)tile * TILE;
    int base = (tile % NTILE) * TILE;
    bool up = ((base & k) == 0);
    for (int i = threadIdx.x; i < TILE; i += 256) sk[i] = kb[i];
    __syncthreads();
    for (int j = TILE / 2; j > 0; j >>= 1) {
        for (int t = threadIdx.x; t < TILE / 2; t += 256) {
            int i = ((t & ~(j - 1)) << 1) | (t & (j - 1));
            int ixj = i | j;
            u64 a = sk[i];
            u64 c = sk[ixj];
            if ((a > c) == up) { sk[i] = c; sk[ixj] = a; }
        }
        __syncthreads();
    }
    for (int i = threadIdx.x; i < TILE; i += 256) kb[i] = sk[i];
}

// ---------------------------------------------------------------------------
// Gather sorted top-PADN boxes. Pad rows get far-away degenerate boxes.
// ---------------------------------------------------------------------------
__global__ void gather_sorted(const float* __restrict__ boxes,
                              const u64* __restrict__ keys,
                              float4* __restrict__ sbox, int N) {
    int r = blockIdx.x * 256 + threadIdx.x;
    int b = blockIdx.y;
    if (r >= PADN) return;
    float4 v;
    if (r < PRE_TOPN) {
        u64 key = keys[(size_t)b * SORTN + r];
        int n = (int)(unsigned)(key & 0xffffffffULL);
        v = ((const float4*)boxes)[(size_t)b * N + n];
    } else {
        v = make_float4(-4e8f, -4e8f, -4e8f, -4e8f);
    }
    sbox[(size_t)b * PADN + r] = v;
}

// ---------------------------------------------------------------------------
// Exact-f32 suppression predicate (bit-identical to the f64 reference test).
// ---------------------------------------------------------------------------
__device__ __forceinline__ void iou_bit(float4 me, float ar, float4 cj, float aj,
                                        int j, unsigned& lo, unsigned& hi, int& tie) {
#pragma clang fp contract(off)
    float xx1 = fmaxf(me.x, cj.x);
    float yy1 = fmaxf(me.y, cj.y);
    float xx2 = fminf(me.z, cj.z);
    float yy2 = fminf(me.w, cj.w);
    float w = fmaxf((xx2 - xx1) + 1.0f, 0.0f);
    float h = fmaxf((yy2 - yy1) + 1.0f, 0.0f);
    float inter = w * h;
    float un = (ar + aj) - inter;
    float t = __builtin_fmaf(-0.7f, un, inter);
    float u25 = un * 0x1p-25f;
    unsigned sup = (t > u25) ? 1u : 0u;
    tie |= (t == u25) ? 1 : 0;
    if (j < 32) lo |= sup << j;
    else        hi |= sup << (j - 32);
}

__device__ __attribute__((noinline)) u64 slow_word(float4 me, float ar,
                                                   const float4* cbox,
                                                   const float* carea) {
#pragma clang fp contract(off)
    const double MD = (double)0.7f + 0x1p-25;   // exact midpoint multiplier
    u64 word = 0;
    for (int j = 0; j < 64; ++j) {
        float4 cj = cbox[j];
        float aj = carea[j];
        float xx1 = fmaxf(me.x, cj.x);
        float yy1 = fmaxf(me.y, cj.y);
        float xx2 = fminf(me.z, cj.z);
        float yy2 = fminf(me.w, cj.w);
        float w = fmaxf((xx2 - xx1) + 1.0f, 0.0f);
        float h = fmaxf((yy2 - yy1) + 1.0f, 0.0f);
        float inter = w * h;
        float un = (ar + aj) - inter;
        bool sup = ((double)inter >= MD * (double)un);
        word |= ((u64)sup) << j;
    }
    return word;
}

// ---------------------------------------------------------------------------
// Build ROW-MAJOR suppression bitmap for col-block pairs [pair0, ...).
// Diagonal words are ALSO written to the contiguous diag[] array.
// ---------------------------------------------------------------------------
__global__ __launch_bounds__(256) void build_bitmap(const float4* __restrict__ sbox,
                                                    u64* __restrict__ bitmap,
                                                    u64* __restrict__ diag,
                                                    const int* __restrict__ done,
                                                    int pair0) {
    int pair = pair0 + blockIdx.x;   // covers cbs 2*pair, 2*pair+1
    int chunk = blockIdx.y;          // 256-row chunk
    int b = blockIdx.z;
    if (done[b]) return;
    if (2 * chunk > pair) return;    // chunk's first row >= (2p+2)*64 -> empty
    int tid = threadIdx.x;
    int w = tid & 1;
    int cb = pair * 2 + w;
    int lim = (cb + 1) * 64;         // rows with words in column-block cb

    __shared__ float4 cbox[2][64];
    __shared__ float carea[2][64];
    const float4* sb = sbox + (size_t)b * PADN;
    if (tid < 128) {
        int which = tid >> 6, j = tid & 63;
        float4 c4 = sb[(pair * 2 + which) * 64 + j];
        cbox[which][j] = c4;
        carea[which][j] = ((c4.z - c4.x) + 1.0f) * ((c4.w - c4.y) + 1.0f);
    }
    int rl = tid >> 1;               // 0..127
    int r1 = chunk * 256 + rl;       // <= 46*256+127 = 11903 < PADN
    int r2 = r1 + 128;               // <= 12031 < PADN
    bool a1 = (r1 < lim);
    bool a2 = (r2 < lim);
    float4 me1 = sb[r1];
    float4 me2 = sb[r2];
    float ar1 = ((me1.z - me1.x) + 1.0f) * ((me1.w - me1.y) + 1.0f);
    float ar2 = ((me2.z - me2.x) + 1.0f) * ((me2.w - me2.y) + 1.0f);
    __syncthreads();

    u64* dgb = diag + (size_t)b * PADN;
    if (a1) {
        unsigned lo1 = 0, hi1 = 0;
        int tie1 = 0;
#pragma unroll
        for (int j = 0; j < 64; ++j) {
            iou_bit(me1, ar1, cbox[w][j], carea[w][j], j, lo1, hi1, tie1);
        }
        u64 w1 = ((u64)hi1 << 32) | lo1;
        if (__builtin_expect(tie1, 0)) w1 = slow_word(me1, ar1, cbox[w], carea[w]);
        int d1 = r1 - cb * 64;
        if (d1 >= 0) {                               // diagonal block word
            w1 &= ~((2ULL << d1) - 1ULL);
            dgb[r1] = w1;
        }
        bitmap[(size_t)b * TRI_WORDS + rowoff(r1) + (cb - (r1 >> 6))] = w1;
    }
    if (a2) {
        unsigned lo2 = 0, hi2 = 0;
        int tie2 = 0;
#pragma unroll
        for (int j = 0; j < 64; ++j) {
            iou_bit(me2, ar2, cbox[w][j], carea[w][j], j, lo2, hi2, tie2);
        }
        u64 w2 = ((u64)hi2 << 32) | lo2;
        if (__builtin_expect(tie2, 0)) w2 = slow_word(me2, ar2, cbox[w], carea[w]);
        int d2 = r2 - cb * 64;
        if (d2 >= 0) {
            w2 &= ~((2ULL << d2) - 1ULL);
            dgb[r2] = w2;
        }
        bitmap[(size_t)b * TRI_WORDS + rowoff(r2) + (cb - (r2 >> 6))] = w2;
    }
}

// ---------------------------------------------------------------------------
// DPP helpers: 16-lane OR-reduce, wave total via readlanes, and the
// canonical 64-lane inclusive prefix-OR scan.
// ---------------------------------------------------------------------------
__device__ __forceinline__ unsigned dpp_or16(unsigned v) {
    v |= (unsigned)__builtin_amdgcn_update_dpp(0, (int)v, 0xB1, 0xF, 0xF, true);   // quad_perm {1,0,3,2}
    v |= (unsigned)__builtin_amdgcn_update_dpp(0, (int)v, 0x4E, 0xF, 0xF, true);   // quad_perm {2,3,0,1}
    v |= (unsigned)__builtin_amdgcn_update_dpp(0, (int)v, 0x141, 0xF, 0xF, true);  // row_half_mirror
    v |= (unsigned)__builtin_amdgcn_update_dpp(0, (int)v, 0x140, 0xF, 0xF, true);  // row_mirror
    return v;
}

__device__ __forceinline__ unsigned wave_or_from_rows(unsigned rowred) {
    unsigned a = (unsigned)__builtin_amdgcn_readlane((int)rowred, 0) |
                 (unsigned)__builtin_amdgcn_readlane((int)rowred, 16);
    unsigned c = (unsigned)__builtin_amdgcn_readlane((int)rowred, 32) |
                 (unsigned)__builtin_amdgcn_readlane((int)rowred, 48);
    return a | c;
}

__device__ __forceinline__ unsigned wave_incl_prefix_or(unsigned v) {
    v |= (unsigned)__builtin_amdgcn_update_dpp(0, (int)v, 0x111, 0xF, 0xF, true);  // row_shr:1
    v |= (unsigned)__builtin_amdgcn_update_dpp(0, (int)v, 0x112, 0xF, 0xF, true);  // row_shr:2
    v |= (unsigned)__builtin_amdgcn_update_dpp(0, (int)v, 0x114, 0xF, 0xF, true);  // row_shr:4
    v |= (unsigned)__builtin_amdgcn_update_dpp(0, (int)v, 0x118, 0xF, 0xF, true);  // row_shr:8
    v |= (unsigned)__builtin_amdgcn_update_dpp(0, (int)v, 0x142, 0xA, 0xF, true);  // row_bcast:15 -> rows 1,3
    v |= (unsigned)__builtin_amdgcn_update_dpp(0, (int)v, 0x143, 0xC, 0xF, true);  // row_bcast:31 -> rows 2,3
    return v;
}

// ---------------------------------------------------------------------------
// Resumable scan, round-15 = round-13 structure + LAG-2 SOFTWARE PIPELINE:
//  - OR-crew at iter rb CONSUMES registers preloaded during iter rb-1 (tails
//    of picks of rb-2, cols [rb+1, rb1)) -- pure VALU -- then ISSUES loads
//    for picks of rb-1 (consumption cols [rb+2, rb1), off = 3+ce). Every
//    load gets a full iteration of slack, so no exposed memory latency.
//  - wave0 runs a 2-deep delta pipeline: on pick at iter m, self-load
//    word(p, m+1) and word(p, m+2); sup_extra at iter c = cur1 | cur2 =
//    picks(c-1)@c | picks(c-2)@c. Cols >= m+3 come from the crew's consume
//    at iter m+2; stage-crossing tails from the catch-up (all K0 picks x
//    [rb0, rb1)). Coverage: col c gets picks c-1 (cur1), c-2 (cur2/pend2),
//    <= c-3 (crew, barrier-ordered before the read).
// Semantics identical to rounds 7-14.
// ---------------------------------------------------------------------------
__global__ __launch_bounds__(1024) void scan_nms(const float4* __restrict__ sbox,
                                                 const u64* __restrict__ bitmap,
                                                 const u64* __restrict__ diag,
                                                 float* __restrict__ out,
                                                 u64* __restrict__ S_g,
                                                 int* __restrict__ picks_g,
                                                 int* __restrict__ kcnt,
                                                 int* __restrict__ done,
                                                 int rb0, int rb1) {
    int b = blockIdx.x;
    if (done[b]) return;
    int tid = threadIdx.x;
    int lane = tid & 63;
    int wv = tid >> 6;                     // 0..15
    __shared__ u64 s_S[MASK_WORDS];        // 1.5 KB running suppression mask
    __shared__ int s_pp[POST_TOPN];        // 8 KB committed pick rows
    __shared__ int s_prevpicks[2][64];
    __shared__ int s_np[2];
    __shared__ int s_K;

    u64* Sg = S_g + (size_t)b * MASK_WORDS;
    int* pg = picks_g + (size_t)b * POST_TOPN;
    int K0 = kcnt[b];
    if (tid == 0) s_K = K0;
    if (tid < 2) s_np[tid] = 0;
    if (tid < MASK_WORDS) s_S[tid] = (tid < NBLK && rb0 > 0) ? Sg[tid] : 0ULL;
    for (int t = tid; t < K0; t += 1024) s_pp[t] = pg[t];
    WG_SYNC();

    const u64* bm = bitmap + (size_t)b * TRI_WORDS;
    const u64* dgb = diag + (size_t)b * PADN;
    const float4* sbb = sbox + (size_t)b * PADN;

    u64 myrow = 0;
    u64 cur1 = 0, cur2 = 0, pend2 = 0;     // wave0 2-deep delta pipeline
    u64 pf[16];                            // OR-crew preload regs (static idx)
#pragma unroll
    for (int t = 0; t < 16; ++t) pf[t] = 0;
    bool haveC = false, actC = false;
    u64 amaskC = 0;
    int colC = 0;
    float4 mybox = make_float4(0.f, 0.f, 0.f, 0.f);

    if (wv == 0) {
        // prologue diag row + box for rb0 (coalesced; overlaps catch-up)
        int r = rb0 * 64 + lane;
        myrow = dgb[r];
        mybox = sbb[r];
    } else if (rb0 > 0 && K0 > 0) {
        // ---- CATCH-UP: cols [rb0, rb1) x all K0 prior picks ----
        int width = rb1 - rb0;             // <= 128 by stage construction
        int nseg2 = (width + 63) >> 6;     // 1 or 2
        int w = wv - 1;                    // 0..14
        int s2, str, nstr;
        if (nseg2 == 2) { s2 = w & 1; str = w >> 1; nstr = (s2 == 0) ? 8 : 7; }
        else            { s2 = 0;     str = w;      nstr = 15; }
        int ce = s2 * 64 + lane;
        bool act = (ce < width);
        u64 amask = act ? ~0ULL : 0ULL;
        int cb = rb0 + ce;
        int cbc = act ? cb : rb0;
        u64 acc = 0;
        int last = K0 - 1;
        for (int q = str; q < K0; q += 8 * nstr) {
            int q0 = q;
            int q1 = q + nstr;     if (q1 > last) q1 = q0;
            int q2 = q + 2 * nstr; if (q2 > last) q2 = q0;
            int q3 = q + 3 * nstr; if (q3 > last) q3 = q0;
            int q4 = q + 4 * nstr; if (q4 > last) q4 = q0;
            int q5 = q + 5 * nstr; if (q5 > last) q5 = q0;
            int q6 = q + 6 * nstr; if (q6 > last) q6 = q0;
            int q7 = q + 7 * nstr; if (q7 > last) q7 = q0;
            int p0 = s_pp[q0], p1 = s_pp[q1], p2 = s_pp[q2], p3 = s_pp[q3];
            int p4 = s_pp[q4], p5 = s_pp[q5], p6 = s_pp[q6], p7 = s_pp[q7];
            u64 v0 = bm[rowoff(p0) + (cbc - (p0 >> 6))];
            u64 v1 = bm[rowoff(p1) + (cbc - (p1 >> 6))];
            u64 v2 = bm[rowoff(p2) + (cbc - (p2 >> 6))];
            u64 v3 = bm[rowoff(p3) + (cbc - (p3 >> 6))];
            u64 v4 = bm[rowoff(p4) + (cbc - (p4 >> 6))];
            u64 v5 = bm[rowoff(p5) + (cbc - (p5 >> 6))];
            u64 v6 = bm[rowoff(p6) + (cbc - (p6 >> 6))];
            u64 v7 = bm[rowoff(p7) + (cbc - (p7 >> 6))];
            acc |= ((v0 | v1) | (v2 | v3)) | ((v4 | v5) | (v6 | v7));
        }
        acc &= amask;
        if (act && acc) atomicOr(&s_S[cb], acc);
    }
    WG_SYNC();

    int rb = rb0;
    for (; rb < rb1; ++rb) {
        int K = s_K;                       // uniform (post-barrier)
        if (K >= POST_TOPN) break;
        int base = rb * 64;
        bool havenext = (rb + 1 < rb1);
        bool havenext2 = (rb + 2 < rb1);
        int pq = (rb + 1) & 1;             // parity of picks of rb-1

        if (wv == 0) {
            // early prefetch of next diagonal row+box (coalesced diag[])
            u64 nrow = 0;
            float4 nbox = make_float4(0.f, 0.f, 0.f, 0.f);
            if (havenext) {
                int rn = (rb + 1) * 64 + lane;
                nrow = dgb[rn];
                nbox = sbb[rn];
            }
            // delta: picks(rb-1)@rb (cur1) | picks(rb-2)@rb (cur2)
            u64 dd = cur1 | cur2;
            unsigned rlo = dpp_or16((unsigned)(dd & 0xffffffffULL));
            unsigned rhi = dpp_or16((unsigned)(dd >> 32));
            u64 dtot = ((u64)wave_or_from_rows(rhi) << 32) | wave_or_from_rows(rlo);
            u64 t4 = s_S[rb] | dtot;
            if (rb == NBLK - 1) t4 |= 0xFFFFFFFF00000000ULL;   // pad rows >= 12000
            unsigned tlo = (unsigned)__builtin_amdgcn_readfirstlane((int)(t4 & 0xffffffffULL));
            unsigned thi = (unsigned)__builtin_amdgcn_readfirstlane((int)(t4 >> 32));
            u64 alive = ~(((u64)thi << 32) | tlo);
            unsigned mlo = (unsigned)(myrow & 0xffffffffULL);
            unsigned mhi = (unsigned)(myrow >> 32);

            // ---- frontier-batched greedy (exact serial-greedy pick set) ----
            u64 picks = 0;
            int round = 0;
            while (alive) {
                if (round >= 8) {
                    // serial fallback for pathological chain depth
                    u64 cur = alive;
                    while (cur) {
                        int i = (int)__builtin_ctzll(cur);
                        picks |= 1ULL << i;
                        unsigned rl = (unsigned)__builtin_amdgcn_readlane((int)mlo, i);
                        unsigned rh = (unsigned)__builtin_amdgcn_readlane((int)mhi, i);
                        u64 row = ((u64)rh << 32) | rl;
                        alive &= ~row;
                        cur = alive & ~((2ULL << i) - 1ULL);
                    }
                    break;
                }
                bool isal = ((alive >> lane) & 1ULL) != 0ULL;
                unsigned clo = isal ? mlo : 0u;
                unsigned chi = isal ? mhi : 0u;
                unsigned plo = wave_incl_prefix_or(clo);
                unsigned phi = wave_incl_prefix_or(chi);
                u64 pre = ((u64)phi << 32) | plo;
                bool infront = isal && (((pre >> lane) & 1ULL) == 0ULL);
                u64 front = __ballot(infront);
                picks |= front;
                unsigned slo = infront ? mlo : 0u;
                unsigned shi = infront ? mhi : 0u;
                slo = dpp_or16(slo); shi = dpp_or16(shi);
                u64 sup = ((u64)wave_or_from_rows(shi) << 32) | wave_or_from_rows(slo);
                alive &= ~(front | sup);
                ++round;
            }

            int avail = POST_TOPN - K;
            int np = __popcll(picks);
            while (np > avail) {                       // truncate latest picks
                picks &= ~(1ULL << (63 - __clzll(picks)));
                --np;
            }
            int c = lane;
            bool ipick = ((picks >> c) & 1ULL) != 0;
            u64 n1 = 0, n2 = 0;
            if (ipick) {
                int rank = __popcll(picks & ((1ULL << c) - 1ULL));
                int p = base + c;
                s_prevpicks[rb & 1][rank] = p;
                pg[K + rank] = p;                      // persist pick row
                float* o = out + ((size_t)b * POST_TOPN + K + rank) * 5;
                o[0] = (float)b; o[1] = mybox.x; o[2] = mybox.y; o[3] = mybox.z; o[4] = mybox.w;
                if (havenext)  n1 = bm[rowoff(p) + 1];   // word (p, rb+1)
                if (havenext2) n2 = bm[rowoff(p) + 2];   // word (p, rb+2)
            }
            cur1 = n1; cur2 = pend2; pend2 = n2;       // shift the pipeline
            if (c == 0) {
                s_K = K + np;
                s_np[rb & 1] = np;
            }
            myrow = nrow; mybox = nbox;
        } else {
            // -- consume: preloads issued last iter (picks of rb-2) -> s_S --
            if (haveC) {
                u64 acc = 0;
#pragma unroll
                for (int t = 0; t < 16; ++t) acc |= pf[t];
                acc &= amaskC;
                if (actC && acc) atomicOr(&s_S[colC], acc);
            }
            haveC = false;
            // -- issue: tails of picks of rb-1, consumed at iter rb+1 over
            //    cols [rb+2, rb1). wave w: col-seg (w-1)%3, stripe (w-1)/3. --
            int npp = s_np[pq];
            int lenn = rb1 - (rb + 2);
            int w = wv - 1;                   // 0..14
            int a3 = (w * 11) >> 5;           // w / 3
            int r3 = w - a3 * 3;              // w % 3
            if (npp > 0 && lenn > 0 && r3 * 64 < lenn) {
                const int* pp = s_prevpicks[pq];
                int ce = r3 * 64 + lane;
                bool act = (ce < lenn);
                actC = act;
                amaskC = act ? ~0ULL : 0ULL;
                colC = rb + 2 + (act ? ce : 0);
                int off = act ? (3 + ce) : 0;
                int last = npp - 1;
#pragma unroll
                for (int t = 0; t < 16; ++t) {
                    int q = a3 + 5 * t;       // stride-5 covers npp <= 64 (t<13)
                    if (q > last) q = a3;     // idempotent clamp (OR-safe)
                    pf[t] = bm[rowoff(pp[q]) + off];
                }
                haveC = true;
            }
        }
        WG_SYNC();
    }

    int K = s_K;
    bool finished = (K >= POST_TOPN) || (rb1 >= NBLK);
    if (finished) {
        for (int r = K + tid; r < POST_TOPN; r += 1024) {
            float* o = out + ((size_t)b * POST_TOPN + r) * 5;
            o[0] = 0.0f; o[1] = 0.0f; o[2] = 0.0f; o[3] = 0.0f; o[4] = 0.0f;
        }
        if (tid == 0) done[b] = 1;
    } else {
        // persist running mask; picks of the last blocks get their tails
        // (cols >= rb1) OR'd by the NEXT stage's catch-up via picks_g.
        if (tid < NBLK) Sg[tid] = s_S[tid];
    }
    if (tid == 0) kcnt[b] = K;
}

// ---------------------------------------------------------------------------
// Fallback (round-2) NMS kernel — used only if ws_size can't hold the bitmap.
// ---------------------------------------------------------------------------
__global__ __launch_bounds__(1024) void nms_kernel(const float* __restrict__ boxes,
                                                   const u64* __restrict__ keys,
                                                   float* __restrict__ out,
                                                   int N) {
#pragma clang fp contract(off)
    __shared__ float4 kbox[POST_TOPN];
    __shared__ float kar[POST_TOPN];
    __shared__ float4 cbox[64];
    __shared__ float car_s[64];
    __shared__ int supp[64];
    __shared__ int s_cnt;

    int b = blockIdx.x;
    int tid = threadIdx.x;
    const u64* kb = keys + (size_t)b * SORTN;
    const float* bb = boxes + (size_t)b * N * 4;

    if (tid == 0) s_cnt = 0;
    __syncthreads();

    for (int start = 0; start < PRE_TOPN; start += 64) {
        int K = s_cnt;
        if (K >= POST_TOPN) break;
        int csize = min(64, PRE_TOPN - start);

        if (tid < 64) {
            int c = tid;
            if (c < csize) {
                u64 key = kb[start + c];
                int n = (int)(unsigned int)(key & 0xFFFFFFFFULL);
                const float* p = bb + (size_t)n * 4;
                float x1 = p[0], y1 = p[1], x2 = p[2], y2 = p[3];
                cbox[c] = make_float4(x1, y1, x2, y2);
                car_s[c] = ((x2 - x1) + 1.0f) * ((y2 - y1) + 1.0f);
            }
            supp[c] = 0;
        }
        __syncthreads();

        {
            int c = tid & 63;
            int sl = tid >> 6;
            if (c < csize) {
                float4 me = cbox[c];
                float ar = car_s[c];
                int flag = 0;
                for (int kk = sl; kk < K; kk += 16) {
                    float4 k0 = kbox[kk];
                    float a0 = kar[kk];
                    float xx1 = fmaxf(k0.x, me.x);
                    float yy1 = fmaxf(k0.y, me.y);
                    float xx2 = fminf(k0.z, me.z);
                    float yy2 = fminf(k0.w, me.w);
                    float w0 = fmaxf((xx2 - xx1) + 1.0f, 0.0f);
                    float h0 = fmaxf((yy2 - yy1) + 1.0f, 0.0f);
                    float inter0 = w0 * h0;
                    float iou0 = inter0 / ((a0 + ar) - inter0);
                    if (iou0 > 0.7f) { flag = 1; break; }
                }
                if (flag) supp[c] = 1;
            }
        }
        __syncthreads();

        if (tid < 64) {
            int c = tid;
            bool alive = (c < csize) && (supp[c] == 0);
            float4 me = cbox[c];
            float ar = car_s[c];
            int cnt = K;
            u64 m = __ballot(alive);
            while (m != 0 && cnt < POST_TOPN) {
                int i = __ffsll((unsigned long long)m) - 1;
                float ix1 = __shfl(me.x, i);
                float iy1 = __shfl(me.y, i);
                float ix2 = __shfl(me.z, i);
                float iy2 = __shfl(me.w, i);
                float iar = __shfl(ar, i);
                if (c == i) {
                    kbox[cnt] = me;
                    kar[cnt] = ar;
                    float* o = out + ((size_t)b * POST_TOPN + cnt) * 5;
                    o[0] = (float)b; o[1] = me.x; o[2] = me.y; o[3] = me.z; o[4] = me.w;
                }
                if (alive && c > i) {
                    float xx1 = fmaxf(ix1, me.x);
                    float yy1 = fmaxf(iy1, me.y);
                    float xx2 = fminf(ix2, me.z);
                    float yy2 = fminf(iy2, me.w);
                    float w = fmaxf((xx2 - xx1) + 1.0f, 0.0f);
                    float h = fmaxf((yy2 - yy1) + 1.0f, 0.0f);
                    float inter = w * h;
                    float iou = inter / ((iar + ar) - inter);
                    if (iou > 0.7f) alive = false;
                }
                cnt++;
                m = __ballot(alive);
                u64 clearmask = (2ULL << i) - 1ULL;
                m &= ~clearmask;
            }
            if (c == 0) s_cnt = cnt;
        }
        __syncthreads();
    }

    __syncthreads();
    int K = s_cnt;
    for (int r = K + tid; r < POST_TOPN; r += (int)blockDim.x) {
        float* o = out + ((size_t)b * POST_TOPN + r) * 5;
        o[0] = 0.0f; o[1] = 0.0f; o[2] = 0.0f; o[3] = 0.0f; o[4] = 0.0f;
    }
}

// ---------------------------------------------------------------------------
extern "C" void kernel_launch(void* const* d_in, const int* in_sizes, int n_in,
                              void* d_out, int out_size, void* d_ws, size_t ws_size,
                              hipStream_t stream) {
    const float* anchors = (const float*)d_in[0];
    const float* deltas  = (const float*)d_in[1];
    const float* scores  = (const float*)d_in[2];
    float* out = (float*)d_out;

    int N = in_sizes[0] / 4;           // 27380
    int B = in_sizes[2] / N;           // 8

    size_t off = 0;
    auto take = [&](size_t bytes) { size_t o = off; off = (off + bytes + 255) & ~(size_t)255; return o; };
    size_t boxesOff  = take((size_t)B * N * 4 * sizeof(float));
    size_t keysOff   = take((size_t)B * SORTN * sizeof(u64));
    size_t sboxOff   = take((size_t)B * PADN * sizeof(float4));
    size_t bitmapOff = take((size_t)B * TRI_WORDS * sizeof(u64));
    size_t diagOff   = take((size_t)B * PADN * sizeof(u64));
    size_t SgOff     = take((size_t)B * MASK_WORDS * sizeof(u64));
    size_t pgOff     = take((size_t)B * POST_TOPN * sizeof(int));
    size_t kcntOff   = take((size_t)B * sizeof(int));
    size_t doneOff   = take((size_t)B * sizeof(int));
    bool bitmap_path = (off <= ws_size);

    float* boxes = (float*)((char*)d_ws + boxesOff);
    u64*   keys  = (u64*)((char*)d_ws + keysOff);
    u64* diag    = bitmap_path ? (u64*)((char*)d_ws + diagOff)  : nullptr;
    u64* S_g     = bitmap_path ? (u64*)((char*)d_ws + SgOff)    : nullptr;
    int* pg      = bitmap_path ? (int*)((char*)d_ws + pgOff)    : nullptr;
    int* kcnt    = bitmap_path ? (int*)((char*)d_ws + kcntOff)  : nullptr;
    int* done    = bitmap_path ? (int*)((char*)d_ws + doneOff)  : nullptr;

    dim3 g1((unsigned)((SORTN + 255) / 256), (unsigned)B);
    decode_pack<<<g1, 256, 0, stream>>>(anchors, deltas, scores, boxes, keys, kcnt, done, N);

    // ---- sort: 2048-tiles local sort, then per level k a fused register-
    // orbit global kernel (all j >= 2048) + one LDS local merge (j <= 1024).
    int ntiles = B * NTILE;                       // 128 blocks
    bitonic_local_sort<<<ntiles, 256, 0, stream>>>(keys);
    {
        unsigned g1b = (unsigned)(B * (SORTN >> 1) / 256);
        bitonic_fused_global<1><<<g1b, 256, 0, stream>>>(keys);
        bitonic_local_merge<<<ntiles, 256, 0, stream>>>(keys, 4096);
        unsigned g2b = (unsigned)(B * (SORTN >> 2) / 256);
        bitonic_fused_global<2><<<g2b, 256, 0, stream>>>(keys);
        bitonic_local_merge<<<ntiles, 256, 0, stream>>>(keys, 8192);
        unsigned g3b = (unsigned)(B * (SORTN >> 3) / 256);
        bitonic_fused_global<3><<<g3b, 256, 0, stream>>>(keys);
        bitonic_local_merge<<<ntiles, 256, 0, stream>>>(keys, 16384);
        unsigned g4b = (unsigned)(B * (SORTN >> 4) / 256);
        bitonic_fused_global<4><<<g4b, 256, 0, stream>>>(keys);
        bitonic_local_merge<<<ntiles, 256, 0, stream>>>(keys, 32768);
    }

    if (bitmap_path) {
        float4* sbox = (float4*)((char*)d_ws + sboxOff);
        u64* bitmap  = (u64*)((char*)d_ws + bitmapOff);
        dim3 gg((unsigned)((PADN + 255) / 256), (unsigned)B);
        gather_sorted<<<gg, 256, 0, stream>>>(boxes, keys, sbox, N);

        // Progressive build/scan with per-batch done[] cutoff. Segments in
        // col-block units (even; widths <= 128 per the catch-up's 2-segment
        // mapping).
        const int seg[6] = {0, 48, 64, 88, 120, NBLK};
        for (int s = 0; s < 5; ++s) {
            int c0 = seg[s], c1 = seg[s + 1];
            int p0 = c0 / 2;
            int npair = (c1 - c0) / 2;
            unsigned gy = (unsigned)(((c1 / 2 - 1) >> 1) + 1);   // 256-row chunks
            dim3 gb((unsigned)npair, gy, (unsigned)B);
            build_bitmap<<<gb, 256, 0, stream>>>(sbox, bitmap, diag, done, p0);
            scan_nms<<<B, 1024, 0, stream>>>(sbox, bitmap, diag, out, S_g, pg, kcnt, done, c0, c1);
        }
    } else {
        nms_kernel<<<B, 1024, 0, stream>>>(boxes, keys, out, N);
    }
}